// Round 8
// baseline (690.339 us; speedup 1.0000x reference)
//
#include <hip/hip_runtime.h>
#include <math.h>

#define LSEQ 1280
#define L0SEQ 1250
#define DM 64
#define NHEADS 4
#define DHD 16
#define NHASH 4
#define NBUK 20
#define NCHUNK 80
#define FFD 256
#define NBATCH 16
#define NBH 64

#define XSZ (NBATCH*LSEQ*DM)        // 1310720
#define QKSZ (NBH*LSEQ*DHD)         // 1310720
#define OHSZ (NBH*NHASH*LSEQ*DHD)   // 5242880
#define SLSZ (NBH*NHASH*LSEQ)       // 327680

typedef __attribute__((ext_vector_type(8))) short frag_ab;   // 8 bf16
typedef __attribute__((ext_vector_type(4))) float frag_c;    // 4 fp32

union FU4 { uint4 v; frag_ab f; };

// round-to-nearest-even bf16 (returns low 16 bits)
__device__ __forceinline__ unsigned rnbf(float x){
    unsigned b = __float_as_uint(x);
    return (b + 0x7fffu + ((b >> 16) & 1u)) >> 16;
}
__device__ __forceinline__ float bf2f(unsigned h){ return __uint_as_float(h << 16); }
__device__ __forceinline__ unsigned rot16(unsigned x){ return (x >> 16) | (x << 16); }

// exact triple split (truncation): x = h + m + l
__device__ __forceinline__ void split3(float x, unsigned& h, unsigned& m, unsigned& l){
    unsigned bx = __float_as_uint(x);
    h = bx >> 16;
    float r = x - __uint_as_float(bx & 0xffff0000u);
    unsigned br = __float_as_uint(r);
    m = br >> 16;
    float r2 = r - __uint_as_float(br & 0xffff0000u);
    l = __float_as_uint(r2) >> 16;
}

// ---------------- embed: x = pad(wave^T) @ in_w + in_b ----------------
__global__ __launch_bounds__(256) void k_embed(
    const float* __restrict__ wave, const float* __restrict__ in_w,
    const float* __restrict__ in_b, float* __restrict__ x1, float* __restrict__ x2)
{
    int idx = blockIdx.x * 256 + threadIdx.x;   // over B*L*D
    int d = idx & 63;
    int t = idx >> 6;
    int b = t / LSEQ;
    int tt = t % LSEQ;
    float v0 = 0.f, v1 = 0.f;
    if (tt < L0SEQ) {
        v0 = wave[(size_t)(b*2+0)*L0SEQ + tt];
        v1 = wave[(size_t)(b*2+1)*L0SEQ + tt];
    }
    float x = v0 * in_w[d] + v1 * in_w[64 + d] + in_b[d];
    x1[idx] = x;
    x2[idx] = x;
}

// ---------------- weight pre-split into MFMA-B layout (trunc-3, k-slot paired) ----------------
__global__ __launch_bounds__(256) void k_prep(
    const float* __restrict__ wo_w, const float* __restrict__ w1,
    const float* __restrict__ w2, unsigned* __restrict__ wsplit)
{
    int gid = blockIdx.x * 256 + threadIdx.x;
    if (gid >= 4*36864) return;
    int l = gid / 36864;
    int r = gid % 36864;
    float src; unsigned* dst; int idx; int stride;
    if (r < 4096) {                 // wo: K=64, N=64
        int k = r >> 6, n = r & 63;
        src = wo_w[l*4096 + k*64 + n];
        dst = wsplit + l*12288;
        idx = (((k>>4)*4 + (n>>4))*16 + (n&15))*16 + (k&15);
        stride = 4096;
    } else if (r < 20480) {         // w1: K=64, N=256
        int rr = r - 4096;
        int k = rr >> 8, n = rr & 255;
        src = w1[l*16384 + k*256 + n];
        dst = wsplit + 49152 + l*49152;
        idx = (((k>>4)*16 + (n>>4))*16 + (n&15))*16 + (k&15);
        stride = 16384;
    } else {                        // w2: K=256, N=64
        int rr = r - 20480;
        int k = rr >> 6, n = rr & 63;
        src = w2[l*16384 + k*64 + n];
        dst = wsplit + 245760 + l*49152;
        idx = (((k>>4)*4 + (n>>4))*16 + (n&15))*16 + (k&15);
        stride = 16384;
    }
    unsigned h, m, lo;
    split3(src, h, m, lo);
    dst[idx]            = h | (m<<16);
    dst[idx + stride]   = m | (h<<16);
    dst[idx + 2*stride] = lo | (h<<16);
}

// ---------------- LN + QK/V projection + LSH bucketing + PRE-SPLIT q/k/v ----------------
// block = 64 tokens of one batch; grid 320
// Writes u32 split arrays (qs=[qh|ql] 0.25-folded, ks1=[kh|kl] normalized,
// vs1=[vh|vm], vs3=[vl|vh]) so k_attn staging is a pure copy.
__global__ __launch_bounds__(256) void k_qkv(
    const float* __restrict__ x2, const float* __restrict__ g, const float* __restrict__ bta,
    const float* __restrict__ wqk, const float* __restrict__ wv, const float* __restrict__ rot,
    unsigned* __restrict__ qs, unsigned* __restrict__ ks1,
    unsigned* __restrict__ vs1, unsigned* __restrict__ vs3, int* __restrict__ buckets)
{
    __shared__ float xln[64][65];
    __shared__ float qkt[64][65];
    __shared__ float vvt[64][65];
    __shared__ float rots[640];
    __shared__ float psum[64][4];
    __shared__ float psq[64][4];
    int tid = threadIdx.x;
    int b  = blockIdx.x / 20;
    int t0 = (blockIdx.x % 20) * 64;
    const float* xbase = x2 + (size_t)(b*LSEQ + t0)*DM;
    int r = tid >> 2, qq = tid & 3;
    float vals[16];
    float s = 0.f, ss = 0.f;
    for (int i = 0; i < 16; i++) {
        float vv = xbase[r*DM + qq*16 + i];
        vals[i] = vv; s += vv; ss += vv*vv;
    }
    psum[r][qq] = s; psq[r][qq] = ss;
    for (int i = tid; i < 640; i += 256) rots[i] = rot[i];
    __syncthreads();
    float m  = (psum[r][0]+psum[r][1]+psum[r][2]+psum[r][3]) * (1.f/64.f);
    float vr = (psq[r][0]+psq[r][1]+psq[r][2]+psq[r][3]) * (1.f/64.f) - m*m;
    float rstd = 1.f / sqrtf(vr + 1e-5f);
    for (int i = 0; i < 16; i++) {
        int c = qq*16 + i;
        xln[r][c] = (vals[i]-m)*rstd*g[c] + bta[c];
    }
    __syncthreads();
    // matmuls: thread tile = 4 tokens x 4 cols
    int cg = tid & 15, tg = tid >> 4;
    int c0 = cg*4, tl0 = tg*4;
    float aq[4][4], av[4][4];
    for (int i=0;i<4;i++) for (int j=0;j<4;j++){ aq[i][j]=0.f; av[i][j]=0.f; }
    for (int f = 0; f < 64; f++) {
        float4 wq4 = *(const float4*)&wqk[f*64 + c0];
        float4 wv4 = *(const float4*)&wv [f*64 + c0];
        float xv[4];
        for (int i=0;i<4;i++) xv[i] = xln[tl0+i][f];
        for (int i=0;i<4;i++) {
            aq[i][0] += xv[i]*wq4.x; aq[i][1] += xv[i]*wq4.y;
            aq[i][2] += xv[i]*wq4.z; aq[i][3] += xv[i]*wq4.w;
            av[i][0] += xv[i]*wv4.x; av[i][1] += xv[i]*wv4.y;
            av[i][2] += xv[i]*wv4.z; av[i][3] += xv[i]*wv4.w;
        }
    }
    for (int i=0;i<4;i++) {
        qkt[tl0+i][c0+0] = aq[i][0]; qkt[tl0+i][c0+1] = aq[i][1];
        qkt[tl0+i][c0+2] = aq[i][2]; qkt[tl0+i][c0+3] = aq[i][3];
        vvt[tl0+i][c0+0] = av[i][0]; vvt[tl0+i][c0+1] = av[i][1];
        vvt[tl0+i][c0+2] = av[i][2]; vvt[tl0+i][c0+3] = av[i][3];
    }
    __syncthreads();
    // split + buckets: thread = (token, head)
    int ttk = tid >> 2, hh = tid & 3;
    float qf[16], vf[16];
    for (int f=0; f<16; f++) qf[f] = qkt[ttk][hh*16+f];
    for (int f=0; f<16; f++) vf[f] = vvt[ttk][hh*16+f];
    int tglob = t0 + ttk;
    size_t sb = (((size_t)(b*NHEADS+hh))*LSEQ + tglob)*16;
    float nsq = 0.f;
    for (int e=0; e<16; e++) nsq += qf[e]*qf[e];
    float inv = 1.f / fmaxf(sqrtf(nsq), 1e-12f);
    unsigned wq[16], wk[16], wv1[16], wv3[16];
    #pragma unroll
    for (int e=0; e<16; e++){
        float xq = qf[e]*0.25f;
        unsigned qh = rnbf(xq);
        unsigned ql = rnbf(xq - bf2f(qh));
        wq[e] = qh | (ql<<16);
        float xk = qf[e]*inv;
        unsigned kh = rnbf(xk);
        unsigned kl = rnbf(xk - bf2f(kh));
        wk[e] = kh | (kl<<16);
        unsigned vh_, vm_, vl_;
        split3(vf[e], vh_, vm_, vl_);
        wv1[e] = vh_ | (vm_<<16);
        wv3[e] = vl_ | (vh_<<16);
    }
    #pragma unroll
    for (int e4=0; e4<4; e4++){
        *(uint4*)&qs [sb + e4*4] = *(uint4*)&wq [e4*4];
        *(uint4*)&ks1[sb + e4*4] = *(uint4*)&wk [e4*4];
        *(uint4*)&vs1[sb + e4*4] = *(uint4*)&wv1[e4*4];
        *(uint4*)&vs3[sb + e4*4] = *(uint4*)&wv3[e4*4];
    }
    for (int nh = 0; nh < NHASH; nh++) {
        float rv[10];
        for (int i=0;i<10;i++) {
            float acc = 0.f;
            for (int f=0; f<16; f++) acc += qf[f]*rots[(f*NHASH+nh)*10 + i];
            rv[i] = acc;
        }
        float best = rv[0]; int bi = 0;
        for (int i=1;i<10;i++) if (rv[i] > best) { best = rv[i]; bi = i; }
        for (int i=0;i<10;i++) if (-rv[i] > best) { best = -rv[i]; bi = 10+i; }
        buckets[((size_t)(b*NHEADS+hh)*NHASH + nh)*LSEQ + tglob] = bi;
    }
}

// ---------------- counting sort per (bh, hash): stable, ballot-ranked ----------------
// one wave per (bh,hash) group; grid 256, block 64
__global__ __launch_bounds__(64) void k_sort(
    const int* __restrict__ buckets, int* __restrict__ sorted)
{
    __shared__ int hist[20];
    __shared__ int startl[20];
    int lane = threadIdx.x;
    int gidx = blockIdx.x;
    const int* bk = buckets + (size_t)gidx * LSEQ;
    int* dst = sorted + (size_t)gidx * LSEQ;
    if (lane < 20) hist[lane] = 0;
    __syncthreads();
    int myb[20];
    for (int ch = 0; ch < 20; ch++) {
        myb[ch] = bk[ch*64 + lane];
        atomicAdd(&hist[myb[ch]], 1);
    }
    __syncthreads();
    if (lane == 0) {
        int acc = 0;
        for (int b2 = 0; b2 < 20; b2++) { startl[b2] = acc; acc += hist[b2]; }
    }
    __syncthreads();
    unsigned long long below = (lane == 63) ? 0x7fffffffffffffffull
                                            : ((1ull << lane) - 1ull);
    for (int ch = 0; ch < 20; ch++) {
        int bv = myb[ch];
        unsigned long long mymask = 0, ownmask = 0;
        #pragma unroll
        for (int b2 = 0; b2 < 20; b2++) {
            unsigned long long m2 = __ballot(bv == b2);
            if (b2 == bv)   mymask  = m2;
            if (b2 == lane) ownmask = m2;
        }
        int rank = __popcll(mymask & below);
        int base = startl[bv];
        dst[base + rank] = ch*64 + lane;
        __syncthreads();
        if (lane < 20) startl[lane] += __popcll(ownmask);
        __syncthreads();
    }
}

// ---------------- chunked attention v7: copy-staging from pre-split arrays ----------------
// one (bh, chunk) per block; grid 5120, block 256 (4 waves)
__global__ __launch_bounds__(256) void k_attn(
    const unsigned* __restrict__ qs, const unsigned* __restrict__ ks1g,
    const unsigned* __restrict__ vs1g, const unsigned* __restrict__ vs3g,
    const int* __restrict__ sorted, float* __restrict__ o_hash, float* __restrict__ slog)
{
    __shared__ __align__(16) unsigned SMEM[13120];
    unsigned* Va1 = SMEM;              // [kt 8][dh 16][key 16 u32] kt-stride 328, dh-stride 20
    unsigned* Va2 = SMEM + 2624;
    unsigned* Va3 = SMEM + 5248;
    unsigned* Ka1 = SMEM + 7872;       // [key 128][dh 16 u32] stride 20 (phase 1)
    unsigned* Ka2 = SMEM + 10432;
    unsigned* Pa1 = SMEM + 7872;       // phase 2 alias
    unsigned* Pa2 = SMEM + 10432;
    int* kposS = (int*)(SMEM + 12992);

    int tid = threadIdx.x;
    int bh = blockIdx.x / NCHUNK;
    int c  = blockIdx.x % NCHUNK;
    int h  = c / NBUK, cc = c % NBUK;
    int cp = (c + NCHUNK - 1) % NCHUNK;
    int hp = cp / NBUK, ccp = cp % NBUK;

    int key = tid & 127;
    int pos = (key < 64)
        ? sorted[((size_t)bh*NHASH + h)*LSEQ + cc*64 + key]
        : sorted[((size_t)bh*NHASH + hp)*LSEQ + ccp*64 + (key-64)];
    size_t srow = ((size_t)bh*LSEQ + pos)*16;
    if (tid < 128) {
        kposS[key] = pos;
        const uint4* kr = (const uint4*)(ks1g + srow);
        #pragma unroll
        for (int e4=0; e4<4; e4++){
            uint4 t = kr[e4];
            *(uint4*)&Ka1[key*20 + e4*4] = t;
            uint4 rt; rt.x=rot16(t.x); rt.y=rot16(t.y); rt.z=rot16(t.z); rt.w=rot16(t.w);
            *(uint4*)&Ka2[key*20 + e4*4] = rt;
        }
    } else {
        const uint4* v1r = (const uint4*)(vs1g + srow);
        const uint4* v3r = (const uint4*)(vs3g + srow);
        int kt = key >> 4, jl = key & 15;
        int lb = kt*328 + jl;
        #pragma unroll
        for (int e4=0; e4<4; e4++){
            uint4 a = v1r[e4], cc2 = v3r[e4];
            unsigned aa[4] = {a.x,a.y,a.z,a.w};
            unsigned cb[4] = {cc2.x,cc2.y,cc2.z,cc2.w};
            #pragma unroll
            for (int i=0;i<4;i++){
                int d = e4*4 + i;
                Va1[lb + d*20] = aa[i];
                Va2[lb + d*20] = rot16(aa[i]);
                Va3[lb + d*20] = cb[i];
            }
        }
    }
    __syncthreads();

    int w = tid >> 6, lane = tid & 63;
    int quad = lane >> 4, col = lane & 15;

    // Q A-frag: direct load of pre-split [qh|ql]
    int qgpos = kposS[16*w + col];
    FU4 QA;
    QA.v = *(const uint4*)(qs + ((size_t)bh*LSEQ + qgpos)*16 + quad*4);
    frag_ab qA = QA.f;

    frag_c acc[8];
    #pragma unroll
    for (int nt=0; nt<8; nt++){
        FU4 B1, B2;
        B1.v = *(const uint4*)&Ka1[(nt*16+col)*20 + 4*quad];
        B2.v = *(const uint4*)&Ka2[(nt*16+col)*20 + 4*quad];
        frag_c a = {0.f,0.f,0.f,0.f};
        a = __builtin_amdgcn_mfma_f32_16x16x32_bf16(qA, B1.f, a, 0, 0, 0);
        a = __builtin_amdgcn_mfma_f32_16x16x32_bf16(qA, B2.f, a, 0, 0, 0);
        acc[nt] = a;
    }
    int qp[4];
    #pragma unroll
    for (int reg=0; reg<4; reg++) qp[reg] = kposS[16*w + quad*4 + reg];
    #pragma unroll
    for (int nt=0; nt<8; nt++){
        int kp2 = kposS[nt*16 + col];
        #pragma unroll
        for (int reg=0; reg<4; reg++)
            if (kp2 == qp[reg]) acc[nt][reg] = -5e4f;
    }
    float mx[4] = {-3.4e38f,-3.4e38f,-3.4e38f,-3.4e38f};
    #pragma unroll
    for (int nt=0; nt<8; nt++)
        #pragma unroll
        for (int reg=0; reg<4; reg++) mx[reg] = fmaxf(mx[reg], acc[nt][reg]);
    #pragma unroll
    for (int reg=0; reg<4; reg++){
        float m2 = mx[reg];
        m2 = fmaxf(m2, __shfl_xor(m2, 1)); m2 = fmaxf(m2, __shfl_xor(m2, 2));
        m2 = fmaxf(m2, __shfl_xor(m2, 4)); m2 = fmaxf(m2, __shfl_xor(m2, 8));
        mx[reg] = m2;
    }
    float sm2[4] = {0.f,0.f,0.f,0.f};
    #pragma unroll
    for (int nt=0; nt<8; nt++)
        #pragma unroll
        for (int reg=0; reg<4; reg++){
            float e = __expf(acc[nt][reg] - mx[reg]);
            acc[nt][reg] = e; sm2[reg] += e;
        }
    #pragma unroll
    for (int reg=0; reg<4; reg++){
        float s2 = sm2[reg];
        s2 += __shfl_xor(s2, 1); s2 += __shfl_xor(s2, 2);
        s2 += __shfl_xor(s2, 4); s2 += __shfl_xor(s2, 8);
        sm2[reg] = s2;
    }
    float invs[4];
    #pragma unroll
    for (int reg=0; reg<4; reg++) invs[reg] = 1.f / sm2[reg];
    if (col == 0) {
        #pragma unroll
        for (int reg=0; reg<4; reg++)
            slog[((size_t)bh*NHASH + h)*LSEQ + qp[reg]] = mx[reg] + __logf(sm2[reg]);
    }

    frag_c o = {0.f,0.f,0.f,0.f};
    __syncthreads();
    #pragma unroll
    for (int pass=0; pass<4; pass++){
        #pragma unroll
        for (int t2=0; t2<2; t2++){
            int nt = pass*2 + t2;
            #pragma unroll
            for (int reg=0; reg<4; reg++){
                float p = acc[nt][reg] * invs[reg];
                unsigned ph_, pm_, pl_;
                split3(p, ph_, pm_, pl_);
                int idx = t2*1280 + (16*w + 4*quad + reg)*20 + col;
                Pa1[idx] = ph_ | (pm_<<16);
                Pa2[idx] = ph_ | (pl_<<16);
            }
        }
        __syncthreads();
        #pragma unroll
        for (int t2=0; t2<2; t2++){
            int ktg = pass*2 + t2;
            FU4 A1, A2, B1, B2, B3;
            int pidx = t2*1280 + (16*w + col)*20 + 4*quad;
            A1.v = *(const uint4*)&Pa1[pidx];
            A2.v = *(const uint4*)&Pa2[pidx];
            int vidx = ktg*328 + col*20 + 4*quad;
            B1.v = *(const uint4*)&Va1[vidx];
            B2.v = *(const uint4*)&Va2[vidx];
            B3.v = *(const uint4*)&Va3[vidx];
            o = __builtin_amdgcn_mfma_f32_16x16x32_bf16(A1.f, B1.f, o, 0, 0, 0);
            o = __builtin_amdgcn_mfma_f32_16x16x32_bf16(A1.f, B2.f, o, 0, 0, 0);
            o = __builtin_amdgcn_mfma_f32_16x16x32_bf16(A2.f, B3.f, o, 0, 0, 0);
        }
        if (pass < 3) __syncthreads();
    }
    size_t obase = ((size_t)bh*NHASH + h)*LSEQ;
    #pragma unroll
    for (int reg=0; reg<4; reg++)
        o_hash[(obase + qp[reg])*DHD + col] = o[reg];
}

// ---------------- fused tail: combine + WO + residual + LN2 + W1 + gelu + W2 + residual ----------------
__global__ __launch_bounds__(256) void k_tail(
    const float* __restrict__ o_hash, const float* __restrict__ slog,
    const unsigned* __restrict__ wo_s, const float* __restrict__ wo_b,
    const float* __restrict__ g2, const float* __restrict__ b2t,
    const unsigned* __restrict__ w1_s, const float* __restrict__ b1,
    const unsigned* __restrict__ w2_s, const float* __restrict__ b2f,
    float* __restrict__ x1, float* __restrict__ x2)
{
    __shared__ unsigned SM[16384];      // 64 KB: xA1, xA2, gA1, gA2
    unsigned* xA1 = SM;
    unsigned* xA2 = SM + 4096;
    unsigned* gA1 = SM + 8192;
    unsigned* gA2 = SM + 12288;

    int tid = threadIdx.x;
    int b  = blockIdx.x / 20;
    int t0 = (blockIdx.x % 20) * 64;
    int w = tid >> 6, lane = tid & 63;
    int quad = lane >> 4, col = lane & 15;
    int t = t0 + 16*w + col;

    FU4 aA1[4], aA2[4];
    #pragma unroll
    for (int kt=0; kt<4; kt++){
        int bh = b*NHEADS + kt;
        float sl[4];
        #pragma unroll
        for (int nh=0; nh<4; nh++) sl[nh] = slog[((size_t)bh*NHASH + nh)*LSEQ + t];
        float mx = fmaxf(fmaxf(sl[0],sl[1]), fmaxf(sl[2],sl[3]));
        float wgt[4]; float wsum = 0.f;
        #pragma unroll
        for (int nh=0; nh<4; nh++){ wgt[nh] = __expf(sl[nh]-mx); wsum += wgt[nh]; }
        float iv = 1.f/wsum;
        float a4[4] = {0.f,0.f,0.f,0.f};
        #pragma unroll
        for (int nh=0; nh<4; nh++){
            float4 oh = *(const float4*)&o_hash[(((size_t)bh*NHASH + nh)*LSEQ + t)*DHD + quad*4];
            float wn = wgt[nh]*iv;
            a4[0] += wn*oh.x; a4[1] += wn*oh.y; a4[2] += wn*oh.z; a4[3] += wn*oh.w;
        }
        #pragma unroll
        for (int i=0;i<4;i++){
            unsigned h_, m_, l_;
            split3(a4[i], h_, m_, l_);
            ((unsigned*)&aA1[kt].v)[i] = h_ | (m_<<16);
            ((unsigned*)&aA2[kt].v)[i] = h_ | (l_<<16);
        }
    }

    frag_c awo[4];
    #pragma unroll
    for (int nt=0; nt<4; nt++){
        frag_c a = {0.f,0.f,0.f,0.f};
        #pragma unroll
        for (int kt=0; kt<4; kt++){
            FU4 B1, B2, B3;
            int bidx = ((kt*4 + nt)*16 + col)*16 + quad*4;
            B1.v = *(const uint4*)&wo_s[bidx];
            B2.v = *(const uint4*)&wo_s[bidx + 4096];
            B3.v = *(const uint4*)&wo_s[bidx + 8192];
            a = __builtin_amdgcn_mfma_f32_16x16x32_bf16(aA1[kt].f, B1.f, a, 0, 0, 0);
            a = __builtin_amdgcn_mfma_f32_16x16x32_bf16(aA1[kt].f, B2.f, a, 0, 0, 0);
            a = __builtin_amdgcn_mfma_f32_16x16x32_bf16(aA2[kt].f, B3.f, a, 0, 0, 0);
        }
        awo[nt] = a;
    }
    float x1n[4][4];
    float s1[4] = {0,0,0,0}, s2[4] = {0,0,0,0};
    #pragma unroll
    for (int nt=0; nt<4; nt++){
        float wb = wo_b[nt*16 + col];
        #pragma unroll
        for (int reg=0; reg<4; reg++){
            int rg = t0 + 16*w + quad*4 + reg;
            size_t xi = ((size_t)b*LSEQ + rg)*DM + nt*16 + col;
            float xv = x1[xi] + awo[nt][reg] + wb;
            x1[xi] = xv;
            x1n[nt][reg] = xv;
            s1[reg] += xv; s2[reg] += xv*xv;
        }
    }
    #pragma unroll
    for (int reg=0; reg<4; reg++){
        float a = s1[reg], q = s2[reg];
        a += __shfl_xor(a,1); a += __shfl_xor(a,2); a += __shfl_xor(a,4); a += __shfl_xor(a,8);
        q += __shfl_xor(q,1); q += __shfl_xor(q,2); q += __shfl_xor(q,4); q += __shfl_xor(q,8);
        s1[reg] = a; s2[reg] = q;
    }
    float rstd[4], mean[4];
    #pragma unroll
    for (int reg=0; reg<4; reg++){
        mean[reg] = s1[reg]*(1.f/64.f);
        float var = s2[reg]*(1.f/64.f) - mean[reg]*mean[reg];
        rstd[reg] = 1.f/sqrtf(var + 1e-5f);
    }
    #pragma unroll
    for (int nt=0; nt<4; nt++){
        int d = nt*16 + col;
        float gv = g2[d], bv = b2t[d];
        #pragma unroll
        for (int reg=0; reg<4; reg++){
            int row = 16*w + quad*4 + reg;
            float xv = (x1n[nt][reg]-mean[reg])*rstd[reg]*gv + bv;
            unsigned h_, m_, l_;
            split3(xv, h_, m_, l_);
            int word = d ^ ((row & 7) << 2);
            xA1[row*64 + word] = h_ | (m_<<16);
            xA2[row*64 + word] = h_ | (l_<<16);
        }
    }

    FU4 xa1[4], xa2[4];
    {
        int arow = 16*w + col;
        int sw = (col & 7) << 2;
        #pragma unroll
        for (int kt=0; kt<4; kt++){
            int word = (kt*16 + quad*4) ^ sw;
            xa1[kt].v = *(const uint4*)&xA1[arow*64 + word];
            xa2[kt].v = *(const uint4*)&xA2[arow*64 + word];
        }
    }

    frag_c aw2[4] = {{0,0,0,0},{0,0,0,0},{0,0,0,0},{0,0,0,0}};
    for (int ch = 0; ch < 4; ch++){
        #pragma unroll
        for (int ntl=0; ntl<4; ntl++){
            int nt = ch*4 + ntl;
            frag_c a = {0.f,0.f,0.f,0.f};
            #pragma unroll
            for (int kt=0; kt<4; kt++){
                FU4 B1, B2, B3;
                int bidx = ((kt*16 + nt)*16 + col)*16 + quad*4;
                B1.v = *(const uint4*)&w1_s[bidx];
                B2.v = *(const uint4*)&w1_s[bidx + 16384];
                B3.v = *(const uint4*)&w1_s[bidx + 32768];
                a = __builtin_amdgcn_mfma_f32_16x16x32_bf16(xa1[kt].f, B1.f, a, 0, 0, 0);
                a = __builtin_amdgcn_mfma_f32_16x16x32_bf16(xa1[kt].f, B2.f, a, 0, 0, 0);
                a = __builtin_amdgcn_mfma_f32_16x16x32_bf16(xa2[kt].f, B3.f, a, 0, 0, 0);
            }
            float bb = b1[nt*16 + col];
            #pragma unroll
            for (int reg=0; reg<4; reg++){
                float xx = a[reg] + bb;
                float ge = 0.5f*xx*(1.f + erff(xx*0.70710678118654752f));
                unsigned h_, m_, l_;
                split3(ge, h_, m_, l_);
                int row = 16*w + quad*4 + reg;
                int word = (ntl*16 + col) ^ ((row & 7) << 2);
                gA1[row*64 + word] = h_ | (m_<<16);
                gA2[row*64 + word] = h_ | (l_<<16);
            }
        }
        int arow = 16*w + col;
        int sw = (col & 7) << 2;
        #pragma unroll
        for (int kt2=0; kt2<4; kt2++){
            FU4 A1, A2;
            int word = (kt2*16 + quad*4) ^ sw;
            A1.v = *(const uint4*)&gA1[arow*64 + word];
            A2.v = *(const uint4*)&gA2[arow*64 + word];
            int kg = ch*4 + kt2;
            #pragma unroll
            for (int nt2=0; nt2<4; nt2++){
                FU4 B1, B2, B3;
                int bidx = ((kg*4 + nt2)*16 + col)*16 + quad*4;
                B1.v = *(const uint4*)&w2_s[bidx];
                B2.v = *(const uint4*)&w2_s[bidx + 16384];
                B3.v = *(const uint4*)&w2_s[bidx + 32768];
                aw2[nt2] = __builtin_amdgcn_mfma_f32_16x16x32_bf16(A1.f, B1.f, aw2[nt2], 0, 0, 0);
                aw2[nt2] = __builtin_amdgcn_mfma_f32_16x16x32_bf16(A1.f, B2.f, aw2[nt2], 0, 0, 0);
                aw2[nt2] = __builtin_amdgcn_mfma_f32_16x16x32_bf16(A2.f, B3.f, aw2[nt2], 0, 0, 0);
            }
        }
    }

    #pragma unroll
    for (int nt=0; nt<4; nt++){
        float bb = b2f[nt*16 + col];
        #pragma unroll
        for (int reg=0; reg<4; reg++){
            int rg = t0 + 16*w + quad*4 + reg;
            size_t xi = ((size_t)b*LSEQ + rg)*DM + nt*16 + col;
            x2[xi] += aw2[nt][reg] + bb;
        }
    }
}

// ---------------- output proj: y = 0.5*(x1+x2) @ out_w + out_b, crop to 1250 ----------------
__global__ __launch_bounds__(256) void k_out(
    const float* __restrict__ x1, const float* __restrict__ x2,
    const float* __restrict__ out_w, const float* __restrict__ out_b, float* __restrict__ y)
{
    int idx = blockIdx.x * 256 + threadIdx.x;
    if (idx >= NBATCH * L0SEQ) return;
    int b = idx / L0SEQ, t = idx % L0SEQ;
    const float* r1 = x1 + ((size_t)b*LSEQ + t)*DM;
    const float* r2 = x2 + ((size_t)b*LSEQ + t)*DM;
    float s = 0.f;
    for (int d = 0; d < DM; d++) s += (r1[d]+r2[d])*0.5f*out_w[d];
    y[idx] = s + out_b[0];
}

extern "C" void kernel_launch(void* const* d_in, const int* in_sizes, int n_in,
                              void* d_out, int out_size, void* d_ws, size_t ws_size,
                              hipStream_t stream)
{
    const float* wave  = (const float*)d_in[0];
    const float* in_w  = (const float*)d_in[1];
    const float* in_b  = (const float*)d_in[2];
    const float* ln1_g = (const float*)d_in[3];
    const float* ln1_b = (const float*)d_in[4];
    const float* wqk   = (const float*)d_in[5];
    const float* wv    = (const float*)d_in[6];
    const float* wo_w  = (const float*)d_in[7];
    const float* wo_b  = (const float*)d_in[8];
    const float* rot   = (const float*)d_in[9];
    const float* ln2_g = (const float*)d_in[10];
    const float* ln2_b = (const float*)d_in[11];
    const float* w1    = (const float*)d_in[12];
    const float* b1    = (const float*)d_in[13];
    const float* w2    = (const float*)d_in[14];
    const float* b2    = (const float*)d_in[15];
    const float* out_w = (const float*)d_in[16];
    const float* out_b = (const float*)d_in[17];
    float* y = (float*)d_out;

    float* ws = (float*)d_ws;
    float* x1      = ws;                       // XSZ f32
    float* x2      = x1 + XSZ;                 // XSZ f32
    unsigned* qs   = (unsigned*)(x2 + XSZ);    // QKSZ u32
    unsigned* ks1  = qs  + QKSZ;               // QKSZ u32
    unsigned* vs1  = ks1 + QKSZ;               // QKSZ u32
    unsigned* vs3  = vs1 + QKSZ;               // QKSZ u32
    float* o_hash  = (float*)(vs3 + QKSZ);     // OHSZ f32
    float* slogb   = o_hash + OHSZ;            // SLSZ f32
    int* buckets   = (int*)(slogb + SLSZ);     // SLSZ int
    int* sorted    = buckets + SLSZ;           // SLSZ int
    unsigned* wsplit = (unsigned*)(sorted + SLSZ); // 442368 u32

    k_prep<<<576, 256, 0, stream>>>(wo_w, w1, w2, wsplit);
    k_embed<<<XSZ/256, 256, 0, stream>>>(wave, in_w, in_b, x1, x2);
    for (int layer = 0; layer < 4; layer++) {
        k_qkv<<<320, 256, 0, stream>>>(x2, ln1_g + layer*64, ln1_b + layer*64,
                                       wqk + layer*4096, wv + layer*4096, rot + layer*640,
                                       qs, ks1, vs1, vs3, buckets);
        k_sort<<<256, 64, 0, stream>>>(buckets, sorted);
        k_attn<<<NBH*NCHUNK, 256, 0, stream>>>(qs, ks1, vs1, vs3, sorted, o_hash, slogb);
        k_tail<<<320, 256, 0, stream>>>(o_hash, slogb,
                                        wsplit + layer*12288, wo_b + layer*64,
                                        ln2_g + layer*64, ln2_b + layer*64,
                                        wsplit + 49152 + layer*49152, b1 + layer*256,
                                        wsplit + 245760 + layer*49152, b2 + layer*64,
                                        x1, x2);
    }
    k_out<<<(NBATCH*L0SEQ + 255)/256, 256, 0, stream>>>(x1, x2, out_w, out_b, y);
}

// Round 9
// 639.683 us; speedup vs baseline: 1.0792x; 1.0792x over previous
//
#include <hip/hip_runtime.h>
#include <math.h>

#define LSEQ 1280
#define L0SEQ 1250
#define DM 64
#define NHEADS 4
#define DHD 16
#define NHASH 4
#define NBUK 20
#define NCHUNK 80
#define FFD 256
#define NBATCH 16
#define NBH 64

#define XSZ (NBATCH*LSEQ*DM)        // 1310720
#define QKSZ (NBH*LSEQ*DHD)         // 1310720
#define OHSZ (NBH*NHASH*LSEQ*DHD)   // 5242880
#define SLSZ (NBH*NHASH*LSEQ)       // 327680

typedef __attribute__((ext_vector_type(8))) short frag_ab;   // 8 bf16
typedef __attribute__((ext_vector_type(4))) float frag_c;    // 4 fp32

union FU4 { uint4 v; frag_ab f; };

// round-to-nearest-even bf16 (returns low 16 bits)
__device__ __forceinline__ unsigned rnbf(float x){
    unsigned b = __float_as_uint(x);
    return (b + 0x7fffu + ((b >> 16) & 1u)) >> 16;
}
__device__ __forceinline__ float bf2f(unsigned h){ return __uint_as_float(h << 16); }
__device__ __forceinline__ unsigned rot16(unsigned x){ return (x >> 16) | (x << 16); }

// exact triple split (truncation): x = h + m + l
__device__ __forceinline__ void split3(float x, unsigned& h, unsigned& m, unsigned& l){
    unsigned bx = __float_as_uint(x);
    h = bx >> 16;
    float r = x - __uint_as_float(bx & 0xffff0000u);
    unsigned br = __float_as_uint(r);
    m = br >> 16;
    float r2 = r - __uint_as_float(br & 0xffff0000u);
    l = __float_as_uint(r2) >> 16;
}

// ---------------- embed: x = pad(wave^T) @ in_w + in_b ----------------
__global__ __launch_bounds__(256) void k_embed(
    const float* __restrict__ wave, const float* __restrict__ in_w,
    const float* __restrict__ in_b, float* __restrict__ x1, float* __restrict__ x2)
{
    int idx = blockIdx.x * 256 + threadIdx.x;   // over B*L*D
    int d = idx & 63;
    int t = idx >> 6;
    int b = t / LSEQ;
    int tt = t % LSEQ;
    float v0 = 0.f, v1 = 0.f;
    if (tt < L0SEQ) {
        v0 = wave[(size_t)(b*2+0)*L0SEQ + tt];
        v1 = wave[(size_t)(b*2+1)*L0SEQ + tt];
    }
    float x = v0 * in_w[d] + v1 * in_w[64 + d] + in_b[d];
    x1[idx] = x;
    x2[idx] = x;
}

// ---------------- weight pre-split into MFMA-B layout (trunc-3, k-slot paired) ----------------
__global__ __launch_bounds__(256) void k_prep(
    const float* __restrict__ wo_w, const float* __restrict__ w1,
    const float* __restrict__ w2, unsigned* __restrict__ wsplit)
{
    int gid = blockIdx.x * 256 + threadIdx.x;
    if (gid >= 4*36864) return;
    int l = gid / 36864;
    int r = gid % 36864;
    float src; unsigned* dst; int idx; int stride;
    if (r < 4096) {                 // wo: K=64, N=64
        int k = r >> 6, n = r & 63;
        src = wo_w[l*4096 + k*64 + n];
        dst = wsplit + l*12288;
        idx = (((k>>4)*4 + (n>>4))*16 + (n&15))*16 + (k&15);
        stride = 4096;
    } else if (r < 20480) {         // w1: K=64, N=256
        int rr = r - 4096;
        int k = rr >> 8, n = rr & 255;
        src = w1[l*16384 + k*256 + n];
        dst = wsplit + 49152 + l*49152;
        idx = (((k>>4)*16 + (n>>4))*16 + (n&15))*16 + (k&15);
        stride = 16384;
    } else {                        // w2: K=256, N=64
        int rr = r - 20480;
        int k = rr >> 6, n = rr & 63;
        src = w2[l*16384 + k*64 + n];
        dst = wsplit + 245760 + l*49152;
        idx = (((k>>4)*4 + (n>>4))*16 + (n&15))*16 + (k&15);
        stride = 16384;
    }
    unsigned h, m, lo;
    split3(src, h, m, lo);
    dst[idx]            = h | (m<<16);
    dst[idx + stride]   = m | (h<<16);
    dst[idx + 2*stride] = lo | (h<<16);
}

// ---------------- LN + QK/V projection + LSH bucketing + PRE-SPLIT q/k/v ----------------
// block = 64 tokens of one batch; grid 320
__global__ __launch_bounds__(256) void k_qkv(
    const float* __restrict__ x2, const float* __restrict__ g, const float* __restrict__ bta,
    const float* __restrict__ wqk, const float* __restrict__ wv, const float* __restrict__ rot,
    unsigned* __restrict__ qs, unsigned* __restrict__ ks1,
    unsigned* __restrict__ vs1, unsigned* __restrict__ vs3, int* __restrict__ buckets)
{
    __shared__ float xln[64][65];
    __shared__ float qkt[64][65];
    __shared__ float vvt[64][65];
    __shared__ float rots[640];
    __shared__ float psum[64][4];
    __shared__ float psq[64][4];
    int tid = threadIdx.x;
    int b  = blockIdx.x / 20;
    int t0 = (blockIdx.x % 20) * 64;
    const float* xbase = x2 + (size_t)(b*LSEQ + t0)*DM;
    int r = tid >> 2, qq = tid & 3;
    float vals[16];
    float s = 0.f, ss = 0.f;
    for (int i = 0; i < 16; i++) {
        float vv = xbase[r*DM + qq*16 + i];
        vals[i] = vv; s += vv; ss += vv*vv;
    }
    psum[r][qq] = s; psq[r][qq] = ss;
    for (int i = tid; i < 640; i += 256) rots[i] = rot[i];
    __syncthreads();
    float m  = (psum[r][0]+psum[r][1]+psum[r][2]+psum[r][3]) * (1.f/64.f);
    float vr = (psq[r][0]+psq[r][1]+psq[r][2]+psq[r][3]) * (1.f/64.f) - m*m;
    float rstd = 1.f / sqrtf(vr + 1e-5f);
    for (int i = 0; i < 16; i++) {
        int c = qq*16 + i;
        xln[r][c] = (vals[i]-m)*rstd*g[c] + bta[c];
    }
    __syncthreads();
    int cg = tid & 15, tg = tid >> 4;
    int c0 = cg*4, tl0 = tg*4;
    float aq[4][4], av[4][4];
    for (int i=0;i<4;i++) for (int j=0;j<4;j++){ aq[i][j]=0.f; av[i][j]=0.f; }
    for (int f = 0; f < 64; f++) {
        float4 wq4 = *(const float4*)&wqk[f*64 + c0];
        float4 wv4 = *(const float4*)&wv [f*64 + c0];
        float xv[4];
        for (int i=0;i<4;i++) xv[i] = xln[tl0+i][f];
        for (int i=0;i<4;i++) {
            aq[i][0] += xv[i]*wq4.x; aq[i][1] += xv[i]*wq4.y;
            aq[i][2] += xv[i]*wq4.z; aq[i][3] += xv[i]*wq4.w;
            av[i][0] += xv[i]*wv4.x; av[i][1] += xv[i]*wv4.y;
            av[i][2] += xv[i]*wv4.z; av[i][3] += xv[i]*wv4.w;
        }
    }
    for (int i=0;i<4;i++) {
        qkt[tl0+i][c0+0] = aq[i][0]; qkt[tl0+i][c0+1] = aq[i][1];
        qkt[tl0+i][c0+2] = aq[i][2]; qkt[tl0+i][c0+3] = aq[i][3];
        vvt[tl0+i][c0+0] = av[i][0]; vvt[tl0+i][c0+1] = av[i][1];
        vvt[tl0+i][c0+2] = av[i][2]; vvt[tl0+i][c0+3] = av[i][3];
    }
    __syncthreads();
    int ttk = tid >> 2, hh = tid & 3;
    float qf[16], vf[16];
    for (int f=0; f<16; f++) qf[f] = qkt[ttk][hh*16+f];
    for (int f=0; f<16; f++) vf[f] = vvt[ttk][hh*16+f];
    int tglob = t0 + ttk;
    size_t sb = (((size_t)(b*NHEADS+hh))*LSEQ + tglob)*16;
    float nsq = 0.f;
    for (int e=0; e<16; e++) nsq += qf[e]*qf[e];
    float inv = 1.f / fmaxf(sqrtf(nsq), 1e-12f);
    unsigned wq[16], wk[16], wv1[16], wv3[16];
    #pragma unroll
    for (int e=0; e<16; e++){
        float xq = qf[e]*0.25f;
        unsigned qh = rnbf(xq);
        unsigned ql = rnbf(xq - bf2f(qh));
        wq[e] = qh | (ql<<16);
        float xk = qf[e]*inv;
        unsigned kh = rnbf(xk);
        unsigned kl = rnbf(xk - bf2f(kh));
        wk[e] = kh | (kl<<16);
        unsigned vh_, vm_, vl_;
        split3(vf[e], vh_, vm_, vl_);
        wv1[e] = vh_ | (vm_<<16);
        wv3[e] = vl_ | (vh_<<16);
    }
    #pragma unroll
    for (int e4=0; e4<4; e4++){
        *(uint4*)&qs [sb + e4*4] = *(uint4*)&wq [e4*4];
        *(uint4*)&ks1[sb + e4*4] = *(uint4*)&wk [e4*4];
        *(uint4*)&vs1[sb + e4*4] = *(uint4*)&wv1[e4*4];
        *(uint4*)&vs3[sb + e4*4] = *(uint4*)&wv3[e4*4];
    }
    for (int nh = 0; nh < NHASH; nh++) {
        float rv[10];
        for (int i=0;i<10;i++) {
            float acc = 0.f;
            for (int f=0; f<16; f++) acc += qf[f]*rots[(f*NHASH+nh)*10 + i];
            rv[i] = acc;
        }
        float best = rv[0]; int bi = 0;
        for (int i=1;i<10;i++) if (rv[i] > best) { best = rv[i]; bi = i; }
        for (int i=0;i<10;i++) if (-rv[i] > best) { best = -rv[i]; bi = 10+i; }
        buckets[((size_t)(b*NHEADS+hh)*NHASH + nh)*LSEQ + tglob] = bi;
    }
}

// ---------------- counting sort per (bh, hash): stable, ballot-ranked ----------------
__global__ __launch_bounds__(64) void k_sort(
    const int* __restrict__ buckets, int* __restrict__ sorted)
{
    __shared__ int hist[20];
    __shared__ int startl[20];
    int lane = threadIdx.x;
    int gidx = blockIdx.x;
    const int* bk = buckets + (size_t)gidx * LSEQ;
    int* dst = sorted + (size_t)gidx * LSEQ;
    if (lane < 20) hist[lane] = 0;
    __syncthreads();
    int myb[20];
    for (int ch = 0; ch < 20; ch++) {
        myb[ch] = bk[ch*64 + lane];
        atomicAdd(&hist[myb[ch]], 1);
    }
    __syncthreads();
    if (lane == 0) {
        int acc = 0;
        for (int b2 = 0; b2 < 20; b2++) { startl[b2] = acc; acc += hist[b2]; }
    }
    __syncthreads();
    unsigned long long below = (lane == 63) ? 0x7fffffffffffffffull
                                            : ((1ull << lane) - 1ull);
    for (int ch = 0; ch < 20; ch++) {
        int bv = myb[ch];
        unsigned long long mymask = 0, ownmask = 0;
        #pragma unroll
        for (int b2 = 0; b2 < 20; b2++) {
            unsigned long long m2 = __ballot(bv == b2);
            if (b2 == bv)   mymask  = m2;
            if (b2 == lane) ownmask = m2;
        }
        int rank = __popcll(mymask & below);
        int base = startl[bv];
        dst[base + rank] = ch*64 + lane;
        __syncthreads();
        if (lane < 20) startl[lane] += __popcll(ownmask);
        __syncthreads();
    }
}

// ---------------- chunked attention: copy-staging from pre-split arrays ----------------
__global__ __launch_bounds__(256) void k_attn(
    const unsigned* __restrict__ qs, const unsigned* __restrict__ ks1g,
    const unsigned* __restrict__ vs1g, const unsigned* __restrict__ vs3g,
    const int* __restrict__ sorted, float* __restrict__ o_hash, float* __restrict__ slog)
{
    __shared__ __align__(16) unsigned SMEM[13120];
    unsigned* Va1 = SMEM;
    unsigned* Va2 = SMEM + 2624;
    unsigned* Va3 = SMEM + 5248;
    unsigned* Ka1 = SMEM + 7872;
    unsigned* Ka2 = SMEM + 10432;
    unsigned* Pa1 = SMEM + 7872;
    unsigned* Pa2 = SMEM + 10432;
    int* kposS = (int*)(SMEM + 12992);

    int tid = threadIdx.x;
    int bh = blockIdx.x / NCHUNK;
    int c  = blockIdx.x % NCHUNK;
    int h  = c / NBUK, cc = c % NBUK;
    int cp = (c + NCHUNK - 1) % NCHUNK;
    int hp = cp / NBUK, ccp = cp % NBUK;

    int key = tid & 127;
    int pos = (key < 64)
        ? sorted[((size_t)bh*NHASH + h)*LSEQ + cc*64 + key]
        : sorted[((size_t)bh*NHASH + hp)*LSEQ + ccp*64 + (key-64)];
    size_t srow = ((size_t)bh*LSEQ + pos)*16;
    if (tid < 128) {
        kposS[key] = pos;
        const uint4* kr = (const uint4*)(ks1g + srow);
        #pragma unroll
        for (int e4=0; e4<4; e4++){
            uint4 t = kr[e4];
            *(uint4*)&Ka1[key*20 + e4*4] = t;
            uint4 rt; rt.x=rot16(t.x); rt.y=rot16(t.y); rt.z=rot16(t.z); rt.w=rot16(t.w);
            *(uint4*)&Ka2[key*20 + e4*4] = rt;
        }
    } else {
        const uint4* v1r = (const uint4*)(vs1g + srow);
        const uint4* v3r = (const uint4*)(vs3g + srow);
        int kt = key >> 4, jl = key & 15;
        int lb = kt*328 + jl;
        #pragma unroll
        for (int e4=0; e4<4; e4++){
            uint4 a = v1r[e4], cc2 = v3r[e4];
            unsigned aa[4] = {a.x,a.y,a.z,a.w};
            unsigned cb[4] = {cc2.x,cc2.y,cc2.z,cc2.w};
            #pragma unroll
            for (int i=0;i<4;i++){
                int d = e4*4 + i;
                Va1[lb + d*20] = aa[i];
                Va2[lb + d*20] = rot16(aa[i]);
                Va3[lb + d*20] = cb[i];
            }
        }
    }
    __syncthreads();

    int w = tid >> 6, lane = tid & 63;
    int quad = lane >> 4, col = lane & 15;

    int qgpos = kposS[16*w + col];
    FU4 QA;
    QA.v = *(const uint4*)(qs + ((size_t)bh*LSEQ + qgpos)*16 + quad*4);
    frag_ab qA = QA.f;

    frag_c acc[8];
    #pragma unroll
    for (int nt=0; nt<8; nt++){
        FU4 B1, B2;
        B1.v = *(const uint4*)&Ka1[(nt*16+col)*20 + 4*quad];
        B2.v = *(const uint4*)&Ka2[(nt*16+col)*20 + 4*quad];
        frag_c a = {0.f,0.f,0.f,0.f};
        a = __builtin_amdgcn_mfma_f32_16x16x32_bf16(qA, B1.f, a, 0, 0, 0);
        a = __builtin_amdgcn_mfma_f32_16x16x32_bf16(qA, B2.f, a, 0, 0, 0);
        acc[nt] = a;
    }
    int qp[4];
    #pragma unroll
    for (int reg=0; reg<4; reg++) qp[reg] = kposS[16*w + quad*4 + reg];
    #pragma unroll
    for (int nt=0; nt<8; nt++){
        int kp2 = kposS[nt*16 + col];
        #pragma unroll
        for (int reg=0; reg<4; reg++)
            if (kp2 == qp[reg]) acc[nt][reg] = -5e4f;
    }
    float mx[4] = {-3.4e38f,-3.4e38f,-3.4e38f,-3.4e38f};
    #pragma unroll
    for (int nt=0; nt<8; nt++)
        #pragma unroll
        for (int reg=0; reg<4; reg++) mx[reg] = fmaxf(mx[reg], acc[nt][reg]);
    #pragma unroll
    for (int reg=0; reg<4; reg++){
        float m2 = mx[reg];
        m2 = fmaxf(m2, __shfl_xor(m2, 1)); m2 = fmaxf(m2, __shfl_xor(m2, 2));
        m2 = fmaxf(m2, __shfl_xor(m2, 4)); m2 = fmaxf(m2, __shfl_xor(m2, 8));
        mx[reg] = m2;
    }
    float sm2[4] = {0.f,0.f,0.f,0.f};
    #pragma unroll
    for (int nt=0; nt<8; nt++)
        #pragma unroll
        for (int reg=0; reg<4; reg++){
            float e = __expf(acc[nt][reg] - mx[reg]);
            acc[nt][reg] = e; sm2[reg] += e;
        }
    #pragma unroll
    for (int reg=0; reg<4; reg++){
        float s2 = sm2[reg];
        s2 += __shfl_xor(s2, 1); s2 += __shfl_xor(s2, 2);
        s2 += __shfl_xor(s2, 4); s2 += __shfl_xor(s2, 8);
        sm2[reg] = s2;
    }
    float invs[4];
    #pragma unroll
    for (int reg=0; reg<4; reg++) invs[reg] = 1.f / sm2[reg];
    if (col == 0) {
        #pragma unroll
        for (int reg=0; reg<4; reg++)
            slog[((size_t)bh*NHASH + h)*LSEQ + qp[reg]] = mx[reg] + __logf(sm2[reg]);
    }

    frag_c o = {0.f,0.f,0.f,0.f};
    __syncthreads();
    #pragma unroll
    for (int pass=0; pass<4; pass++){
        #pragma unroll
        for (int t2=0; t2<2; t2++){
            int nt = pass*2 + t2;
            #pragma unroll
            for (int reg=0; reg<4; reg++){
                float p = acc[nt][reg] * invs[reg];
                unsigned ph_, pm_, pl_;
                split3(p, ph_, pm_, pl_);
                int idx = t2*1280 + (16*w + 4*quad + reg)*20 + col;
                Pa1[idx] = ph_ | (pm_<<16);
                Pa2[idx] = ph_ | (pl_<<16);
            }
        }
        __syncthreads();
        #pragma unroll
        for (int t2=0; t2<2; t2++){
            int ktg = pass*2 + t2;
            FU4 A1, A2, B1, B2, B3;
            int pidx = t2*1280 + (16*w + col)*20 + 4*quad;
            A1.v = *(const uint4*)&Pa1[pidx];
            A2.v = *(const uint4*)&Pa2[pidx];
            int vidx = ktg*328 + col*20 + 4*quad;
            B1.v = *(const uint4*)&Va1[vidx];
            B2.v = *(const uint4*)&Va2[vidx];
            B3.v = *(const uint4*)&Va3[vidx];
            o = __builtin_amdgcn_mfma_f32_16x16x32_bf16(A1.f, B1.f, o, 0, 0, 0);
            o = __builtin_amdgcn_mfma_f32_16x16x32_bf16(A1.f, B2.f, o, 0, 0, 0);
            o = __builtin_amdgcn_mfma_f32_16x16x32_bf16(A2.f, B3.f, o, 0, 0, 0);
        }
        if (pass < 3) __syncthreads();
    }
    size_t obase = ((size_t)bh*NHASH + h)*LSEQ;
    #pragma unroll
    for (int reg=0; reg<4; reg++)
        o_hash[(obase + qp[reg])*DHD + col] = o[reg];
}

// ---------------- fused tail v2: 16-token blocks, 4 waves cooperate; grid 1280 ----------------
// wave w: WO nt=w; W1 cols [64w,64w+64) + gelu (private gmid); W2 K-quarter [64w,64w+64)
// partials reduced across waves in LDS; wave w finalizes x2 cols [16w,16w+16).
__global__ __launch_bounds__(256) void k_tail(
    const float* __restrict__ o_hash, const float* __restrict__ slog,
    const unsigned* __restrict__ wo_s, const float* __restrict__ wo_b,
    const float* __restrict__ g2, const float* __restrict__ b2t,
    const unsigned* __restrict__ w1_s, const float* __restrict__ b1,
    const unsigned* __restrict__ w2_s, const float* __restrict__ b2f,
    float* __restrict__ x1, float* __restrict__ x2)
{
    __shared__ unsigned xA1[1024], xA2[1024];   // 16 rows x 64 words (xor-swizzled)
    __shared__ unsigned gA1[4096], gA2[4096];   // per-wave private 1024-u32 quarters
    __shared__ float lnS[64], lnQ[64];          // [w][tok]
    float* red = (float*)gA1;                   // aliased after W2 MFMAs (16 KB = 4096 floats)

    int tid = threadIdx.x;
    int b  = blockIdx.x / 80;
    int t0 = (blockIdx.x % 80) * 16;
    int w = tid >> 6, lane = tid & 63;
    int quad = lane >> 4, col = lane & 15;
    int tA = t0 + col;                          // A-layout row token

    // ---- combine across hash rounds -> WO A-frags (redundant per wave, tiny) ----
    FU4 aA1[4], aA2[4];
    #pragma unroll
    for (int kt=0; kt<4; kt++){
        int bh = b*NHEADS + kt;
        float sl[4];
        #pragma unroll
        for (int nh=0; nh<4; nh++) sl[nh] = slog[((size_t)bh*NHASH + nh)*LSEQ + tA];
        float mx = fmaxf(fmaxf(sl[0],sl[1]), fmaxf(sl[2],sl[3]));
        float wgt[4]; float wsum = 0.f;
        #pragma unroll
        for (int nh=0; nh<4; nh++){ wgt[nh] = __expf(sl[nh]-mx); wsum += wgt[nh]; }
        float iv = 1.f/wsum;
        float a4[4] = {0.f,0.f,0.f,0.f};
        #pragma unroll
        for (int nh=0; nh<4; nh++){
            float4 oh = *(const float4*)&o_hash[(((size_t)bh*NHASH + nh)*LSEQ + tA)*DHD + quad*4];
            float wn = wgt[nh]*iv;
            a4[0] += wn*oh.x; a4[1] += wn*oh.y; a4[2] += wn*oh.z; a4[3] += wn*oh.w;
        }
        #pragma unroll
        for (int i=0;i<4;i++){
            unsigned h_, m_, l_;
            split3(a4[i], h_, m_, l_);
            ((unsigned*)&aA1[kt].v)[i] = h_ | (m_<<16);
            ((unsigned*)&aA2[kt].v)[i] = h_ | (l_<<16);
        }
    }

    // ---- WO: this wave's N-tile (nt = w) ----
    frag_c awo = {0.f,0.f,0.f,0.f};
    #pragma unroll
    for (int kt=0; kt<4; kt++){
        FU4 B1, B2, B3;
        int bidx = ((kt*4 + w)*16 + col)*16 + quad*4;
        B1.v = *(const uint4*)&wo_s[bidx];
        B2.v = *(const uint4*)&wo_s[bidx + 4096];
        B3.v = *(const uint4*)&wo_s[bidx + 8192];
        awo = __builtin_amdgcn_mfma_f32_16x16x32_bf16(aA1[kt].f, B1.f, awo, 0, 0, 0);
        awo = __builtin_amdgcn_mfma_f32_16x16x32_bf16(aA1[kt].f, B2.f, awo, 0, 0, 0);
        awo = __builtin_amdgcn_mfma_f32_16x16x32_bf16(aA2[kt].f, B3.f, awo, 0, 0, 0);
    }
    // C layout: row = quad*4+reg (token), col_out = w*16 + col
    int cg = w*16 + col;
    float x1n[4];
    float s1[4], s2[4];
    {
        float wb = wo_b[cg];
        #pragma unroll
        for (int reg=0; reg<4; reg++){
            int rg = t0 + quad*4 + reg;
            size_t xi = ((size_t)b*LSEQ + rg)*DM + cg;
            float xv = x1[xi] + awo[reg] + wb;
            x1[xi] = xv;
            x1n[reg] = xv;
            s1[reg] = xv; s2[reg] = xv*xv;
        }
    }
    // per-token partial over this wave's 16 cols
    #pragma unroll
    for (int reg=0; reg<4; reg++){
        float a = s1[reg], q = s2[reg];
        a += __shfl_xor(a,1); a += __shfl_xor(a,2); a += __shfl_xor(a,4); a += __shfl_xor(a,8);
        q += __shfl_xor(q,1); q += __shfl_xor(q,2); q += __shfl_xor(q,4); q += __shfl_xor(q,8);
        s1[reg] = a; s2[reg] = q;
    }
    if (col == 0) {
        #pragma unroll
        for (int reg=0; reg<4; reg++){
            lnS[w*16 + quad*4 + reg] = s1[reg];
            lnQ[w*16 + quad*4 + reg] = s2[reg];
        }
    }
    __syncthreads();
    float mean[4], rstd[4];
    #pragma unroll
    for (int reg=0; reg<4; reg++){
        int tok = quad*4 + reg;
        float a = lnS[tok] + lnS[16+tok] + lnS[32+tok] + lnS[48+tok];
        float q = lnQ[tok] + lnQ[16+tok] + lnQ[32+tok] + lnQ[48+tok];
        mean[reg] = a*(1.f/64.f);
        float var = q*(1.f/64.f) - mean[reg]*mean[reg];
        rstd[reg] = 1.f/sqrtf(var + 1e-5f);
    }
    // LN apply + split -> xA (this wave's 16 cols)
    {
        float gv = g2[cg], bv = b2t[cg];
        #pragma unroll
        for (int reg=0; reg<4; reg++){
            int row = quad*4 + reg;
            float xv = (x1n[reg]-mean[reg])*rstd[reg]*gv + bv;
            unsigned h_, m_, l_;
            split3(xv, h_, m_, l_);
            int word = cg ^ ((row & 7) << 2);
            xA1[row*64 + word] = h_ | (m_<<16);
            xA2[row*64 + word] = h_ | (l_<<16);
        }
    }
    __syncthreads();
    // hoist W1 A-frags (full K=64, same for all waves)
    FU4 xa1[4], xa2[4];
    {
        int sw = (col & 7) << 2;
        #pragma unroll
        for (int kt=0; kt<4; kt++){
            int word = (kt*16 + quad*4) ^ sw;
            xa1[kt].v = *(const uint4*)&xA1[col*64 + word];
            xa2[kt].v = *(const uint4*)&xA2[col*64 + word];
        }
    }

    // ---- W1 + gelu -> private gmid; W2 partial over this wave's K-quarter ----
    unsigned* myg1 = gA1 + w*1024;
    unsigned* myg2 = gA2 + w*1024;
    #pragma unroll
    for (int ntl=0; ntl<4; ntl++){
        int nt = w*4 + ntl;
        frag_c a = {0.f,0.f,0.f,0.f};
        #pragma unroll
        for (int kt=0; kt<4; kt++){
            FU4 B1, B2, B3;
            int bidx = ((kt*16 + nt)*16 + col)*16 + quad*4;
            B1.v = *(const uint4*)&w1_s[bidx];
            B2.v = *(const uint4*)&w1_s[bidx + 16384];
            B3.v = *(const uint4*)&w1_s[bidx + 32768];
            a = __builtin_amdgcn_mfma_f32_16x16x32_bf16(xa1[kt].f, B1.f, a, 0, 0, 0);
            a = __builtin_amdgcn_mfma_f32_16x16x32_bf16(xa1[kt].f, B2.f, a, 0, 0, 0);
            a = __builtin_amdgcn_mfma_f32_16x16x32_bf16(xa2[kt].f, B3.f, a, 0, 0, 0);
        }
        float bb = b1[nt*16 + col];
        #pragma unroll
        for (int reg=0; reg<4; reg++){
            float xx = a[reg] + bb;
            float ge = 0.5f*xx*(1.f + erff(xx*0.70710678118654752f));
            unsigned h_, m_, l_;
            split3(ge, h_, m_, l_);
            int row = quad*4 + reg;
            int word = (ntl*16 + col) ^ ((row & 7) << 2);
            myg1[row*64 + word] = h_ | (m_<<16);
            myg2[row*64 + word] = h_ | (l_<<16);
        }
    }
    frag_c aw2[4] = {{0,0,0,0},{0,0,0,0},{0,0,0,0},{0,0,0,0}};
    {
        int sw = (col & 7) << 2;
        #pragma unroll
        for (int kt2=0; kt2<4; kt2++){
            FU4 A1, A2;
            int word = (kt2*16 + quad*4) ^ sw;
            A1.v = *(const uint4*)&myg1[col*64 + word];
            A2.v = *(const uint4*)&myg2[col*64 + word];
            int kg = w*4 + kt2;
            #pragma unroll
            for (int nt2=0; nt2<4; nt2++){
                FU4 B1, B2, B3;
                int bidx = ((kg*4 + nt2)*16 + col)*16 + quad*4;
                B1.v = *(const uint4*)&w2_s[bidx];
                B2.v = *(const uint4*)&w2_s[bidx + 16384];
                B3.v = *(const uint4*)&w2_s[bidx + 32768];
                aw2[nt2] = __builtin_amdgcn_mfma_f32_16x16x32_bf16(A1.f, B1.f, aw2[nt2], 0, 0, 0);
                aw2[nt2] = __builtin_amdgcn_mfma_f32_16x16x32_bf16(A1.f, B2.f, aw2[nt2], 0, 0, 0);
                aw2[nt2] = __builtin_amdgcn_mfma_f32_16x16x32_bf16(A2.f, B3.f, aw2[nt2], 0, 0, 0);
            }
        }
    }
    // ---- cross-wave reduce of W2 partials (red aliases gA1; all W2 reads done) ----
    __syncthreads();
    #pragma unroll
    for (int nt2=0; nt2<4; nt2++)
        #pragma unroll
        for (int reg=0; reg<4; reg++)
            red[((w*4 + nt2)*4 + reg)*64 + lane] = aw2[nt2][reg];
    __syncthreads();
    {
        float bb = b2f[cg];
        #pragma unroll
        for (int reg=0; reg<4; reg++){
            float v = red[((0*4 + w)*4 + reg)*64 + lane]
                    + red[((1*4 + w)*4 + reg)*64 + lane]
                    + red[((2*4 + w)*4 + reg)*64 + lane]
                    + red[((3*4 + w)*4 + reg)*64 + lane];
            int rg = t0 + quad*4 + reg;
            size_t xi = ((size_t)b*LSEQ + rg)*DM + cg;
            x2[xi] += v + bb;
        }
    }
}

// ---------------- output proj: y = 0.5*(x1+x2) @ out_w + out_b, crop to 1250 ----------------
__global__ __launch_bounds__(256) void k_out(
    const float* __restrict__ x1, const float* __restrict__ x2,
    const float* __restrict__ out_w, const float* __restrict__ out_b, float* __restrict__ y)
{
    int idx = blockIdx.x * 256 + threadIdx.x;
    if (idx >= NBATCH * L0SEQ) return;
    int b = idx / L0SEQ, t = idx % L0SEQ;
    const float* r1 = x1 + ((size_t)b*LSEQ + t)*DM;
    const float* r2 = x2 + ((size_t)b*LSEQ + t)*DM;
    float s = 0.f;
    for (int d = 0; d < DM; d++) s += (r1[d]+r2[d])*0.5f*out_w[d];
    y[idx] = s + out_b[0];
}

extern "C" void kernel_launch(void* const* d_in, const int* in_sizes, int n_in,
                              void* d_out, int out_size, void* d_ws, size_t ws_size,
                              hipStream_t stream)
{
    const float* wave  = (const float*)d_in[0];
    const float* in_w  = (const float*)d_in[1];
    const float* in_b  = (const float*)d_in[2];
    const float* ln1_g = (const float*)d_in[3];
    const float* ln1_b = (const float*)d_in[4];
    const float* wqk   = (const float*)d_in[5];
    const float* wv    = (const float*)d_in[6];
    const float* wo_w  = (const float*)d_in[7];
    const float* wo_b  = (const float*)d_in[8];
    const float* rot   = (const float*)d_in[9];
    const float* ln2_g = (const float*)d_in[10];
    const float* ln2_b = (const float*)d_in[11];
    const float* w1    = (const float*)d_in[12];
    const float* b1    = (const float*)d_in[13];
    const float* w2    = (const float*)d_in[14];
    const float* b2    = (const float*)d_in[15];
    const float* out_w = (const float*)d_in[16];
    const float* out_b = (const float*)d_in[17];
    float* y = (float*)d_out;

    float* ws = (float*)d_ws;
    float* x1      = ws;                       // XSZ f32
    float* x2      = x1 + XSZ;                 // XSZ f32
    unsigned* qs   = (unsigned*)(x2 + XSZ);    // QKSZ u32
    unsigned* ks1  = qs  + QKSZ;               // QKSZ u32
    unsigned* vs1  = ks1 + QKSZ;               // QKSZ u32
    unsigned* vs3  = vs1 + QKSZ;               // QKSZ u32
    float* o_hash  = (float*)(vs3 + QKSZ);     // OHSZ f32
    float* slogb   = o_hash + OHSZ;            // SLSZ f32
    int* buckets   = (int*)(slogb + SLSZ);     // SLSZ int
    int* sorted    = buckets + SLSZ;           // SLSZ int
    unsigned* wsplit = (unsigned*)(sorted + SLSZ); // 442368 u32

    k_prep<<<576, 256, 0, stream>>>(wo_w, w1, w2, wsplit);
    k_embed<<<XSZ/256, 256, 0, stream>>>(wave, in_w, in_b, x1, x2);
    for (int layer = 0; layer < 4; layer++) {
        k_qkv<<<320, 256, 0, stream>>>(x2, ln1_g + layer*64, ln1_b + layer*64,
                                       wqk + layer*4096, wv + layer*4096, rot + layer*640,
                                       qs, ks1, vs1, vs3, buckets);
        k_sort<<<256, 64, 0, stream>>>(buckets, sorted);
        k_attn<<<NBH*NCHUNK, 256, 0, stream>>>(qs, ks1, vs1, vs3, sorted, o_hash, slogb);
        k_tail<<<NBATCH*LSEQ/16, 256, 0, stream>>>(o_hash, slogb,
                                        wsplit + layer*12288, wo_b + layer*64,
                                        ln2_g + layer*64, ln2_b + layer*64,
                                        wsplit + 49152 + layer*49152, b1 + layer*256,
                                        wsplit + 245760 + layer*49152, b2 + layer*64,
                                        x1, x2);
    }
    k_out<<<(NBATCH*L0SEQ + 255)/256, 256, 0, stream>>>(x1, x2, out_w, out_b, y);
}

// Round 10
// 630.482 us; speedup vs baseline: 1.0949x; 1.0146x over previous
//
#include <hip/hip_runtime.h>
#include <math.h>

#define LSEQ 1280
#define L0SEQ 1250
#define DM 64
#define NHEADS 4
#define DHD 16
#define NHASH 4
#define NBUK 20
#define NCHUNK 80
#define FFD 256
#define NBATCH 16
#define NBH 64

#define XSZ (NBATCH*LSEQ*DM)        // 1310720
#define QKSZ (NBH*LSEQ*DHD)         // 1310720
#define OHSZ (NBH*NHASH*LSEQ*DHD)   // 5242880
#define SLSZ (NBH*NHASH*LSEQ)       // 327680

typedef __attribute__((ext_vector_type(8))) short frag_ab;   // 8 bf16
typedef __attribute__((ext_vector_type(4))) float frag_c;    // 4 fp32

union FU4 { uint4 v; frag_ab f; };

// round-to-nearest-even bf16 (returns low 16 bits)
__device__ __forceinline__ unsigned rnbf(float x){
    unsigned b = __float_as_uint(x);
    return (b + 0x7fffu + ((b >> 16) & 1u)) >> 16;
}
__device__ __forceinline__ float bf2f(unsigned h){ return __uint_as_float(h << 16); }
__device__ __forceinline__ unsigned rot16(unsigned x){ return (x >> 16) | (x << 16); }

// exact triple split (truncation): x = h + m + l
__device__ __forceinline__ void split3(float x, unsigned& h, unsigned& m, unsigned& l){
    unsigned bx = __float_as_uint(x);
    h = bx >> 16;
    float r = x - __uint_as_float(bx & 0xffff0000u);
    unsigned br = __float_as_uint(r);
    m = br >> 16;
    float r2 = r - __uint_as_float(br & 0xffff0000u);
    l = __float_as_uint(r2) >> 16;
}

// ---------------- embed: x = pad(wave^T) @ in_w + in_b ----------------
__global__ __launch_bounds__(256) void k_embed(
    const float* __restrict__ wave, const float* __restrict__ in_w,
    const float* __restrict__ in_b, float* __restrict__ x1, float* __restrict__ x2)
{
    int idx = blockIdx.x * 256 + threadIdx.x;   // over B*L*D
    int d = idx & 63;
    int t = idx >> 6;
    int b = t / LSEQ;
    int tt = t % LSEQ;
    float v0 = 0.f, v1 = 0.f;
    if (tt < L0SEQ) {
        v0 = wave[(size_t)(b*2+0)*L0SEQ + tt];
        v1 = wave[(size_t)(b*2+1)*L0SEQ + tt];
    }
    float x = v0 * in_w[d] + v1 * in_w[64 + d] + in_b[d];
    x1[idx] = x;
    x2[idx] = x;
}

// ---------------- weight pre-split into MFMA-B layout (trunc-3, k-slot paired) ----------------
__global__ __launch_bounds__(256) void k_prep(
    const float* __restrict__ wo_w, const float* __restrict__ w1,
    const float* __restrict__ w2, unsigned* __restrict__ wsplit)
{
    int gid = blockIdx.x * 256 + threadIdx.x;
    if (gid >= 4*36864) return;
    int l = gid / 36864;
    int r = gid % 36864;
    float src; unsigned* dst; int idx; int stride;
    if (r < 4096) {                 // wo: K=64, N=64
        int k = r >> 6, n = r & 63;
        src = wo_w[l*4096 + k*64 + n];
        dst = wsplit + l*12288;
        idx = (((k>>4)*4 + (n>>4))*16 + (n&15))*16 + (k&15);
        stride = 4096;
    } else if (r < 20480) {         // w1: K=64, N=256
        int rr = r - 4096;
        int k = rr >> 8, n = rr & 255;
        src = w1[l*16384 + k*256 + n];
        dst = wsplit + 49152 + l*49152;
        idx = (((k>>4)*16 + (n>>4))*16 + (n&15))*16 + (k&15);
        stride = 16384;
    } else {                        // w2: K=256, N=64
        int rr = r - 20480;
        int k = rr >> 6, n = rr & 63;
        src = w2[l*16384 + k*64 + n];
        dst = wsplit + 245760 + l*49152;
        idx = (((k>>4)*4 + (n>>4))*16 + (n&15))*16 + (k&15);
        stride = 16384;
    }
    unsigned h, m, lo;
    split3(src, h, m, lo);
    dst[idx]            = h | (m<<16);
    dst[idx + stride]   = m | (h<<16);
    dst[idx + 2*stride] = lo | (h<<16);
}

// ---------------- LN + QK/V proj + bucketing + pre-split, v2: 16-token blocks ----------------
// grid 1280 (5 waves/SIMD). Phase A: LN. Phase B: per-thread 1tok x 4col matmul.
// Phase C: 4 threads per (token,head): splits (sub=elem quarter) + one hash each.
__global__ __launch_bounds__(256) void k_qkv(
    const float* __restrict__ x2, const float* __restrict__ g, const float* __restrict__ bta,
    const float* __restrict__ wqk, const float* __restrict__ wv, const float* __restrict__ rot,
    unsigned* __restrict__ qs, unsigned* __restrict__ ks1,
    unsigned* __restrict__ vs1, unsigned* __restrict__ vs3, int* __restrict__ buckets)
{
    __shared__ float xln[16][68];
    __shared__ float qkt[16][68];
    __shared__ float vvt[16][68];
    __shared__ float rots[640];
    int tid = threadIdx.x;
    int b  = blockIdx.x / 80;
    int t0 = (blockIdx.x % 80) * 16;
    int tok = tid >> 4;             // 0..15
    int cg  = tid & 15;
    int c4  = cg * 4;

    for (int i = tid; i < 640; i += 256) rots[i] = rot[i];

    // ---- phase A: load + LN ----
    float4 xv4 = *(const float4*)&x2[((size_t)b*LSEQ + t0 + tok)*DM + c4];
    float s = xv4.x + xv4.y + xv4.z + xv4.w;
    float ss = xv4.x*xv4.x + xv4.y*xv4.y + xv4.z*xv4.z + xv4.w*xv4.w;
    s  += __shfl_xor(s,1);  s  += __shfl_xor(s,2);  s  += __shfl_xor(s,4);  s  += __shfl_xor(s,8);
    ss += __shfl_xor(ss,1); ss += __shfl_xor(ss,2); ss += __shfl_xor(ss,4); ss += __shfl_xor(ss,8);
    float m = s * (1.f/64.f);
    float vr = ss * (1.f/64.f) - m*m;
    float rstd = 1.f / sqrtf(vr + 1e-5f);
    {
        float4 g4 = *(const float4*)&g[c4];
        float4 b4 = *(const float4*)&bta[c4];
        float4 o;
        o.x = (xv4.x-m)*rstd*g4.x + b4.x;
        o.y = (xv4.y-m)*rstd*g4.y + b4.y;
        o.z = (xv4.z-m)*rstd*g4.z + b4.z;
        o.w = (xv4.w-m)*rstd*g4.w + b4.w;
        *(float4*)&xln[tok][c4] = o;
    }
    __syncthreads();

    // ---- phase B: matmul (1 token x 4 cols x 2 mats) ----
    float aq[4] = {0,0,0,0}, av[4] = {0,0,0,0};
    for (int f = 0; f < 64; f++) {
        float4 wq4 = *(const float4*)&wqk[f*64 + c4];
        float4 wv4 = *(const float4*)&wv [f*64 + c4];
        float xv = xln[tok][f];
        aq[0] += xv*wq4.x; aq[1] += xv*wq4.y; aq[2] += xv*wq4.z; aq[3] += xv*wq4.w;
        av[0] += xv*wv4.x; av[1] += xv*wv4.y; av[2] += xv*wv4.z; av[3] += xv*wv4.w;
    }
    *(float4*)&qkt[tok][c4] = *(float4*)aq;
    *(float4*)&vvt[tok][c4] = *(float4*)av;
    __syncthreads();

    // ---- phase C: splits + buckets. pair p=(token,head); sub = elem quarter / hash ----
    int p = tid >> 2;               // 0..63
    int ptok = p >> 2, head = p & 3;
    int sub = tid & 3;
    int e0 = sub * 4;
    int t = t0 + ptok;
    float4 qf4 = *(const float4*)&qkt[ptok][head*16 + e0];
    float nsq = qf4.x*qf4.x + qf4.y*qf4.y + qf4.z*qf4.z + qf4.w*qf4.w;
    nsq += __shfl_xor(nsq,1); nsq += __shfl_xor(nsq,2);
    float inv = 1.f / fmaxf(sqrtf(nsq), 1e-12f);
    float qe[4] = {qf4.x, qf4.y, qf4.z, qf4.w};
    unsigned wq[4], wk[4];
    #pragma unroll
    for (int i=0;i<4;i++){
        float xq = qe[i]*0.25f;
        unsigned qh = rnbf(xq);
        unsigned ql = rnbf(xq - bf2f(qh));
        wq[i] = qh | (ql<<16);
        float xk = qe[i]*inv;
        unsigned kh = rnbf(xk);
        unsigned kl = rnbf(xk - bf2f(kh));
        wk[i] = kh | (kl<<16);
    }
    float4 vf4 = *(const float4*)&vvt[ptok][head*16 + e0];
    float ve[4] = {vf4.x, vf4.y, vf4.z, vf4.w};
    unsigned wv1[4], wv3[4];
    #pragma unroll
    for (int i=0;i<4;i++){
        unsigned vh_, vm_, vl_;
        split3(ve[i], vh_, vm_, vl_);
        wv1[i] = vh_ | (vm_<<16);
        wv3[i] = vl_ | (vh_<<16);
    }
    size_t sb = (((size_t)(b*NHEADS+head))*LSEQ + t)*16 + e0;
    *(uint4*)&qs [sb] = *(uint4*)wq;
    *(uint4*)&ks1[sb] = *(uint4*)wk;
    *(uint4*)&vs1[sb] = *(uint4*)wv1;
    *(uint4*)&vs3[sb] = *(uint4*)wv3;

    // buckets: this thread does hash nh = sub
    float qf[16];
    {
        float4 a0 = *(const float4*)&qkt[ptok][head*16 + 0];
        float4 a1 = *(const float4*)&qkt[ptok][head*16 + 4];
        float4 a2 = *(const float4*)&qkt[ptok][head*16 + 8];
        float4 a3 = *(const float4*)&qkt[ptok][head*16 + 12];
        qf[0]=a0.x; qf[1]=a0.y; qf[2]=a0.z; qf[3]=a0.w;
        qf[4]=a1.x; qf[5]=a1.y; qf[6]=a1.z; qf[7]=a1.w;
        qf[8]=a2.x; qf[9]=a2.y; qf[10]=a2.z; qf[11]=a2.w;
        qf[12]=a3.x; qf[13]=a3.y; qf[14]=a3.z; qf[15]=a3.w;
    }
    int nh = sub;
    float rv[10];
    #pragma unroll
    for (int i=0;i<10;i++) {
        float acc = 0.f;
        #pragma unroll
        for (int f=0; f<16; f++) acc += qf[f]*rots[(f*NHASH+nh)*10 + i];
        rv[i] = acc;
    }
    float best = rv[0]; int bi = 0;
    #pragma unroll
    for (int i=1;i<10;i++) if (rv[i] > best) { best = rv[i]; bi = i; }
    #pragma unroll
    for (int i=0;i<10;i++) if (-rv[i] > best) { best = -rv[i]; bi = 10+i; }
    buckets[((size_t)(b*NHEADS+head)*NHASH + nh)*LSEQ + t] = bi;
}

// ---------------- counting sort per (bh, hash): stable, ballot-ranked ----------------
__global__ __launch_bounds__(64) void k_sort(
    const int* __restrict__ buckets, int* __restrict__ sorted)
{
    __shared__ int hist[20];
    __shared__ int startl[20];
    int lane = threadIdx.x;
    int gidx = blockIdx.x;
    const int* bk = buckets + (size_t)gidx * LSEQ;
    int* dst = sorted + (size_t)gidx * LSEQ;
    if (lane < 20) hist[lane] = 0;
    __syncthreads();
    int myb[20];
    for (int ch = 0; ch < 20; ch++) {
        myb[ch] = bk[ch*64 + lane];
        atomicAdd(&hist[myb[ch]], 1);
    }
    __syncthreads();
    if (lane == 0) {
        int acc = 0;
        for (int b2 = 0; b2 < 20; b2++) { startl[b2] = acc; acc += hist[b2]; }
    }
    __syncthreads();
    unsigned long long below = (lane == 63) ? 0x7fffffffffffffffull
                                            : ((1ull << lane) - 1ull);
    for (int ch = 0; ch < 20; ch++) {
        int bv = myb[ch];
        unsigned long long mymask = 0, ownmask = 0;
        #pragma unroll
        for (int b2 = 0; b2 < 20; b2++) {
            unsigned long long m2 = __ballot(bv == b2);
            if (b2 == bv)   mymask  = m2;
            if (b2 == lane) ownmask = m2;
        }
        int rank = __popcll(mymask & below);
        int base = startl[bv];
        dst[base + rank] = ch*64 + lane;
        __syncthreads();
        if (lane < 20) startl[lane] += __popcll(ownmask);
        __syncthreads();
    }
}

// ---------------- chunked attention: copy-staging from pre-split arrays ----------------
__global__ __launch_bounds__(256) void k_attn(
    const unsigned* __restrict__ qs, const unsigned* __restrict__ ks1g,
    const unsigned* __restrict__ vs1g, const unsigned* __restrict__ vs3g,
    const int* __restrict__ sorted, float* __restrict__ o_hash, float* __restrict__ slog)
{
    __shared__ __align__(16) unsigned SMEM[13120];
    unsigned* Va1 = SMEM;
    unsigned* Va2 = SMEM + 2624;
    unsigned* Va3 = SMEM + 5248;
    unsigned* Ka1 = SMEM + 7872;
    unsigned* Ka2 = SMEM + 10432;
    unsigned* Pa1 = SMEM + 7872;
    unsigned* Pa2 = SMEM + 10432;
    int* kposS = (int*)(SMEM + 12992);

    int tid = threadIdx.x;
    int bh = blockIdx.x / NCHUNK;
    int c  = blockIdx.x % NCHUNK;
    int h  = c / NBUK, cc = c % NBUK;
    int cp = (c + NCHUNK - 1) % NCHUNK;
    int hp = cp / NBUK, ccp = cp % NBUK;

    int key = tid & 127;
    int pos = (key < 64)
        ? sorted[((size_t)bh*NHASH + h)*LSEQ + cc*64 + key]
        : sorted[((size_t)bh*NHASH + hp)*LSEQ + ccp*64 + (key-64)];
    size_t srow = ((size_t)bh*LSEQ + pos)*16;
    if (tid < 128) {
        kposS[key] = pos;
        const uint4* kr = (const uint4*)(ks1g + srow);
        #pragma unroll
        for (int e4=0; e4<4; e4++){
            uint4 t = kr[e4];
            *(uint4*)&Ka1[key*20 + e4*4] = t;
            uint4 rt; rt.x=rot16(t.x); rt.y=rot16(t.y); rt.z=rot16(t.z); rt.w=rot16(t.w);
            *(uint4*)&Ka2[key*20 + e4*4] = rt;
        }
    } else {
        const uint4* v1r = (const uint4*)(vs1g + srow);
        const uint4* v3r = (const uint4*)(vs3g + srow);
        int kt = key >> 4, jl = key & 15;
        int lb = kt*328 + jl;
        #pragma unroll
        for (int e4=0; e4<4; e4++){
            uint4 a = v1r[e4], cc2 = v3r[e4];
            unsigned aa[4] = {a.x,a.y,a.z,a.w};
            unsigned cb[4] = {cc2.x,cc2.y,cc2.z,cc2.w};
            #pragma unroll
            for (int i=0;i<4;i++){
                int d = e4*4 + i;
                Va1[lb + d*20] = aa[i];
                Va2[lb + d*20] = rot16(aa[i]);
                Va3[lb + d*20] = cb[i];
            }
        }
    }
    __syncthreads();

    int w = tid >> 6, lane = tid & 63;
    int quad = lane >> 4, col = lane & 15;

    int qgpos = kposS[16*w + col];
    FU4 QA;
    QA.v = *(const uint4*)(qs + ((size_t)bh*LSEQ + qgpos)*16 + quad*4);
    frag_ab qA = QA.f;

    frag_c acc[8];
    #pragma unroll
    for (int nt=0; nt<8; nt++){
        FU4 B1, B2;
        B1.v = *(const uint4*)&Ka1[(nt*16+col)*20 + 4*quad];
        B2.v = *(const uint4*)&Ka2[(nt*16+col)*20 + 4*quad];
        frag_c a = {0.f,0.f,0.f,0.f};
        a = __builtin_amdgcn_mfma_f32_16x16x32_bf16(qA, B1.f, a, 0, 0, 0);
        a = __builtin_amdgcn_mfma_f32_16x16x32_bf16(qA, B2.f, a, 0, 0, 0);
        acc[nt] = a;
    }
    int qp[4];
    #pragma unroll
    for (int reg=0; reg<4; reg++) qp[reg] = kposS[16*w + quad*4 + reg];
    #pragma unroll
    for (int nt=0; nt<8; nt++){
        int kp2 = kposS[nt*16 + col];
        #pragma unroll
        for (int reg=0; reg<4; reg++)
            if (kp2 == qp[reg]) acc[nt][reg] = -5e4f;
    }
    float mx[4] = {-3.4e38f,-3.4e38f,-3.4e38f,-3.4e38f};
    #pragma unroll
    for (int nt=0; nt<8; nt++)
        #pragma unroll
        for (int reg=0; reg<4; reg++) mx[reg] = fmaxf(mx[reg], acc[nt][reg]);
    #pragma unroll
    for (int reg=0; reg<4; reg++){
        float m2 = mx[reg];
        m2 = fmaxf(m2, __shfl_xor(m2, 1)); m2 = fmaxf(m2, __shfl_xor(m2, 2));
        m2 = fmaxf(m2, __shfl_xor(m2, 4)); m2 = fmaxf(m2, __shfl_xor(m2, 8));
        mx[reg] = m2;
    }
    float sm2[4] = {0.f,0.f,0.f,0.f};
    #pragma unroll
    for (int nt=0; nt<8; nt++)
        #pragma unroll
        for (int reg=0; reg<4; reg++){
            float e = __expf(acc[nt][reg] - mx[reg]);
            acc[nt][reg] = e; sm2[reg] += e;
        }
    #pragma unroll
    for (int reg=0; reg<4; reg++){
        float s2 = sm2[reg];
        s2 += __shfl_xor(s2, 1); s2 += __shfl_xor(s2, 2);
        s2 += __shfl_xor(s2, 4); s2 += __shfl_xor(s2, 8);
        sm2[reg] = s2;
    }
    float invs[4];
    #pragma unroll
    for (int reg=0; reg<4; reg++) invs[reg] = 1.f / sm2[reg];
    if (col == 0) {
        #pragma unroll
        for (int reg=0; reg<4; reg++)
            slog[((size_t)bh*NHASH + h)*LSEQ + qp[reg]] = mx[reg] + __logf(sm2[reg]);
    }

    frag_c o = {0.f,0.f,0.f,0.f};
    __syncthreads();
    #pragma unroll
    for (int pass=0; pass<4; pass++){
        #pragma unroll
        for (int t2=0; t2<2; t2++){
            int nt = pass*2 + t2;
            #pragma unroll
            for (int reg=0; reg<4; reg++){
                float p = acc[nt][reg] * invs[reg];
                unsigned ph_, pm_, pl_;
                split3(p, ph_, pm_, pl_);
                int idx = t2*1280 + (16*w + 4*quad + reg)*20 + col;
                Pa1[idx] = ph_ | (pm_<<16);
                Pa2[idx] = ph_ | (pl_<<16);
            }
        }
        __syncthreads();
        #pragma unroll
        for (int t2=0; t2<2; t2++){
            int ktg = pass*2 + t2;
            FU4 A1, A2, B1, B2, B3;
            int pidx = t2*1280 + (16*w + col)*20 + 4*quad;
            A1.v = *(const uint4*)&Pa1[pidx];
            A2.v = *(const uint4*)&Pa2[pidx];
            int vidx = ktg*328 + col*20 + 4*quad;
            B1.v = *(const uint4*)&Va1[vidx];
            B2.v = *(const uint4*)&Va2[vidx];
            B3.v = *(const uint4*)&Va3[vidx];
            o = __builtin_amdgcn_mfma_f32_16x16x32_bf16(A1.f, B1.f, o, 0, 0, 0);
            o = __builtin_amdgcn_mfma_f32_16x16x32_bf16(A1.f, B2.f, o, 0, 0, 0);
            o = __builtin_amdgcn_mfma_f32_16x16x32_bf16(A2.f, B3.f, o, 0, 0, 0);
        }
        if (pass < 3) __syncthreads();
    }
    size_t obase = ((size_t)bh*NHASH + h)*LSEQ;
    #pragma unroll
    for (int reg=0; reg<4; reg++)
        o_hash[(obase + qp[reg])*DHD + col] = o[reg];
}

// ---------------- fused tail v3: 16-token blocks, cooperative combine in LDS ----------------
__global__ __launch_bounds__(256) void k_tail(
    const float* __restrict__ o_hash, const float* __restrict__ slog,
    const unsigned* __restrict__ wo_s, const float* __restrict__ wo_b,
    const float* __restrict__ g2, const float* __restrict__ b2t,
    const unsigned* __restrict__ w1_s, const float* __restrict__ b1,
    const unsigned* __restrict__ w2_s, const float* __restrict__ b2f,
    float* __restrict__ x1, float* __restrict__ x2)
{
    __shared__ unsigned cA1[1024], cA2[1024];   // combined att split, xA-style swizzle
    __shared__ unsigned xA1[1024], xA2[1024];
    __shared__ unsigned gA1[4096], gA2[4096];
    __shared__ float lnS[64], lnQ[64];
    float* red = (float*)gA1;                   // aliased after W2 MFMAs

    int tid = threadIdx.x;
    int b  = blockIdx.x / 80;
    int t0 = (blockIdx.x % 80) * 16;
    int w = tid >> 6, lane = tid & 63;
    int quad = lane >> 4, col = lane & 15;

    // ---- phase 0: cooperative combine -> cA (one pass, all 256 threads) ----
    {
        int tok = tid >> 4;         // 0..15
        int dg  = tid & 15;
        int d0  = dg * 4;
        int kt  = dg >> 2;          // head
        int t = t0 + tok;
        int bh = b*NHEADS + kt;
        float sl[4];
        #pragma unroll
        for (int nh=0; nh<4; nh++) sl[nh] = slog[((size_t)bh*NHASH + nh)*LSEQ + t];
        float mx = fmaxf(fmaxf(sl[0],sl[1]), fmaxf(sl[2],sl[3]));
        float wgt[4]; float wsum = 0.f;
        #pragma unroll
        for (int nh=0; nh<4; nh++){ wgt[nh] = __expf(sl[nh]-mx); wsum += wgt[nh]; }
        float iv = 1.f/wsum;
        float a4[4] = {0.f,0.f,0.f,0.f};
        #pragma unroll
        for (int nh=0; nh<4; nh++){
            float4 oh = *(const float4*)&o_hash[(((size_t)bh*NHASH + nh)*LSEQ + t)*DHD + (d0 & 15)];
            float wn = wgt[nh]*iv;
            a4[0] += wn*oh.x; a4[1] += wn*oh.y; a4[2] += wn*oh.z; a4[3] += wn*oh.w;
        }
        int sw = (tok & 7) << 2;
        unsigned cw1[4], cw2[4];
        #pragma unroll
        for (int i=0;i<4;i++){
            unsigned h_, m_, l_;
            split3(a4[i], h_, m_, l_);
            cw1[i] = h_ | (m_<<16);
            cw2[i] = h_ | (l_<<16);
        }
        *(uint4*)&cA1[tok*64 + (d0 ^ sw)] = *(uint4*)cw1;
        *(uint4*)&cA2[tok*64 + (d0 ^ sw)] = *(uint4*)cw2;
    }
    __syncthreads();
    FU4 aA1[4], aA2[4];
    {
        int sw = (col & 7) << 2;
        #pragma unroll
        for (int kt=0; kt<4; kt++){
            int word = (kt*16 + quad*4) ^ sw;
            aA1[kt].v = *(const uint4*)&cA1[col*64 + word];
            aA2[kt].v = *(const uint4*)&cA2[col*64 + word];
        }
    }

    // ---- WO: this wave's N-tile (nt = w) ----
    frag_c awo = {0.f,0.f,0.f,0.f};
    #pragma unroll
    for (int kt=0; kt<4; kt++){
        FU4 B1, B2, B3;
        int bidx = ((kt*4 + w)*16 + col)*16 + quad*4;
        B1.v = *(const uint4*)&wo_s[bidx];
        B2.v = *(const uint4*)&wo_s[bidx + 4096];
        B3.v = *(const uint4*)&wo_s[bidx + 8192];
        awo = __builtin_amdgcn_mfma_f32_16x16x32_bf16(aA1[kt].f, B1.f, awo, 0, 0, 0);
        awo = __builtin_amdgcn_mfma_f32_16x16x32_bf16(aA1[kt].f, B2.f, awo, 0, 0, 0);
        awo = __builtin_amdgcn_mfma_f32_16x16x32_bf16(aA2[kt].f, B3.f, awo, 0, 0, 0);
    }
    int cg = w*16 + col;
    float x1n[4];
    float s1[4], s2[4];
    {
        float wb = wo_b[cg];
        #pragma unroll
        for (int reg=0; reg<4; reg++){
            int rg = t0 + quad*4 + reg;
            size_t xi = ((size_t)b*LSEQ + rg)*DM + cg;
            float xv = x1[xi] + awo[reg] + wb;
            x1[xi] = xv;
            x1n[reg] = xv;
            s1[reg] = xv; s2[reg] = xv*xv;
        }
    }
    #pragma unroll
    for (int reg=0; reg<4; reg++){
        float a = s1[reg], q = s2[reg];
        a += __shfl_xor(a,1); a += __shfl_xor(a,2); a += __shfl_xor(a,4); a += __shfl_xor(a,8);
        q += __shfl_xor(q,1); q += __shfl_xor(q,2); q += __shfl_xor(q,4); q += __shfl_xor(q,8);
        s1[reg] = a; s2[reg] = q;
    }
    if (col == 0) {
        #pragma unroll
        for (int reg=0; reg<4; reg++){
            lnS[w*16 + quad*4 + reg] = s1[reg];
            lnQ[w*16 + quad*4 + reg] = s2[reg];
        }
    }
    __syncthreads();
    float mean[4], rstd[4];
    #pragma unroll
    for (int reg=0; reg<4; reg++){
        int tok = quad*4 + reg;
        float a = lnS[tok] + lnS[16+tok] + lnS[32+tok] + lnS[48+tok];
        float q = lnQ[tok] + lnQ[16+tok] + lnQ[32+tok] + lnQ[48+tok];
        mean[reg] = a*(1.f/64.f);
        float var = q*(1.f/64.f) - mean[reg]*mean[reg];
        rstd[reg] = 1.f/sqrtf(var + 1e-5f);
    }
    {
        float gv = g2[cg], bv = b2t[cg];
        #pragma unroll
        for (int reg=0; reg<4; reg++){
            int row = quad*4 + reg;
            float xv = (x1n[reg]-mean[reg])*rstd[reg]*gv + bv;
            unsigned h_, m_, l_;
            split3(xv, h_, m_, l_);
            int word = cg ^ ((row & 7) << 2);
            xA1[row*64 + word] = h_ | (m_<<16);
            xA2[row*64 + word] = h_ | (l_<<16);
        }
    }
    __syncthreads();
    FU4 xa1[4], xa2[4];
    {
        int sw = (col & 7) << 2;
        #pragma unroll
        for (int kt=0; kt<4; kt++){
            int word = (kt*16 + quad*4) ^ sw;
            xa1[kt].v = *(const uint4*)&xA1[col*64 + word];
            xa2[kt].v = *(const uint4*)&xA2[col*64 + word];
        }
    }

    // ---- W1 + gelu -> private gmid; W2 partial over this wave's K-quarter ----
    unsigned* myg1 = gA1 + w*1024;
    unsigned* myg2 = gA2 + w*1024;
    #pragma unroll
    for (int ntl=0; ntl<4; ntl++){
        int nt = w*4 + ntl;
        frag_c a = {0.f,0.f,0.f,0.f};
        #pragma unroll
        for (int kt=0; kt<4; kt++){
            FU4 B1, B2, B3;
            int bidx = ((kt*16 + nt)*16 + col)*16 + quad*4;
            B1.v = *(const uint4*)&w1_s[bidx];
            B2.v = *(const uint4*)&w1_s[bidx + 16384];
            B3.v = *(const uint4*)&w1_s[bidx + 32768];
            a = __builtin_amdgcn_mfma_f32_16x16x32_bf16(xa1[kt].f, B1.f, a, 0, 0, 0);
            a = __builtin_amdgcn_mfma_f32_16x16x32_bf16(xa1[kt].f, B2.f, a, 0, 0, 0);
            a = __builtin_amdgcn_mfma_f32_16x16x32_bf16(xa2[kt].f, B3.f, a, 0, 0, 0);
        }
        float bb = b1[nt*16 + col];
        #pragma unroll
        for (int reg=0; reg<4; reg++){
            float xx = a[reg] + bb;
            float ge = 0.5f*xx*(1.f + erff(xx*0.70710678118654752f));
            unsigned h_, m_, l_;
            split3(ge, h_, m_, l_);
            int row = quad*4 + reg;
            int word = (ntl*16 + col) ^ ((row & 7) << 2);
            myg1[row*64 + word] = h_ | (m_<<16);
            myg2[row*64 + word] = h_ | (l_<<16);
        }
    }
    frag_c aw2[4] = {{0,0,0,0},{0,0,0,0},{0,0,0,0},{0,0,0,0}};
    {
        int sw = (col & 7) << 2;
        #pragma unroll
        for (int kt2=0; kt2<4; kt2++){
            FU4 A1, A2;
            int word = (kt2*16 + quad*4) ^ sw;
            A1.v = *(const uint4*)&myg1[col*64 + word];
            A2.v = *(const uint4*)&myg2[col*64 + word];
            int kg = w*4 + kt2;
            #pragma unroll
            for (int nt2=0; nt2<4; nt2++){
                FU4 B1, B2, B3;
                int bidx = ((kg*4 + nt2)*16 + col)*16 + quad*4;
                B1.v = *(const uint4*)&w2_s[bidx];
                B2.v = *(const uint4*)&w2_s[bidx + 16384];
                B3.v = *(const uint4*)&w2_s[bidx + 32768];
                aw2[nt2] = __builtin_amdgcn_mfma_f32_16x16x32_bf16(A1.f, B1.f, aw2[nt2], 0, 0, 0);
                aw2[nt2] = __builtin_amdgcn_mfma_f32_16x16x32_bf16(A1.f, B2.f, aw2[nt2], 0, 0, 0);
                aw2[nt2] = __builtin_amdgcn_mfma_f32_16x16x32_bf16(A2.f, B3.f, aw2[nt2], 0, 0, 0);
            }
        }
    }
    __syncthreads();
    #pragma unroll
    for (int nt2=0; nt2<4; nt2++)
        #pragma unroll
        for (int reg=0; reg<4; reg++)
            red[((w*4 + nt2)*4 + reg)*64 + lane] = aw2[nt2][reg];
    __syncthreads();
    {
        float bb = b2f[cg];
        #pragma unroll
        for (int reg=0; reg<4; reg++){
            float v = red[((0*4 + w)*4 + reg)*64 + lane]
                    + red[((1*4 + w)*4 + reg)*64 + lane]
                    + red[((2*4 + w)*4 + reg)*64 + lane]
                    + red[((3*4 + w)*4 + reg)*64 + lane];
            int rg = t0 + quad*4 + reg;
            size_t xi = ((size_t)b*LSEQ + rg)*DM + cg;
            x2[xi] += v + bb;
        }
    }
}

// ---------------- output proj: y = 0.5*(x1+x2) @ out_w + out_b, crop to 1250 ----------------
__global__ __launch_bounds__(256) void k_out(
    const float* __restrict__ x1, const float* __restrict__ x2,
    const float* __restrict__ out_w, const float* __restrict__ out_b, float* __restrict__ y)
{
    int idx = blockIdx.x * 256 + threadIdx.x;
    if (idx >= NBATCH * L0SEQ) return;
    int b = idx / L0SEQ, t = idx % L0SEQ;
    const float* r1 = x1 + ((size_t)b*LSEQ + t)*DM;
    const float* r2 = x2 + ((size_t)b*LSEQ + t)*DM;
    float s = 0.f;
    for (int d = 0; d < DM; d++) s += (r1[d]+r2[d])*0.5f*out_w[d];
    y[idx] = s + out_b[0];
}

extern "C" void kernel_launch(void* const* d_in, const int* in_sizes, int n_in,
                              void* d_out, int out_size, void* d_ws, size_t ws_size,
                              hipStream_t stream)
{
    const float* wave  = (const float*)d_in[0];
    const float* in_w  = (const float*)d_in[1];
    const float* in_b  = (const float*)d_in[2];
    const float* ln1_g = (const float*)d_in[3];
    const float* ln1_b = (const float*)d_in[4];
    const float* wqk   = (const float*)d_in[5];
    const float* wv    = (const float*)d_in[6];
    const float* wo_w  = (const float*)d_in[7];
    const float* wo_b  = (const float*)d_in[8];
    const float* rot   = (const float*)d_in[9];
    const float* ln2_g = (const float*)d_in[10];
    const float* ln2_b = (const float*)d_in[11];
    const float* w1    = (const float*)d_in[12];
    const float* b1    = (const float*)d_in[13];
    const float* w2    = (const float*)d_in[14];
    const float* b2    = (const float*)d_in[15];
    const float* out_w = (const float*)d_in[16];
    const float* out_b = (const float*)d_in[17];
    float* y = (float*)d_out;

    float* ws = (float*)d_ws;
    float* x1      = ws;                       // XSZ f32
    float* x2      = x1 + XSZ;                 // XSZ f32
    unsigned* qs   = (unsigned*)(x2 + XSZ);    // QKSZ u32
    unsigned* ks1  = qs  + QKSZ;               // QKSZ u32
    unsigned* vs1  = ks1 + QKSZ;               // QKSZ u32
    unsigned* vs3  = vs1 + QKSZ;               // QKSZ u32
    float* o_hash  = (float*)(vs3 + QKSZ);     // OHSZ f32
    float* slogb   = o_hash + OHSZ;            // SLSZ f32
    int* buckets   = (int*)(slogb + SLSZ);     // SLSZ int
    int* sorted    = buckets + SLSZ;           // SLSZ int
    unsigned* wsplit = (unsigned*)(sorted + SLSZ); // 442368 u32

    k_prep<<<576, 256, 0, stream>>>(wo_w, w1, w2, wsplit);
    k_embed<<<XSZ/256, 256, 0, stream>>>(wave, in_w, in_b, x1, x2);
    for (int layer = 0; layer < 4; layer++) {
        k_qkv<<<NBATCH*80, 256, 0, stream>>>(x2, ln1_g + layer*64, ln1_b + layer*64,
                                       wqk + layer*4096, wv + layer*4096, rot + layer*640,
                                       qs, ks1, vs1, vs3, buckets);
        k_sort<<<256, 64, 0, stream>>>(buckets, sorted);
        k_attn<<<NBH*NCHUNK, 256, 0, stream>>>(qs, ks1, vs1, vs3, sorted, o_hash, slogb);
        k_tail<<<NBATCH*LSEQ/16, 256, 0, stream>>>(o_hash, slogb,
                                        wsplit + layer*12288, wo_b + layer*64,
                                        ln2_g + layer*64, ln2_b + layer*64,
                                        wsplit + 49152 + layer*49152, b1 + layer*256,
                                        wsplit + 245760 + layer*49152, b2 + layer*64,
                                        x1, x2);
    }
    k_out<<<(NBATCH*L0SEQ + 255)/256, 256, 0, stream>>>(x1, x2, out_w, out_b, y);
}

// Round 11
// 562.350 us; speedup vs baseline: 1.2276x; 1.1212x over previous
//
#include <hip/hip_runtime.h>
#include <math.h>

#define LSEQ 1280
#define L0SEQ 1250
#define DM 64
#define NHEADS 4
#define DHD 16
#define NHASH 4
#define NBUK 20
#define NCHUNK 80
#define FFD 256
#define NBATCH 16
#define NBH 64

#define XSZ (NBATCH*LSEQ*DM)        // 1310720
#define QKSZ (NBH*LSEQ*DHD)         // 1310720
#define OHSZ (NBH*NHASH*LSEQ*DHD)   // 5242880
#define SLSZ (NBH*NHASH*LSEQ)       // 327680

typedef __attribute__((ext_vector_type(8))) short frag_ab;   // 8 bf16
typedef __attribute__((ext_vector_type(4))) float frag_c;    // 4 fp32

union FU4 { uint4 v; frag_ab f; };

__device__ __forceinline__ unsigned rnbf(float x){
    unsigned b = __float_as_uint(x);
    return (b + 0x7fffu + ((b >> 16) & 1u)) >> 16;
}
__device__ __forceinline__ float bf2f(unsigned h){ return __uint_as_float(h << 16); }
__device__ __forceinline__ unsigned rot16(unsigned x){ return (x >> 16) | (x << 16); }
__device__ __forceinline__ uint4 rot16v(uint4 a){
    uint4 r; r.x=rot16(a.x); r.y=rot16(a.y); r.z=rot16(a.z); r.w=rot16(a.w); return r;
}

// exact triple split (truncation): x = h + m + l
__device__ __forceinline__ void split3(float x, unsigned& h, unsigned& m, unsigned& l){
    unsigned bx = __float_as_uint(x);
    h = bx >> 16;
    float r = x - __uint_as_float(bx & 0xffff0000u);
    unsigned br = __float_as_uint(r);
    m = br >> 16;
    float r2 = r - __uint_as_float(br & 0xffff0000u);
    l = __float_as_uint(r2) >> 16;
}

// ---------------- init: embed (blocks 0..5119) + weight pre-split (blocks 5120..5695) ----------------
// weight split arrays: per matrix only B1=[h|m] and B3=[l|h]; B2 = rot16(B1) rebuilt at use.
__global__ __launch_bounds__(256) void k_init(
    const float* __restrict__ wave, const float* __restrict__ in_w, const float* __restrict__ in_b,
    float* __restrict__ x1, float* __restrict__ x2,
    const float* __restrict__ wo_w, const float* __restrict__ w1,
    const float* __restrict__ w2, unsigned* __restrict__ wsplit)
{
    if (blockIdx.x < 5120) {
        int idx = blockIdx.x * 256 + threadIdx.x;
        int d = idx & 63;
        int t = idx >> 6;
        int b = t / LSEQ;
        int tt = t % LSEQ;
        float v0 = 0.f, v1 = 0.f;
        if (tt < L0SEQ) {
            v0 = wave[(size_t)(b*2+0)*L0SEQ + tt];
            v1 = wave[(size_t)(b*2+1)*L0SEQ + tt];
        }
        float x = v0 * in_w[d] + v1 * in_w[64 + d] + in_b[d];
        x1[idx] = x;
        x2[idx] = x;
    } else {
        int gid = (blockIdx.x - 5120) * 256 + threadIdx.x;   // < 147456 exactly
        int l = gid / 36864;
        int r = gid % 36864;
        float src; unsigned* dst; int idx; int stride;
        if (r < 4096) {                 // wo: K=64, N=64
            int k = r >> 6, n = r & 63;
            src = wo_w[l*4096 + k*64 + n];
            dst = wsplit + l*8192;
            idx = (((k>>4)*4 + (n>>4))*16 + (n&15))*16 + (k&15);
            stride = 4096;
        } else if (r < 20480) {         // w1: K=64, N=256
            int rr = r - 4096;
            int k = rr >> 8, n = rr & 255;
            src = w1[l*16384 + k*256 + n];
            dst = wsplit + 32768 + l*32768;
            idx = (((k>>4)*16 + (n>>4))*16 + (n&15))*16 + (k&15);
            stride = 16384;
        } else {                        // w2: K=256, N=64
            int rr = r - 20480;
            int k = rr >> 6, n = rr & 63;
            src = w2[l*16384 + k*64 + n];
            dst = wsplit + 163840 + l*32768;
            idx = (((k>>4)*4 + (n>>4))*16 + (n&15))*16 + (k&15);
            stride = 16384;
        }
        unsigned h, m, lo;
        split3(src, h, m, lo);
        dst[idx]          = h | (m<<16);
        dst[idx + stride] = lo | (h<<16);
    }
}

// ---------------- LN + QK/V proj + bucketing + pre-split (interleaved 256B/token rows) ----------------
// grid 1280. qkvs row (64 u32): [q 0..15][k 16..31][v1 32..47][v3 48..63]
__global__ __launch_bounds__(256) void k_qkv(
    const float* __restrict__ x2, const float* __restrict__ g, const float* __restrict__ bta,
    const float* __restrict__ wqk, const float* __restrict__ wv, const float* __restrict__ rot,
    unsigned* __restrict__ qkvs, int* __restrict__ buckets)
{
    __shared__ float xln[16][68];
    __shared__ float qkt[16][68];
    __shared__ float vvt[16][68];
    __shared__ float rots[640];
    int tid = threadIdx.x;
    int b  = blockIdx.x / 80;
    int t0 = (blockIdx.x % 80) * 16;
    int tok = tid >> 4;
    int cg  = tid & 15;
    int c4  = cg * 4;

    for (int i = tid; i < 640; i += 256) rots[i] = rot[i];

    float4 xv4 = *(const float4*)&x2[((size_t)b*LSEQ + t0 + tok)*DM + c4];
    float s = xv4.x + xv4.y + xv4.z + xv4.w;
    float ss = xv4.x*xv4.x + xv4.y*xv4.y + xv4.z*xv4.z + xv4.w*xv4.w;
    s  += __shfl_xor(s,1);  s  += __shfl_xor(s,2);  s  += __shfl_xor(s,4);  s  += __shfl_xor(s,8);
    ss += __shfl_xor(ss,1); ss += __shfl_xor(ss,2); ss += __shfl_xor(ss,4); ss += __shfl_xor(ss,8);
    float m = s * (1.f/64.f);
    float vr = ss * (1.f/64.f) - m*m;
    float rstd = 1.f / sqrtf(vr + 1e-5f);
    {
        float4 g4 = *(const float4*)&g[c4];
        float4 b4 = *(const float4*)&bta[c4];
        float4 o;
        o.x = (xv4.x-m)*rstd*g4.x + b4.x;
        o.y = (xv4.y-m)*rstd*g4.y + b4.y;
        o.z = (xv4.z-m)*rstd*g4.z + b4.z;
        o.w = (xv4.w-m)*rstd*g4.w + b4.w;
        *(float4*)&xln[tok][c4] = o;
    }
    __syncthreads();

    float aq[4] = {0,0,0,0}, av[4] = {0,0,0,0};
    for (int f = 0; f < 64; f++) {
        float4 wq4 = *(const float4*)&wqk[f*64 + c4];
        float4 wv4 = *(const float4*)&wv [f*64 + c4];
        float xv = xln[tok][f];
        aq[0] += xv*wq4.x; aq[1] += xv*wq4.y; aq[2] += xv*wq4.z; aq[3] += xv*wq4.w;
        av[0] += xv*wv4.x; av[1] += xv*wv4.y; av[2] += xv*wv4.z; av[3] += xv*wv4.w;
    }
    *(float4*)&qkt[tok][c4] = *(float4*)aq;
    *(float4*)&vvt[tok][c4] = *(float4*)av;
    __syncthreads();

    int p = tid >> 2;
    int ptok = p >> 2, head = p & 3;
    int sub = tid & 3;
    int e0 = sub * 4;
    int t = t0 + ptok;
    float4 qf4 = *(const float4*)&qkt[ptok][head*16 + e0];
    float nsq = qf4.x*qf4.x + qf4.y*qf4.y + qf4.z*qf4.z + qf4.w*qf4.w;
    nsq += __shfl_xor(nsq,1); nsq += __shfl_xor(nsq,2);
    float inv = 1.f / fmaxf(sqrtf(nsq), 1e-12f);
    float qe[4] = {qf4.x, qf4.y, qf4.z, qf4.w};
    unsigned wq[4], wk[4];
    #pragma unroll
    for (int i=0;i<4;i++){
        float xq = qe[i]*0.25f;
        unsigned qh = rnbf(xq);
        unsigned ql = rnbf(xq - bf2f(qh));
        wq[i] = qh | (ql<<16);
        float xk = qe[i]*inv;
        unsigned kh = rnbf(xk);
        unsigned kl = rnbf(xk - bf2f(kh));
        wk[i] = kh | (kl<<16);
    }
    float4 vf4 = *(const float4*)&vvt[ptok][head*16 + e0];
    float ve[4] = {vf4.x, vf4.y, vf4.z, vf4.w};
    unsigned wv1[4], wv3[4];
    #pragma unroll
    for (int i=0;i<4;i++){
        unsigned vh_, vm_, vl_;
        split3(ve[i], vh_, vm_, vl_);
        wv1[i] = vh_ | (vm_<<16);
        wv3[i] = vl_ | (vh_<<16);
    }
    size_t sb = (((size_t)(b*NHEADS+head))*LSEQ + t)*64;
    *(uint4*)&qkvs[sb + e0]      = *(uint4*)wq;
    *(uint4*)&qkvs[sb + 16 + e0] = *(uint4*)wk;
    *(uint4*)&qkvs[sb + 32 + e0] = *(uint4*)wv1;
    *(uint4*)&qkvs[sb + 48 + e0] = *(uint4*)wv3;

    float qf[16];
    {
        float4 a0 = *(const float4*)&qkt[ptok][head*16 + 0];
        float4 a1 = *(const float4*)&qkt[ptok][head*16 + 4];
        float4 a2 = *(const float4*)&qkt[ptok][head*16 + 8];
        float4 a3 = *(const float4*)&qkt[ptok][head*16 + 12];
        qf[0]=a0.x; qf[1]=a0.y; qf[2]=a0.z; qf[3]=a0.w;
        qf[4]=a1.x; qf[5]=a1.y; qf[6]=a1.z; qf[7]=a1.w;
        qf[8]=a2.x; qf[9]=a2.y; qf[10]=a2.z; qf[11]=a2.w;
        qf[12]=a3.x; qf[13]=a3.y; qf[14]=a3.z; qf[15]=a3.w;
    }
    int nh = sub;
    float rv[10];
    #pragma unroll
    for (int i=0;i<10;i++) {
        float acc = 0.f;
        #pragma unroll
        for (int f=0; f<16; f++) acc += qf[f]*rots[(f*NHASH+nh)*10 + i];
        rv[i] = acc;
    }
    float best = rv[0]; int bi = 0;
    #pragma unroll
    for (int i=1;i<10;i++) if (rv[i] > best) { best = rv[i]; bi = i; }
    #pragma unroll
    for (int i=0;i<10;i++) if (-rv[i] > best) { best = -rv[i]; bi = 10+i; }
    buckets[((size_t)(b*NHEADS+head)*NHASH + nh)*LSEQ + t] = bi;
}

// ---------------- counting sort per (bh, hash): stable, ballot-ranked ----------------
__global__ __launch_bounds__(64) void k_sort(
    const int* __restrict__ buckets, int* __restrict__ sorted)
{
    __shared__ int hist[20];
    __shared__ int startl[20];
    int lane = threadIdx.x;
    int gidx = blockIdx.x;
    const int* bk = buckets + (size_t)gidx * LSEQ;
    int* dst = sorted + (size_t)gidx * LSEQ;
    if (lane < 20) hist[lane] = 0;
    __syncthreads();
    int myb[20];
    for (int ch = 0; ch < 20; ch++) {
        myb[ch] = bk[ch*64 + lane];
        atomicAdd(&hist[myb[ch]], 1);
    }
    __syncthreads();
    if (lane == 0) {
        int acc = 0;
        for (int b2 = 0; b2 < 20; b2++) { startl[b2] = acc; acc += hist[b2]; }
    }
    __syncthreads();
    unsigned long long below = (lane == 63) ? 0x7fffffffffffffffull
                                            : ((1ull << lane) - 1ull);
    for (int ch = 0; ch < 20; ch++) {
        int bv = myb[ch];
        unsigned long long mymask = 0, ownmask = 0;
        #pragma unroll
        for (int b2 = 0; b2 < 20; b2++) {
            unsigned long long m2 = __ballot(bv == b2);
            if (b2 == bv)   mymask  = m2;
            if (b2 == lane) ownmask = m2;
        }
        int rank = __popcll(mymask & below);
        int base = startl[bv];
        dst[base + rank] = ch*64 + lane;
        __syncthreads();
        if (lane < 20) startl[lane] += __popcll(ownmask);
        __syncthreads();
    }
}

// ---------------- chunked attention v8: slim LDS (B2=rot16, P-lo u16), interleaved gathers ----------------
// LDS 36.9 KB -> 4 blocks/CU
__global__ __launch_bounds__(256) void k_attn(
    const unsigned* __restrict__ qkvs,
    const int* __restrict__ sorted, float* __restrict__ o_hash, float* __restrict__ slog)
{
    __shared__ __align__(16) unsigned SM[9216];
    unsigned* Va1 = SM;                    // [kt8][dh16][key16] kt-stride 328, dh-stride 20
    unsigned* Va3 = SM + 2624;
    unsigned* Ka1 = SM + 5248;             // [key128][16] stride 20 (phase 1)
    unsigned* Pa1 = SM + 5248;             // phase 2 alias: [t2][row64][key16] stride 20
    unsigned short* Pa2h = (unsigned short*)(SM + 7808);  // 2560 u16 (P lo)
    int* kposS = (int*)(SM + 9088);

    int tid = threadIdx.x;
    int bh = blockIdx.x / NCHUNK;
    int c  = blockIdx.x % NCHUNK;
    int h  = c / NBUK, cc = c % NBUK;
    int cp = (c + NCHUNK - 1) % NCHUNK;
    int hp = cp / NBUK, ccp = cp % NBUK;

    int key = tid & 127;
    int pos = (key < 64)
        ? sorted[((size_t)bh*NHASH + h)*LSEQ + cc*64 + key]
        : sorted[((size_t)bh*NHASH + hp)*LSEQ + ccp*64 + (key-64)];
    size_t srow = ((size_t)bh*LSEQ + pos)*64;
    if (tid < 128) {
        kposS[key] = pos;
        const uint4* kr = (const uint4*)(qkvs + srow + 16);
        #pragma unroll
        for (int e4=0; e4<4; e4++)
            *(uint4*)&Ka1[key*20 + e4*4] = kr[e4];
    } else {
        const uint4* v1r = (const uint4*)(qkvs + srow + 32);
        const uint4* v3r = (const uint4*)(qkvs + srow + 48);
        int kt = key >> 4, jl = key & 15;
        int lb = kt*328 + jl;
        #pragma unroll
        for (int e4=0; e4<4; e4++){
            uint4 a = v1r[e4], c2 = v3r[e4];
            unsigned aa[4] = {a.x,a.y,a.z,a.w};
            unsigned cb[4] = {c2.x,c2.y,c2.z,c2.w};
            #pragma unroll
            for (int i=0;i<4;i++){
                int d = e4*4 + i;
                Va1[lb + d*20] = aa[i];
                Va3[lb + d*20] = cb[i];
            }
        }
    }
    __syncthreads();

    int w = tid >> 6, lane = tid & 63;
    int quad = lane >> 4, col = lane & 15;

    int qgpos = kposS[16*w + col];
    FU4 QA;
    QA.v = *(const uint4*)(qkvs + ((size_t)bh*LSEQ + qgpos)*64 + quad*4);
    frag_ab qA = QA.f;

    frag_c acc[8];
    #pragma unroll
    for (int nt=0; nt<8; nt++){
        FU4 B1, B2;
        B1.v = *(const uint4*)&Ka1[(nt*16+col)*20 + 4*quad];
        B2.v = rot16v(B1.v);
        frag_c a = {0.f,0.f,0.f,0.f};
        a = __builtin_amdgcn_mfma_f32_16x16x32_bf16(qA, B1.f, a, 0, 0, 0);
        a = __builtin_amdgcn_mfma_f32_16x16x32_bf16(qA, B2.f, a, 0, 0, 0);
        acc[nt] = a;
    }
    int qp[4];
    #pragma unroll
    for (int reg=0; reg<4; reg++) qp[reg] = kposS[16*w + quad*4 + reg];
    #pragma unroll
    for (int nt=0; nt<8; nt++){
        int kp2 = kposS[nt*16 + col];
        #pragma unroll
        for (int reg=0; reg<4; reg++)
            if (kp2 == qp[reg]) acc[nt][reg] = -5e4f;
    }
    float mx[4] = {-3.4e38f,-3.4e38f,-3.4e38f,-3.4e38f};
    #pragma unroll
    for (int nt=0; nt<8; nt++)
        #pragma unroll
        for (int reg=0; reg<4; reg++) mx[reg] = fmaxf(mx[reg], acc[nt][reg]);
    #pragma unroll
    for (int reg=0; reg<4; reg++){
        float m2 = mx[reg];
        m2 = fmaxf(m2, __shfl_xor(m2, 1)); m2 = fmaxf(m2, __shfl_xor(m2, 2));
        m2 = fmaxf(m2, __shfl_xor(m2, 4)); m2 = fmaxf(m2, __shfl_xor(m2, 8));
        mx[reg] = m2;
    }
    float sm2[4] = {0.f,0.f,0.f,0.f};
    #pragma unroll
    for (int nt=0; nt<8; nt++)
        #pragma unroll
        for (int reg=0; reg<4; reg++){
            float e = __expf(acc[nt][reg] - mx[reg]);
            acc[nt][reg] = e; sm2[reg] += e;
        }
    #pragma unroll
    for (int reg=0; reg<4; reg++){
        float s2 = sm2[reg];
        s2 += __shfl_xor(s2, 1); s2 += __shfl_xor(s2, 2);
        s2 += __shfl_xor(s2, 4); s2 += __shfl_xor(s2, 8);
        sm2[reg] = s2;
    }
    float invs[4];
    #pragma unroll
    for (int reg=0; reg<4; reg++) invs[reg] = 1.f / sm2[reg];
    if (col == 0) {
        #pragma unroll
        for (int reg=0; reg<4; reg++)
            slog[((size_t)bh*NHASH + h)*LSEQ + qp[reg]] = mx[reg] + __logf(sm2[reg]);
    }

    frag_c o = {0.f,0.f,0.f,0.f};
    __syncthreads();   // Ka1 dead -> Pa1 alias safe
    #pragma unroll
    for (int pass=0; pass<4; pass++){
        #pragma unroll
        for (int t2=0; t2<2; t2++){
            int nt = pass*2 + t2;
            #pragma unroll
            for (int reg=0; reg<4; reg++){
                float p = acc[nt][reg] * invs[reg];
                unsigned ph_, pm_, pl_;
                split3(p, ph_, pm_, pl_);
                int idx = t2*1280 + (16*w + 4*quad + reg)*20 + col;
                Pa1[idx] = ph_ | (pm_<<16);
                Pa2h[idx] = (unsigned short)pl_;
            }
        }
        __syncthreads();
        #pragma unroll
        for (int t2=0; t2<2; t2++){
            int ktg = pass*2 + t2;
            FU4 A1, A2, B1, B2, B3;
            int pidx = t2*1280 + (16*w + col)*20 + 4*quad;
            A1.v = *(const uint4*)&Pa1[pidx];
            uint2 z = *(const uint2*)&Pa2h[pidx];
            A2.v.x = (A1.v.x & 0xffffu) | (z.x << 16);
            A2.v.y = (A1.v.y & 0xffffu) | (z.x & 0xffff0000u);
            A2.v.z = (A1.v.z & 0xffffu) | (z.y << 16);
            A2.v.w = (A1.v.w & 0xffffu) | (z.y & 0xffff0000u);
            int vidx = ktg*328 + col*20 + 4*quad;
            B1.v = *(const uint4*)&Va1[vidx];
            B2.v = rot16v(B1.v);
            B3.v = *(const uint4*)&Va3[vidx];
            o = __builtin_amdgcn_mfma_f32_16x16x32_bf16(A1.f, B1.f, o, 0, 0, 0);
            o = __builtin_amdgcn_mfma_f32_16x16x32_bf16(A1.f, B2.f, o, 0, 0, 0);
            o = __builtin_amdgcn_mfma_f32_16x16x32_bf16(A2.f, B3.f, o, 0, 0, 0);
        }
        if (pass < 3) __syncthreads();
    }
    size_t obase = ((size_t)bh*NHASH + h)*LSEQ;
    #pragma unroll
    for (int reg=0; reg<4; reg++)
        o_hash[(obase + qp[reg])*DHD + col] = o[reg];
}

// ---------------- fused tail v4: B2=rot16(B1); optional fused output projection ----------------
__global__ __launch_bounds__(256) void k_tail(
    const float* __restrict__ o_hash, const float* __restrict__ slog,
    const unsigned* __restrict__ wo_s, const float* __restrict__ wo_b,
    const float* __restrict__ g2, const float* __restrict__ b2t,
    const unsigned* __restrict__ w1_s, const float* __restrict__ b1,
    const unsigned* __restrict__ w2_s, const float* __restrict__ b2f,
    float* __restrict__ x1, float* __restrict__ x2,
    const float* __restrict__ out_w, const float* __restrict__ out_b,
    float* __restrict__ y, int do_out)
{
    __shared__ unsigned cA1[1024], cA2[1024];
    __shared__ unsigned xA1[1024], xA2[1024];
    __shared__ unsigned gA1[4096], gA2[4096];
    __shared__ float lnS[64], lnQ[64];
    float* red = (float*)gA1;

    int tid = threadIdx.x;
    int b  = blockIdx.x / 80;
    int t0 = (blockIdx.x % 80) * 16;
    int w = tid >> 6, lane = tid & 63;
    int quad = lane >> 4, col = lane & 15;

    {
        int tok = tid >> 4;
        int dg  = tid & 15;
        int d0  = dg * 4;
        int kt  = dg >> 2;
        int t = t0 + tok;
        int bh = b*NHEADS + kt;
        float sl[4];
        #pragma unroll
        for (int nh=0; nh<4; nh++) sl[nh] = slog[((size_t)bh*NHASH + nh)*LSEQ + t];
        float mx = fmaxf(fmaxf(sl[0],sl[1]), fmaxf(sl[2],sl[3]));
        float wgt[4]; float wsum = 0.f;
        #pragma unroll
        for (int nh=0; nh<4; nh++){ wgt[nh] = __expf(sl[nh]-mx); wsum += wgt[nh]; }
        float iv = 1.f/wsum;
        float a4[4] = {0.f,0.f,0.f,0.f};
        #pragma unroll
        for (int nh=0; nh<4; nh++){
            float4 oh = *(const float4*)&o_hash[(((size_t)bh*NHASH + nh)*LSEQ + t)*DHD + (d0 & 15)];
            float wn = wgt[nh]*iv;
            a4[0] += wn*oh.x; a4[1] += wn*oh.y; a4[2] += wn*oh.z; a4[3] += wn*oh.w;
        }
        int sw = (tok & 7) << 2;
        unsigned cw1[4], cw2[4];
        #pragma unroll
        for (int i=0;i<4;i++){
            unsigned h_, m_, l_;
            split3(a4[i], h_, m_, l_);
            cw1[i] = h_ | (m_<<16);
            cw2[i] = h_ | (l_<<16);
        }
        *(uint4*)&cA1[tok*64 + (d0 ^ sw)] = *(uint4*)cw1;
        *(uint4*)&cA2[tok*64 + (d0 ^ sw)] = *(uint4*)cw2;
    }
    __syncthreads();
    FU4 aA1[4], aA2[4];
    {
        int sw = (col & 7) << 2;
        #pragma unroll
        for (int kt=0; kt<4; kt++){
            int word = (kt*16 + quad*4) ^ sw;
            aA1[kt].v = *(const uint4*)&cA1[col*64 + word];
            aA2[kt].v = *(const uint4*)&cA2[col*64 + word];
        }
    }

    frag_c awo = {0.f,0.f,0.f,0.f};
    #pragma unroll
    for (int kt=0; kt<4; kt++){
        FU4 B1, B2, B3;
        int bidx = ((kt*4 + w)*16 + col)*16 + quad*4;
        B1.v = *(const uint4*)&wo_s[bidx];
        B2.v = rot16v(B1.v);
        B3.v = *(const uint4*)&wo_s[bidx + 4096];
        awo = __builtin_amdgcn_mfma_f32_16x16x32_bf16(aA1[kt].f, B1.f, awo, 0, 0, 0);
        awo = __builtin_amdgcn_mfma_f32_16x16x32_bf16(aA1[kt].f, B2.f, awo, 0, 0, 0);
        awo = __builtin_amdgcn_mfma_f32_16x16x32_bf16(aA2[kt].f, B3.f, awo, 0, 0, 0);
    }
    int cg = w*16 + col;
    float x1n[4];
    float s1[4], s2[4];
    {
        float wb = wo_b[cg];
        #pragma unroll
        for (int reg=0; reg<4; reg++){
            int rg = t0 + quad*4 + reg;
            size_t xi = ((size_t)b*LSEQ + rg)*DM + cg;
            float xv = x1[xi] + awo[reg] + wb;
            x1[xi] = xv;
            x1n[reg] = xv;
            s1[reg] = xv; s2[reg] = xv*xv;
        }
    }
    #pragma unroll
    for (int reg=0; reg<4; reg++){
        float a = s1[reg], q = s2[reg];
        a += __shfl_xor(a,1); a += __shfl_xor(a,2); a += __shfl_xor(a,4); a += __shfl_xor(a,8);
        q += __shfl_xor(q,1); q += __shfl_xor(q,2); q += __shfl_xor(q,4); q += __shfl_xor(q,8);
        s1[reg] = a; s2[reg] = q;
    }
    if (col == 0) {
        #pragma unroll
        for (int reg=0; reg<4; reg++){
            lnS[w*16 + quad*4 + reg] = s1[reg];
            lnQ[w*16 + quad*4 + reg] = s2[reg];
        }
    }
    __syncthreads();
    float mean[4], rstd[4];
    #pragma unroll
    for (int reg=0; reg<4; reg++){
        int tok = quad*4 + reg;
        float a = lnS[tok] + lnS[16+tok] + lnS[32+tok] + lnS[48+tok];
        float q = lnQ[tok] + lnQ[16+tok] + lnQ[32+tok] + lnQ[48+tok];
        mean[reg] = a*(1.f/64.f);
        float var = q*(1.f/64.f) - mean[reg]*mean[reg];
        rstd[reg] = 1.f/sqrtf(var + 1e-5f);
    }
    {
        float gv = g2[cg], bv = b2t[cg];
        #pragma unroll
        for (int reg=0; reg<4; reg++){
            int row = quad*4 + reg;
            float xv = (x1n[reg]-mean[reg])*rstd[reg]*gv + bv;
            unsigned h_, m_, l_;
            split3(xv, h_, m_, l_);
            int word = cg ^ ((row & 7) << 2);
            xA1[row*64 + word] = h_ | (m_<<16);
            xA2[row*64 + word] = h_ | (l_<<16);
        }
    }
    __syncthreads();
    FU4 xa1[4], xa2[4];
    {
        int sw = (col & 7) << 2;
        #pragma unroll
        for (int kt=0; kt<4; kt++){
            int word = (kt*16 + quad*4) ^ sw;
            xa1[kt].v = *(const uint4*)&xA1[col*64 + word];
            xa2[kt].v = *(const uint4*)&xA2[col*64 + word];
        }
    }

    unsigned* myg1 = gA1 + w*1024;
    unsigned* myg2 = gA2 + w*1024;
    #pragma unroll
    for (int ntl=0; ntl<4; ntl++){
        int nt = w*4 + ntl;
        frag_c a = {0.f,0.f,0.f,0.f};
        #pragma unroll
        for (int kt=0; kt<4; kt++){
            FU4 B1, B2, B3;
            int bidx = ((kt*16 + nt)*16 + col)*16 + quad*4;
            B1.v = *(const uint4*)&w1_s[bidx];
            B2.v = rot16v(B1.v);
            B3.v = *(const uint4*)&w1_s[bidx + 16384];
            a = __builtin_amdgcn_mfma_f32_16x16x32_bf16(xa1[kt].f, B1.f, a, 0, 0, 0);
            a = __builtin_amdgcn_mfma_f32_16x16x32_bf16(xa1[kt].f, B2.f, a, 0, 0, 0);
            a = __builtin_amdgcn_mfma_f32_16x16x32_bf16(xa2[kt].f, B3.f, a, 0, 0, 0);
        }
        float bb = b1[nt*16 + col];
        #pragma unroll
        for (int reg=0; reg<4; reg++){
            float xx = a[reg] + bb;
            float ge = 0.5f*xx*(1.f + erff(xx*0.70710678118654752f));
            unsigned h_, m_, l_;
            split3(ge, h_, m_, l_);
            int row = quad*4 + reg;
            int word = (ntl*16 + col) ^ ((row & 7) << 2);
            myg1[row*64 + word] = h_ | (m_<<16);
            myg2[row*64 + word] = h_ | (l_<<16);
        }
    }
    frag_c aw2[4] = {{0,0,0,0},{0,0,0,0},{0,0,0,0},{0,0,0,0}};
    {
        int sw = (col & 7) << 2;
        #pragma unroll
        for (int kt2=0; kt2<4; kt2++){
            FU4 A1, A2;
            int word = (kt2*16 + quad*4) ^ sw;
            A1.v = *(const uint4*)&myg1[col*64 + word];
            A2.v = *(const uint4*)&myg2[col*64 + word];
            int kg = w*4 + kt2;
            #pragma unroll
            for (int nt2=0; nt2<4; nt2++){
                FU4 B1, B2, B3;
                int bidx = ((kg*4 + nt2)*16 + col)*16 + quad*4;
                B1.v = *(const uint4*)&w2_s[bidx];
                B2.v = rot16v(B1.v);
                B3.v = *(const uint4*)&w2_s[bidx + 16384];
                aw2[nt2] = __builtin_amdgcn_mfma_f32_16x16x32_bf16(A1.f, B1.f, aw2[nt2], 0, 0, 0);
                aw2[nt2] = __builtin_amdgcn_mfma_f32_16x16x32_bf16(A1.f, B2.f, aw2[nt2], 0, 0, 0);
                aw2[nt2] = __builtin_amdgcn_mfma_f32_16x16x32_bf16(A2.f, B3.f, aw2[nt2], 0, 0, 0);
            }
        }
    }
    __syncthreads();
    #pragma unroll
    for (int nt2=0; nt2<4; nt2++)
        #pragma unroll
        for (int reg=0; reg<4; reg++)
            red[((w*4 + nt2)*4 + reg)*64 + lane] = aw2[nt2][reg];
    __syncthreads();
    float x2f[4];
    {
        float bb = b2f[cg];
        #pragma unroll
        for (int reg=0; reg<4; reg++){
            float v = red[((0*4 + w)*4 + reg)*64 + lane]
                    + red[((1*4 + w)*4 + reg)*64 + lane]
                    + red[((2*4 + w)*4 + reg)*64 + lane]
                    + red[((3*4 + w)*4 + reg)*64 + lane];
            int rg = t0 + quad*4 + reg;
            size_t xi = ((size_t)b*LSEQ + rg)*DM + cg;
            float nv = x2[xi] + v + bb;
            x2[xi] = nv;
            x2f[reg] = nv;
        }
    }
    if (do_out) {
        float ow = out_w[cg];
        float part[4];
        #pragma unroll
        for (int reg=0; reg<4; reg++){
            float p = (x1n[reg] + x2f[reg]) * 0.5f * ow;
            p += __shfl_xor(p,1); p += __shfl_xor(p,2); p += __shfl_xor(p,4); p += __shfl_xor(p,8);
            part[reg] = p;
        }
        __syncthreads();
        if (col == 0) {
            #pragma unroll
            for (int reg=0; reg<4; reg++)
                lnS[w*16 + quad*4 + reg] = part[reg];
        }
        __syncthreads();
        if (tid < 16) {
            int t = t0 + tid;
            if (t < L0SEQ) {
                float v2 = lnS[tid] + lnS[16+tid] + lnS[32+tid] + lnS[48+tid];
                y[(size_t)b*L0SEQ + t] = v2 + out_b[0];
            }
        }
    }
}

extern "C" void kernel_launch(void* const* d_in, const int* in_sizes, int n_in,
                              void* d_out, int out_size, void* d_ws, size_t ws_size,
                              hipStream_t stream)
{
    const float* wave  = (const float*)d_in[0];
    const float* in_w  = (const float*)d_in[1];
    const float* in_b  = (const float*)d_in[2];
    const float* ln1_g = (const float*)d_in[3];
    const float* ln1_b = (const float*)d_in[4];
    const float* wqk   = (const float*)d_in[5];
    const float* wv    = (const float*)d_in[6];
    const float* wo_w  = (const float*)d_in[7];
    const float* wo_b  = (const float*)d_in[8];
    const float* rot   = (const float*)d_in[9];
    const float* ln2_g = (const float*)d_in[10];
    const float* ln2_b = (const float*)d_in[11];
    const float* w1    = (const float*)d_in[12];
    const float* b1    = (const float*)d_in[13];
    const float* w2    = (const float*)d_in[14];
    const float* b2    = (const float*)d_in[15];
    const float* out_w = (const float*)d_in[16];
    const float* out_b = (const float*)d_in[17];
    float* y = (float*)d_out;

    float* ws = (float*)d_ws;
    float* x1      = ws;                       // XSZ f32
    float* x2      = x1 + XSZ;                 // XSZ f32
    unsigned* qkvs = (unsigned*)(x2 + XSZ);    // 4*QKSZ u32 (interleaved)
    float* o_hash  = (float*)(qkvs + 4*QKSZ);  // OHSZ f32
    float* slogb   = o_hash + OHSZ;            // SLSZ f32
    int* buckets   = (int*)(slogb + SLSZ);     // SLSZ int
    int* sorted    = buckets + SLSZ;           // SLSZ int
    unsigned* wsplit = (unsigned*)(sorted + SLSZ); // 294912 u32

    k_init<<<5696, 256, 0, stream>>>(wave, in_w, in_b, x1, x2, wo_w, w1, w2, wsplit);
    for (int layer = 0; layer < 4; layer++) {
        k_qkv<<<NBATCH*80, 256, 0, stream>>>(x2, ln1_g + layer*64, ln1_b + layer*64,
                                       wqk + layer*4096, wv + layer*4096, rot + layer*640,
                                       qkvs, buckets);
        k_sort<<<256, 64, 0, stream>>>(buckets, sorted);
        k_attn<<<NBH*NCHUNK, 256, 0, stream>>>(qkvs, sorted, o_hash, slogb);
        k_tail<<<NBATCH*LSEQ/16, 256, 0, stream>>>(o_hash, slogb,
                                        wsplit + layer*8192, wo_b + layer*64,
                                        ln2_g + layer*64, ln2_b + layer*64,
                                        wsplit + 32768 + layer*32768, b1 + layer*256,
                                        wsplit + 163840 + layer*32768, b2 + layer*64,
                                        x1, x2,
                                        out_w, out_b, y, (layer == 3) ? 1 : 0);
    }
}

// Round 12
// 562.282 us; speedup vs baseline: 1.2277x; 1.0001x over previous
//
#include <hip/hip_runtime.h>
#include <math.h>

#define LSEQ 1280
#define L0SEQ 1250
#define DM 64
#define NHEADS 4
#define DHD 16
#define NHASH 4
#define NBUK 20
#define NCHUNK 80
#define FFD 256
#define NBATCH 16
#define NBH 64

#define XSZ (NBATCH*LSEQ*DM)        // 1310720
#define QKSZ (NBH*LSEQ*DHD)         // 1310720
#define OHSZ (NBH*NHASH*LSEQ*DHD)   // 5242880
#define SLSZ (NBH*NHASH*LSEQ)       // 327680

typedef __attribute__((ext_vector_type(8))) short frag_ab;   // 8 bf16
typedef __attribute__((ext_vector_type(4))) float frag_c;    // 4 fp32

union FU4 { uint4 v; frag_ab f; };

__device__ __forceinline__ unsigned rnbf(float x){
    unsigned b = __float_as_uint(x);
    return (b + 0x7fffu + ((b >> 16) & 1u)) >> 16;
}
__device__ __forceinline__ float bf2f(unsigned h){ return __uint_as_float(h << 16); }
__device__ __forceinline__ unsigned rot16(unsigned x){ return (x >> 16) | (x << 16); }
__device__ __forceinline__ uint4 rot16v(uint4 a){
    uint4 r; r.x=rot16(a.x); r.y=rot16(a.y); r.z=rot16(a.z); r.w=rot16(a.w); return r;
}

// exact triple split (truncation): x = h + m + l
__device__ __forceinline__ void split3(float x, unsigned& h, unsigned& m, unsigned& l){
    unsigned bx = __float_as_uint(x);
    h = bx >> 16;
    float r = x - __uint_as_float(bx & 0xffff0000u);
    unsigned br = __float_as_uint(r);
    m = br >> 16;
    float r2 = r - __uint_as_float(br & 0xffff0000u);
    l = __float_as_uint(r2) >> 16;
}

// ---------------- init: embed (blocks 0..5119) + weight pre-split (blocks 5120..5695) ----------------
__global__ __launch_bounds__(256) void k_init(
    const float* __restrict__ wave, const float* __restrict__ in_w, const float* __restrict__ in_b,
    float* __restrict__ x1, float* __restrict__ x2,
    const float* __restrict__ wo_w, const float* __restrict__ w1,
    const float* __restrict__ w2, unsigned* __restrict__ wsplit)
{
    if (blockIdx.x < 5120) {
        int idx = blockIdx.x * 256 + threadIdx.x;
        int d = idx & 63;
        int t = idx >> 6;
        int b = t / LSEQ;
        int tt = t % LSEQ;
        float v0 = 0.f, v1 = 0.f;
        if (tt < L0SEQ) {
            v0 = wave[(size_t)(b*2+0)*L0SEQ + tt];
            v1 = wave[(size_t)(b*2+1)*L0SEQ + tt];
        }
        float x = v0 * in_w[d] + v1 * in_w[64 + d] + in_b[d];
        x1[idx] = x;
        x2[idx] = x;
    } else {
        int gid = (blockIdx.x - 5120) * 256 + threadIdx.x;   // < 147456 exactly
        int l = gid / 36864;
        int r = gid % 36864;
        float src; unsigned* dst; int idx; int stride;
        if (r < 4096) {                 // wo: K=64, N=64
            int k = r >> 6, n = r & 63;
            src = wo_w[l*4096 + k*64 + n];
            dst = wsplit + l*8192;
            idx = (((k>>4)*4 + (n>>4))*16 + (n&15))*16 + (k&15);
            stride = 4096;
        } else if (r < 20480) {         // w1: K=64, N=256
            int rr = r - 4096;
            int k = rr >> 8, n = rr & 255;
            src = w1[l*16384 + k*256 + n];
            dst = wsplit + 32768 + l*32768;
            idx = (((k>>4)*16 + (n>>4))*16 + (n&15))*16 + (k&15);
            stride = 16384;
        } else {                        // w2: K=256, N=64
            int rr = r - 20480;
            int k = rr >> 6, n = rr & 63;
            src = w2[l*16384 + k*64 + n];
            dst = wsplit + 163840 + l*32768;
            idx = (((k>>4)*4 + (n>>4))*16 + (n&15))*16 + (k&15);
            stride = 16384;
        }
        unsigned h, m, lo;
        split3(src, h, m, lo);
        dst[idx]          = h | (m<<16);
        dst[idx + stride] = lo | (h<<16);
    }
}

// ---------------- LN + QK/V proj + bucketing + pre-split (interleaved 256B/token rows) ----------------
__global__ __launch_bounds__(256) void k_qkv(
    const float* __restrict__ x2, const float* __restrict__ g, const float* __restrict__ bta,
    const float* __restrict__ wqk, const float* __restrict__ wv, const float* __restrict__ rot,
    unsigned* __restrict__ qkvs, int* __restrict__ buckets)
{
    __shared__ float xln[16][68];
    __shared__ float qkt[16][68];
    __shared__ float vvt[16][68];
    __shared__ float rots[640];
    int tid = threadIdx.x;
    int b  = blockIdx.x / 80;
    int t0 = (blockIdx.x % 80) * 16;
    int tok = tid >> 4;
    int cg  = tid & 15;
    int c4  = cg * 4;

    for (int i = tid; i < 640; i += 256) rots[i] = rot[i];

    float4 xv4 = *(const float4*)&x2[((size_t)b*LSEQ + t0 + tok)*DM + c4];
    float s = xv4.x + xv4.y + xv4.z + xv4.w;
    float ss = xv4.x*xv4.x + xv4.y*xv4.y + xv4.z*xv4.z + xv4.w*xv4.w;
    s  += __shfl_xor(s,1);  s  += __shfl_xor(s,2);  s  += __shfl_xor(s,4);  s  += __shfl_xor(s,8);
    ss += __shfl_xor(ss,1); ss += __shfl_xor(ss,2); ss += __shfl_xor(ss,4); ss += __shfl_xor(ss,8);
    float m = s * (1.f/64.f);
    float vr = ss * (1.f/64.f) - m*m;
    float rstd = 1.f / sqrtf(vr + 1e-5f);
    {
        float4 g4 = *(const float4*)&g[c4];
        float4 b4 = *(const float4*)&bta[c4];
        float4 o;
        o.x = (xv4.x-m)*rstd*g4.x + b4.x;
        o.y = (xv4.y-m)*rstd*g4.y + b4.y;
        o.z = (xv4.z-m)*rstd*g4.z + b4.z;
        o.w = (xv4.w-m)*rstd*g4.w + b4.w;
        *(float4*)&xln[tok][c4] = o;
    }
    __syncthreads();

    float aq[4] = {0,0,0,0}, av[4] = {0,0,0,0};
    for (int f = 0; f < 64; f++) {
        float4 wq4 = *(const float4*)&wqk[f*64 + c4];
        float4 wv4 = *(const float4*)&wv [f*64 + c4];
        float xv = xln[tok][f];
        aq[0] += xv*wq4.x; aq[1] += xv*wq4.y; aq[2] += xv*wq4.z; aq[3] += xv*wq4.w;
        av[0] += xv*wv4.x; av[1] += xv*wv4.y; av[2] += xv*wv4.z; av[3] += xv*wv4.w;
    }
    *(float4*)&qkt[tok][c4] = *(float4*)aq;
    *(float4*)&vvt[tok][c4] = *(float4*)av;
    __syncthreads();

    int p = tid >> 2;
    int ptok = p >> 2, head = p & 3;
    int sub = tid & 3;
    int e0 = sub * 4;
    int t = t0 + ptok;
    float4 qf4 = *(const float4*)&qkt[ptok][head*16 + e0];
    float nsq = qf4.x*qf4.x + qf4.y*qf4.y + qf4.z*qf4.z + qf4.w*qf4.w;
    nsq += __shfl_xor(nsq,1); nsq += __shfl_xor(nsq,2);
    float inv = 1.f / fmaxf(sqrtf(nsq), 1e-12f);
    float qe[4] = {qf4.x, qf4.y, qf4.z, qf4.w};
    unsigned wq[4], wk[4];
    #pragma unroll
    for (int i=0;i<4;i++){
        float xq = qe[i]*0.25f;
        unsigned qh = rnbf(xq);
        unsigned ql = rnbf(xq - bf2f(qh));
        wq[i] = qh | (ql<<16);
        float xk = qe[i]*inv;
        unsigned kh = rnbf(xk);
        unsigned kl = rnbf(xk - bf2f(kh));
        wk[i] = kh | (kl<<16);
    }
    float4 vf4 = *(const float4*)&vvt[ptok][head*16 + e0];
    float ve[4] = {vf4.x, vf4.y, vf4.z, vf4.w};
    unsigned wv1[4], wv3[4];
    #pragma unroll
    for (int i=0;i<4;i++){
        unsigned vh_, vm_, vl_;
        split3(ve[i], vh_, vm_, vl_);
        wv1[i] = vh_ | (vm_<<16);
        wv3[i] = vl_ | (vh_<<16);
    }
    size_t sb = (((size_t)(b*NHEADS+head))*LSEQ + t)*64;
    *(uint4*)&qkvs[sb + e0]      = *(uint4*)wq;
    *(uint4*)&qkvs[sb + 16 + e0] = *(uint4*)wk;
    *(uint4*)&qkvs[sb + 32 + e0] = *(uint4*)wv1;
    *(uint4*)&qkvs[sb + 48 + e0] = *(uint4*)wv3;

    float qf[16];
    {
        float4 a0 = *(const float4*)&qkt[ptok][head*16 + 0];
        float4 a1 = *(const float4*)&qkt[ptok][head*16 + 4];
        float4 a2 = *(const float4*)&qkt[ptok][head*16 + 8];
        float4 a3 = *(const float4*)&qkt[ptok][head*16 + 12];
        qf[0]=a0.x; qf[1]=a0.y; qf[2]=a0.z; qf[3]=a0.w;
        qf[4]=a1.x; qf[5]=a1.y; qf[6]=a1.z; qf[7]=a1.w;
        qf[8]=a2.x; qf[9]=a2.y; qf[10]=a2.z; qf[11]=a2.w;
        qf[12]=a3.x; qf[13]=a3.y; qf[14]=a3.z; qf[15]=a3.w;
    }
    int nh = sub;
    float rv[10];
    #pragma unroll
    for (int i=0;i<10;i++) {
        float acc = 0.f;
        #pragma unroll
        for (int f=0; f<16; f++) acc += qf[f]*rots[(f*NHASH+nh)*10 + i];
        rv[i] = acc;
    }
    float best = rv[0]; int bi = 0;
    #pragma unroll
    for (int i=1;i<10;i++) if (rv[i] > best) { best = rv[i]; bi = i; }
    #pragma unroll
    for (int i=0;i<10;i++) if (-rv[i] > best) { best = -rv[i]; bi = 10+i; }
    buckets[((size_t)(b*NHEADS+head)*NHASH + nh)*LSEQ + t] = bi;
}

// ---------------- counting sort per (bh, hash): stable, ballot-ranked ----------------
__global__ __launch_bounds__(64) void k_sort(
    const int* __restrict__ buckets, int* __restrict__ sorted)
{
    __shared__ int hist[20];
    __shared__ int startl[20];
    int lane = threadIdx.x;
    int gidx = blockIdx.x;
    const int* bk = buckets + (size_t)gidx * LSEQ;
    int* dst = sorted + (size_t)gidx * LSEQ;
    if (lane < 20) hist[lane] = 0;
    __syncthreads();
    int myb[20];
    for (int ch = 0; ch < 20; ch++) {
        myb[ch] = bk[ch*64 + lane];
        atomicAdd(&hist[myb[ch]], 1);
    }
    __syncthreads();
    if (lane == 0) {
        int acc = 0;
        for (int b2 = 0; b2 < 20; b2++) { startl[b2] = acc; acc += hist[b2]; }
    }
    __syncthreads();
    unsigned long long below = (lane == 63) ? 0x7fffffffffffffffull
                                            : ((1ull << lane) - 1ull);
    for (int ch = 0; ch < 20; ch++) {
        int bv = myb[ch];
        unsigned long long mymask = 0, ownmask = 0;
        #pragma unroll
        for (int b2 = 0; b2 < 20; b2++) {
            unsigned long long m2 = __ballot(bv == b2);
            if (b2 == bv)   mymask  = m2;
            if (b2 == lane) ownmask = m2;
        }
        int rank = __popcll(mymask & below);
        int base = startl[bv];
        dst[base + rank] = ch*64 + lane;
        __syncthreads();
        if (lane < 20) startl[lane] += __popcll(ownmask);
        __syncthreads();
    }
}

// ---------------- chunked attention v9: XCD-colocated (bh = blockIdx&63), 30.9 KB LDS ----------------
// All 80 chunks of one bh land on the same XCD (64 % 8 == 0) -> qkvs rows are L2-resident.
// V-lo stored as bare u16; B3 = vl | (B1<<16). 5 blocks/CU.
__global__ __launch_bounds__(256) void k_attn(
    const unsigned* __restrict__ qkvs,
    const int* __restrict__ sorted, float* __restrict__ o_hash, float* __restrict__ slog)
{
    __shared__ __align__(16) unsigned SM[7904];            // 31616 B
    unsigned* Va1 = SM;                                    // 2624 u32 [kt8][dh16][key16] strides 328/20
    unsigned* Ka1 = SM + 2624;                             // 2560 u32 [key128][16] stride 20 (phase 1)
    unsigned* Pa1 = SM + 2624;                             // phase 2 alias
    unsigned short* Vlh  = (unsigned short*)(SM + 5184);   // 2624 u16 (V lo)
    unsigned short* Pa2h = (unsigned short*)(SM + 6496);   // 2560 u16 (P lo)
    int* kposS = (int*)(SM + 7776);                        // 128 ints

    int tid = threadIdx.x;
    int bh = blockIdx.x & 63;          // XCD swizzle: same bh -> same XCD
    int c  = blockIdx.x >> 6;
    int h  = c / NBUK, cc = c % NBUK;
    int cp = (c + NCHUNK - 1) % NCHUNK;
    int hp = cp / NBUK, ccp = cp % NBUK;

    int key = tid & 127;
    int pos = (key < 64)
        ? sorted[((size_t)bh*NHASH + h)*LSEQ + cc*64 + key]
        : sorted[((size_t)bh*NHASH + hp)*LSEQ + ccp*64 + (key-64)];
    size_t srow = ((size_t)bh*LSEQ + pos)*64;
    if (tid < 128) {
        kposS[key] = pos;
        const uint4* kr = (const uint4*)(qkvs + srow + 16);
        #pragma unroll
        for (int e4=0; e4<4; e4++)
            *(uint4*)&Ka1[key*20 + e4*4] = kr[e4];
    } else {
        const uint4* v1r = (const uint4*)(qkvs + srow + 32);
        const uint4* v3r = (const uint4*)(qkvs + srow + 48);
        int kt = key >> 4, jl = key & 15;
        int lb = kt*328 + jl;
        #pragma unroll
        for (int e4=0; e4<4; e4++){
            uint4 a = v1r[e4], c2 = v3r[e4];
            unsigned aa[4] = {a.x,a.y,a.z,a.w};
            unsigned cb[4] = {c2.x,c2.y,c2.z,c2.w};
            #pragma unroll
            for (int i=0;i<4;i++){
                int d = e4*4 + i;
                Va1[lb + d*20] = aa[i];
                Vlh[lb + d*20] = (unsigned short)(cb[i] & 0xffffu);
            }
        }
    }
    __syncthreads();

    int w = tid >> 6, lane = tid & 63;
    int quad = lane >> 4, col = lane & 15;

    int qgpos = kposS[16*w + col];
    FU4 QA;
    QA.v = *(const uint4*)(qkvs + ((size_t)bh*LSEQ + qgpos)*64 + quad*4);
    frag_ab qA = QA.f;

    frag_c acc[8];
    #pragma unroll
    for (int nt=0; nt<8; nt++){
        FU4 B1, B2;
        B1.v = *(const uint4*)&Ka1[(nt*16+col)*20 + 4*quad];
        B2.v = rot16v(B1.v);
        frag_c a = {0.f,0.f,0.f,0.f};
        a = __builtin_amdgcn_mfma_f32_16x16x32_bf16(qA, B1.f, a, 0, 0, 0);
        a = __builtin_amdgcn_mfma_f32_16x16x32_bf16(qA, B2.f, a, 0, 0, 0);
        acc[nt] = a;
    }
    int qp[4];
    #pragma unroll
    for (int reg=0; reg<4; reg++) qp[reg] = kposS[16*w + quad*4 + reg];
    #pragma unroll
    for (int nt=0; nt<8; nt++){
        int kp2 = kposS[nt*16 + col];
        #pragma unroll
        for (int reg=0; reg<4; reg++)
            if (kp2 == qp[reg]) acc[nt][reg] = -5e4f;
    }
    float mx[4] = {-3.4e38f,-3.4e38f,-3.4e38f,-3.4e38f};
    #pragma unroll
    for (int nt=0; nt<8; nt++)
        #pragma unroll
        for (int reg=0; reg<4; reg++) mx[reg] = fmaxf(mx[reg], acc[nt][reg]);
    #pragma unroll
    for (int reg=0; reg<4; reg++){
        float m2 = mx[reg];
        m2 = fmaxf(m2, __shfl_xor(m2, 1)); m2 = fmaxf(m2, __shfl_xor(m2, 2));
        m2 = fmaxf(m2, __shfl_xor(m2, 4)); m2 = fmaxf(m2, __shfl_xor(m2, 8));
        mx[reg] = m2;
    }
    float sm2[4] = {0.f,0.f,0.f,0.f};
    #pragma unroll
    for (int nt=0; nt<8; nt++)
        #pragma unroll
        for (int reg=0; reg<4; reg++){
            float e = __expf(acc[nt][reg] - mx[reg]);
            acc[nt][reg] = e; sm2[reg] += e;
        }
    #pragma unroll
    for (int reg=0; reg<4; reg++){
        float s2 = sm2[reg];
        s2 += __shfl_xor(s2, 1); s2 += __shfl_xor(s2, 2);
        s2 += __shfl_xor(s2, 4); s2 += __shfl_xor(s2, 8);
        sm2[reg] = s2;
    }
    float invs[4];
    #pragma unroll
    for (int reg=0; reg<4; reg++) invs[reg] = 1.f / sm2[reg];
    if (col == 0) {
        #pragma unroll
        for (int reg=0; reg<4; reg++)
            slog[((size_t)bh*NHASH + h)*LSEQ + qp[reg]] = mx[reg] + __logf(sm2[reg]);
    }

    frag_c o = {0.f,0.f,0.f,0.f};
    __syncthreads();   // Ka1 dead -> Pa1 alias safe
    #pragma unroll
    for (int pass=0; pass<4; pass++){
        #pragma unroll
        for (int t2=0; t2<2; t2++){
            int nt = pass*2 + t2;
            #pragma unroll
            for (int reg=0; reg<4; reg++){
                float p = acc[nt][reg] * invs[reg];
                unsigned ph_, pm_, pl_;
                split3(p, ph_, pm_, pl_);
                int idx = t2*1280 + (16*w + 4*quad + reg)*20 + col;
                Pa1[idx] = ph_ | (pm_<<16);
                Pa2h[idx] = (unsigned short)pl_;
            }
        }
        __syncthreads();
        #pragma unroll
        for (int t2=0; t2<2; t2++){
            int ktg = pass*2 + t2;
            FU4 A1, A2, B1, B2, B3;
            int pidx = t2*1280 + (16*w + col)*20 + 4*quad;
            A1.v = *(const uint4*)&Pa1[pidx];
            uint2 z = *(const uint2*)&Pa2h[pidx];
            A2.v.x = (A1.v.x & 0xffffu) | (z.x << 16);
            A2.v.y = (A1.v.y & 0xffffu) | (z.x & 0xffff0000u);
            A2.v.z = (A1.v.z & 0xffffu) | (z.y << 16);
            A2.v.w = (A1.v.w & 0xffffu) | (z.y & 0xffff0000u);
            int vidx = ktg*328 + col*20 + 4*quad;
            B1.v = *(const uint4*)&Va1[vidx];
            B2.v = rot16v(B1.v);
            uint2 zл = *(const uint2*)&Vlh[vidx];
            B3.v.x = (zл.x & 0xffffu) | (B1.v.x << 16);
            B3.v.y = (zл.x >> 16)     | (B1.v.y << 16);
            B3.v.z = (zл.y & 0xffffu) | (B1.v.z << 16);
            B3.v.w = (zл.y >> 16)     | (B1.v.w << 16);
            o = __builtin_amdgcn_mfma_f32_16x16x32_bf16(A1.f, B1.f, o, 0, 0, 0);
            o = __builtin_amdgcn_mfma_f32_16x16x32_bf16(A1.f, B2.f, o, 0, 0, 0);
            o = __builtin_amdgcn_mfma_f32_16x16x32_bf16(A2.f, B3.f, o, 0, 0, 0);
        }
        if (pass < 3) __syncthreads();
    }
    size_t obase = ((size_t)bh*NHASH + h)*LSEQ;
    #pragma unroll
    for (int reg=0; reg<4; reg++)
        o_hash[(obase + qp[reg])*DHD + col] = o[reg];
}

// ---------------- fused tail v4: B2=rot16(B1); optional fused output projection ----------------
__global__ __launch_bounds__(256) void k_tail(
    const float* __restrict__ o_hash, const float* __restrict__ slog,
    const unsigned* __restrict__ wo_s, const float* __restrict__ wo_b,
    const float* __restrict__ g2, const float* __restrict__ b2t,
    const unsigned* __restrict__ w1_s, const float* __restrict__ b1,
    const unsigned* __restrict__ w2_s, const float* __restrict__ b2f,
    float* __restrict__ x1, float* __restrict__ x2,
    const float* __restrict__ out_w, const float* __restrict__ out_b,
    float* __restrict__ y, int do_out)
{
    __shared__ unsigned cA1[1024], cA2[1024];
    __shared__ unsigned xA1[1024], xA2[1024];
    __shared__ unsigned gA1[4096], gA2[4096];
    __shared__ float lnS[64], lnQ[64];
    float* red = (float*)gA1;

    int tid = threadIdx.x;
    int b  = blockIdx.x / 80;
    int t0 = (blockIdx.x % 80) * 16;
    int w = tid >> 6, lane = tid & 63;
    int quad = lane >> 4, col = lane & 15;

    {
        int tok = tid >> 4;
        int dg  = tid & 15;
        int d0  = dg * 4;
        int kt  = dg >> 2;
        int t = t0 + tok;
        int bh = b*NHEADS + kt;
        float sl[4];
        #pragma unroll
        for (int nh=0; nh<4; nh++) sl[nh] = slog[((size_t)bh*NHASH + nh)*LSEQ + t];
        float mx = fmaxf(fmaxf(sl[0],sl[1]), fmaxf(sl[2],sl[3]));
        float wgt[4]; float wsum = 0.f;
        #pragma unroll
        for (int nh=0; nh<4; nh++){ wgt[nh] = __expf(sl[nh]-mx); wsum += wgt[nh]; }
        float iv = 1.f/wsum;
        float a4[4] = {0.f,0.f,0.f,0.f};
        #pragma unroll
        for (int nh=0; nh<4; nh++){
            float4 oh = *(const float4*)&o_hash[(((size_t)bh*NHASH + nh)*LSEQ + t)*DHD + (d0 & 15)];
            float wn = wgt[nh]*iv;
            a4[0] += wn*oh.x; a4[1] += wn*oh.y; a4[2] += wn*oh.z; a4[3] += wn*oh.w;
        }
        int sw = (tok & 7) << 2;
        unsigned cw1[4], cw2[4];
        #pragma unroll
        for (int i=0;i<4;i++){
            unsigned h_, m_, l_;
            split3(a4[i], h_, m_, l_);
            cw1[i] = h_ | (m_<<16);
            cw2[i] = h_ | (l_<<16);
        }
        *(uint4*)&cA1[tok*64 + (d0 ^ sw)] = *(uint4*)cw1;
        *(uint4*)&cA2[tok*64 + (d0 ^ sw)] = *(uint4*)cw2;
    }
    __syncthreads();
    FU4 aA1[4], aA2[4];
    {
        int sw = (col & 7) << 2;
        #pragma unroll
        for (int kt=0; kt<4; kt++){
            int word = (kt*16 + quad*4) ^ sw;
            aA1[kt].v = *(const uint4*)&cA1[col*64 + word];
            aA2[kt].v = *(const uint4*)&cA2[col*64 + word];
        }
    }

    frag_c awo = {0.f,0.f,0.f,0.f};
    #pragma unroll
    for (int kt=0; kt<4; kt++){
        FU4 B1, B2, B3;
        int bidx = ((kt*4 + w)*16 + col)*16 + quad*4;
        B1.v = *(const uint4*)&wo_s[bidx];
        B2.v = rot16v(B1.v);
        B3.v = *(const uint4*)&wo_s[bidx + 4096];
        awo = __builtin_amdgcn_mfma_f32_16x16x32_bf16(aA1[kt].f, B1.f, awo, 0, 0, 0);
        awo = __builtin_amdgcn_mfma_f32_16x16x32_bf16(aA1[kt].f, B2.f, awo, 0, 0, 0);
        awo = __builtin_amdgcn_mfma_f32_16x16x32_bf16(aA2[kt].f, B3.f, awo, 0, 0, 0);
    }
    int cg = w*16 + col;
    float x1n[4];
    float s1[4], s2[4];
    {
        float wb = wo_b[cg];
        #pragma unroll
        for (int reg=0; reg<4; reg++){
            int rg = t0 + quad*4 + reg;
            size_t xi = ((size_t)b*LSEQ + rg)*DM + cg;
            float xv = x1[xi] + awo[reg] + wb;
            x1[xi] = xv;
            x1n[reg] = xv;
            s1[reg] = xv; s2[reg] = xv*xv;
        }
    }
    #pragma unroll
    for (int reg=0; reg<4; reg++){
        float a = s1[reg], q = s2[reg];
        a += __shfl_xor(a,1); a += __shfl_xor(a,2); a += __shfl_xor(a,4); a += __shfl_xor(a,8);
        q += __shfl_xor(q,1); q += __shfl_xor(q,2); q += __shfl_xor(q,4); q += __shfl_xor(q,8);
        s1[reg] = a; s2[reg] = q;
    }
    if (col == 0) {
        #pragma unroll
        for (int reg=0; reg<4; reg++){
            lnS[w*16 + quad*4 + reg] = s1[reg];
            lnQ[w*16 + quad*4 + reg] = s2[reg];
        }
    }
    __syncthreads();
    float mean[4], rstd[4];
    #pragma unroll
    for (int reg=0; reg<4; reg++){
        int tok = quad*4 + reg;
        float a = lnS[tok] + lnS[16+tok] + lnS[32+tok] + lnS[48+tok];
        float q = lnQ[tok] + lnQ[16+tok] + lnQ[32+tok] + lnQ[48+tok];
        mean[reg] = a*(1.f/64.f);
        float var = q*(1.f/64.f) - mean[reg]*mean[reg];
        rstd[reg] = 1.f/sqrtf(var + 1e-5f);
    }
    {
        float gv = g2[cg], bv = b2t[cg];
        #pragma unroll
        for (int reg=0; reg<4; reg++){
            int row = quad*4 + reg;
            float xv = (x1n[reg]-mean[reg])*rstd[reg]*gv + bv;
            unsigned h_, m_, l_;
            split3(xv, h_, m_, l_);
            int word = cg ^ ((row & 7) << 2);
            xA1[row*64 + word] = h_ | (m_<<16);
            xA2[row*64 + word] = h_ | (l_<<16);
        }
    }
    __syncthreads();
    FU4 xa1[4], xa2[4];
    {
        int sw = (col & 7) << 2;
        #pragma unroll
        for (int kt=0; kt<4; kt++){
            int word = (kt*16 + quad*4) ^ sw;
            xa1[kt].v = *(const uint4*)&xA1[col*64 + word];
            xa2[kt].v = *(const uint4*)&xA2[col*64 + word];
        }
    }

    unsigned* myg1 = gA1 + w*1024;
    unsigned* myg2 = gA2 + w*1024;
    #pragma unroll
    for (int ntl=0; ntl<4; ntl++){
        int nt = w*4 + ntl;
        frag_c a = {0.f,0.f,0.f,0.f};
        #pragma unroll
        for (int kt=0; kt<4; kt++){
            FU4 B1, B2, B3;
            int bidx = ((kt*16 + nt)*16 + col)*16 + quad*4;
            B1.v = *(const uint4*)&w1_s[bidx];
            B2.v = rot16v(B1.v);
            B3.v = *(const uint4*)&w1_s[bidx + 16384];
            a = __builtin_amdgcn_mfma_f32_16x16x32_bf16(xa1[kt].f, B1.f, a, 0, 0, 0);
            a = __builtin_amdgcn_mfma_f32_16x16x32_bf16(xa1[kt].f, B2.f, a, 0, 0, 0);
            a = __builtin_amdgcn_mfma_f32_16x16x32_bf16(xa2[kt].f, B3.f, a, 0, 0, 0);
        }
        float bb = b1[nt*16 + col];
        #pragma unroll
        for (int reg=0; reg<4; reg++){
            float xx = a[reg] + bb;
            float ge = 0.5f*xx*(1.f + erff(xx*0.70710678118654752f));
            unsigned h_, m_, l_;
            split3(ge, h_, m_, l_);
            int row = quad*4 + reg;
            int word = (ntl*16 + col) ^ ((row & 7) << 2);
            myg1[row*64 + word] = h_ | (m_<<16);
            myg2[row*64 + word] = h_ | (l_<<16);
        }
    }
    frag_c aw2[4] = {{0,0,0,0},{0,0,0,0},{0,0,0,0},{0,0,0,0}};
    {
        int sw = (col & 7) << 2;
        #pragma unroll
        for (int kt2=0; kt2<4; kt2++){
            FU4 A1, A2;
            int word = (kt2*16 + quad*4) ^ sw;
            A1.v = *(const uint4*)&myg1[col*64 + word];
            A2.v = *(const uint4*)&myg2[col*64 + word];
            int kg = w*4 + kt2;
            #pragma unroll
            for (int nt2=0; nt2<4; nt2++){
                FU4 B1, B2, B3;
                int bidx = ((kg*4 + nt2)*16 + col)*16 + quad*4;
                B1.v = *(const uint4*)&w2_s[bidx];
                B2.v = rot16v(B1.v);
                B3.v = *(const uint4*)&w2_s[bidx + 16384];
                aw2[nt2] = __builtin_amdgcn_mfma_f32_16x16x32_bf16(A1.f, B1.f, aw2[nt2], 0, 0, 0);
                aw2[nt2] = __builtin_amdgcn_mfma_f32_16x16x32_bf16(A1.f, B2.f, aw2[nt2], 0, 0, 0);
                aw2[nt2] = __builtin_amdgcn_mfma_f32_16x16x32_bf16(A2.f, B3.f, aw2[nt2], 0, 0, 0);
            }
        }
    }
    __syncthreads();
    #pragma unroll
    for (int nt2=0; nt2<4; nt2++)
        #pragma unroll
        for (int reg=0; reg<4; reg++)
            red[((w*4 + nt2)*4 + reg)*64 + lane] = aw2[nt2][reg];
    __syncthreads();
    float x2f[4];
    {
        float bb = b2f[cg];
        #pragma unroll
        for (int reg=0; reg<4; reg++){
            float v = red[((0*4 + w)*4 + reg)*64 + lane]
                    + red[((1*4 + w)*4 + reg)*64 + lane]
                    + red[((2*4 + w)*4 + reg)*64 + lane]
                    + red[((3*4 + w)*4 + reg)*64 + lane];
            int rg = t0 + quad*4 + reg;
            size_t xi = ((size_t)b*LSEQ + rg)*DM + cg;
            float nv = x2[xi] + v + bb;
            x2[xi] = nv;
            x2f[reg] = nv;
        }
    }
    if (do_out) {
        float ow = out_w[cg];
        float part[4];
        #pragma unroll
        for (int reg=0; reg<4; reg++){
            float p = (x1n[reg] + x2f[reg]) * 0.5f * ow;
            p += __shfl_xor(p,1); p += __shfl_xor(p,2); p += __shfl_xor(p,4); p += __shfl_xor(p,8);
            part[reg] = p;
        }
        __syncthreads();
        if (col == 0) {
            #pragma unroll
            for (int reg=0; reg<4; reg++)
                lnS[w*16 + quad*4 + reg] = part[reg];
        }
        __syncthreads();
        if (tid < 16) {
            int t = t0 + tid;
            if (t < L0SEQ) {
                float v2 = lnS[tid] + lnS[16+tid] + lnS[32+tid] + lnS[48+tid];
                y[(size_t)b*L0SEQ + t] = v2 + out_b[0];
            }
        }
    }
}

extern "C" void kernel_launch(void* const* d_in, const int* in_sizes, int n_in,
                              void* d_out, int out_size, void* d_ws, size_t ws_size,
                              hipStream_t stream)
{
    const float* wave  = (const float*)d_in[0];
    const float* in_w  = (const float*)d_in[1];
    const float* in_b  = (const float*)d_in[2];
    const float* ln1_g = (const float*)d_in[3];
    const float* ln1_b = (const float*)d_in[4];
    const float* wqk   = (const float*)d_in[5];
    const float* wv    = (const float*)d_in[6];
    const float* wo_w  = (const float*)d_in[7];
    const float* wo_b  = (const float*)d_in[8];
    const float* rot   = (const float*)d_in[9];
    const float* ln2_g = (const float*)d_in[10];
    const float* ln2_b = (const float*)d_in[11];
    const float* w1    = (const float*)d_in[12];
    const float* b1    = (const float*)d_in[13];
    const float* w2    = (const float*)d_in[14];
    const float* b2    = (const float*)d_in[15];
    const float* out_w = (const float*)d_in[16];
    const float* out_b = (const float*)d_in[17];
    float* y = (float*)d_out;

    float* ws = (float*)d_ws;
    float* x1      = ws;                       // XSZ f32
    float* x2      = x1 + XSZ;                 // XSZ f32
    unsigned* qkvs = (unsigned*)(x2 + XSZ);    // 4*QKSZ u32 (interleaved)
    float* o_hash  = (float*)(qkvs + 4*QKSZ);  // OHSZ f32
    float* slogb   = o_hash + OHSZ;            // SLSZ f32
    int* buckets   = (int*)(slogb + SLSZ);     // SLSZ int
    int* sorted    = buckets + SLSZ;           // SLSZ int
    unsigned* wsplit = (unsigned*)(sorted + SLSZ); // 294912 u32

    k_init<<<5696, 256, 0, stream>>>(wave, in_w, in_b, x1, x2, wo_w, w1, w2, wsplit);
    for (int layer = 0; layer < 4; layer++) {
        k_qkv<<<NBATCH*80, 256, 0, stream>>>(x2, ln1_g + layer*64, ln1_b + layer*64,
                                       wqk + layer*4096, wv + layer*4096, rot + layer*640,
                                       qkvs, buckets);
        k_sort<<<256, 64, 0, stream>>>(buckets, sorted);
        k_attn<<<NBH*NCHUNK, 256, 0, stream>>>(qkvs, sorted, o_hash, slogb);
        k_tail<<<NBATCH*LSEQ/16, 256, 0, stream>>>(o_hash, slogb,
                                        wsplit + layer*8192, wo_b + layer*64,
                                        ln2_g + layer*64, ln2_b + layer*64,
                                        wsplit + 32768 + layer*32768, b1 + layer*256,
                                        wsplit + 163840 + layer*32768, b2 + layer*64,
                                        x1, x2,
                                        out_w, out_b, y, (layer == 3) ? 1 : 0);
    }
}

// Round 13
// 561.071 us; speedup vs baseline: 1.2304x; 1.0022x over previous
//
#include <hip/hip_runtime.h>
#include <math.h>

#define LSEQ 1280
#define L0SEQ 1250
#define DM 64
#define NHEADS 4
#define DHD 16
#define NHASH 4
#define NBUK 20
#define NCHUNK 80
#define FFD 256
#define NBATCH 16
#define NBH 64

#define XSZ (NBATCH*LSEQ*DM)        // 1310720
#define QKSZ (NBH*LSEQ*DHD)         // 1310720
#define OHSZ (NBH*NHASH*LSEQ*DHD)   // 5242880
#define SLSZ (NBH*NHASH*LSEQ)       // 327680

typedef __attribute__((ext_vector_type(8))) short frag_ab;   // 8 bf16
typedef __attribute__((ext_vector_type(4))) float frag_c;    // 4 fp32

union FU4 { uint4 v; frag_ab f; };

__device__ __forceinline__ unsigned rnbf(float x){
    unsigned b = __float_as_uint(x);
    return (b + 0x7fffu + ((b >> 16) & 1u)) >> 16;
}
__device__ __forceinline__ float bf2f(unsigned h){ return __uint_as_float(h << 16); }
__device__ __forceinline__ unsigned rot16(unsigned x){ return (x >> 16) | (x << 16); }
__device__ __forceinline__ uint4 rot16v(uint4 a){
    uint4 r; r.x=rot16(a.x); r.y=rot16(a.y); r.z=rot16(a.z); r.w=rot16(a.w); return r;
}

// exact triple split (truncation): x = h + m + l
__device__ __forceinline__ void split3(float x, unsigned& h, unsigned& m, unsigned& l){
    unsigned bx = __float_as_uint(x);
    h = bx >> 16;
    float r = x - __uint_as_float(bx & 0xffff0000u);
    unsigned br = __float_as_uint(r);
    m = br >> 16;
    float r2 = r - __uint_as_float(br & 0xffff0000u);
    l = __float_as_uint(r2) >> 16;
}

// ---------------- init: embed (blocks 0..5119) + weight pre-split (blocks 5120..5695) ----------------
__global__ __launch_bounds__(256) void k_init(
    const float* __restrict__ wave, const float* __restrict__ in_w, const float* __restrict__ in_b,
    float* __restrict__ x1, float* __restrict__ x2,
    const float* __restrict__ wo_w, const float* __restrict__ w1,
    const float* __restrict__ w2, unsigned* __restrict__ wsplit)
{
    if (blockIdx.x < 5120) {
        int idx = blockIdx.x * 256 + threadIdx.x;
        int d = idx & 63;
        int t = idx >> 6;
        int b = t / LSEQ;
        int tt = t % LSEQ;
        float v0 = 0.f, v1 = 0.f;
        if (tt < L0SEQ) {
            v0 = wave[(size_t)(b*2+0)*L0SEQ + tt];
            v1 = wave[(size_t)(b*2+1)*L0SEQ + tt];
        }
        float x = v0 * in_w[d] + v1 * in_w[64 + d] + in_b[d];
        x1[idx] = x;
        x2[idx] = x;
    } else {
        int gid = (blockIdx.x - 5120) * 256 + threadIdx.x;   // < 147456 exactly
        int l = gid / 36864;
        int r = gid % 36864;
        float src; unsigned* dst; int idx; int stride;
        if (r < 4096) {                 // wo: K=64, N=64
            int k = r >> 6, n = r & 63;
            src = wo_w[l*4096 + k*64 + n];
            dst = wsplit + l*8192;
            idx = (((k>>4)*4 + (n>>4))*16 + (n&15))*16 + (k&15);
            stride = 4096;
        } else if (r < 20480) {         // w1: K=64, N=256
            int rr = r - 4096;
            int k = rr >> 8, n = rr & 255;
            src = w1[l*16384 + k*256 + n];
            dst = wsplit + 32768 + l*32768;
            idx = (((k>>4)*16 + (n>>4))*16 + (n&15))*16 + (k&15);
            stride = 16384;
        } else {                        // w2: K=256, N=64
            int rr = r - 20480;
            int k = rr >> 6, n = rr & 63;
            src = w2[l*16384 + k*64 + n];
            dst = wsplit + 163840 + l*32768;
            idx = (((k>>4)*4 + (n>>4))*16 + (n&15))*16 + (k&15);
            stride = 16384;
        }
        unsigned h, m, lo;
        split3(src, h, m, lo);
        dst[idx]          = h | (m<<16);
        dst[idx + stride] = lo | (h<<16);
    }
}

// ---------------- LN + QK/V proj + bucketing + pre-split (interleaved 256B/token rows) ----------------
__global__ __launch_bounds__(256) void k_qkv(
    const float* __restrict__ x2, const float* __restrict__ g, const float* __restrict__ bta,
    const float* __restrict__ wqk, const float* __restrict__ wv, const float* __restrict__ rot,
    unsigned* __restrict__ qkvs, int* __restrict__ buckets)
{
    __shared__ float xln[16][68];
    __shared__ float qkt[16][68];
    __shared__ float vvt[16][68];
    __shared__ float rots[640];
    int tid = threadIdx.x;
    int b  = blockIdx.x / 80;
    int t0 = (blockIdx.x % 80) * 16;
    int tok = tid >> 4;
    int cg  = tid & 15;
    int c4  = cg * 4;

    for (int i = tid; i < 640; i += 256) rots[i] = rot[i];

    float4 xv4 = *(const float4*)&x2[((size_t)b*LSEQ + t0 + tok)*DM + c4];
    float s = xv4.x + xv4.y + xv4.z + xv4.w;
    float ss = xv4.x*xv4.x + xv4.y*xv4.y + xv4.z*xv4.z + xv4.w*xv4.w;
    s  += __shfl_xor(s,1);  s  += __shfl_xor(s,2);  s  += __shfl_xor(s,4);  s  += __shfl_xor(s,8);
    ss += __shfl_xor(ss,1); ss += __shfl_xor(ss,2); ss += __shfl_xor(ss,4); ss += __shfl_xor(ss,8);
    float m = s * (1.f/64.f);
    float vr = ss * (1.f/64.f) - m*m;
    float rstd = 1.f / sqrtf(vr + 1e-5f);
    {
        float4 g4 = *(const float4*)&g[c4];
        float4 b4 = *(const float4*)&bta[c4];
        float4 o;
        o.x = (xv4.x-m)*rstd*g4.x + b4.x;
        o.y = (xv4.y-m)*rstd*g4.y + b4.y;
        o.z = (xv4.z-m)*rstd*g4.z + b4.z;
        o.w = (xv4.w-m)*rstd*g4.w + b4.w;
        *(float4*)&xln[tok][c4] = o;
    }
    __syncthreads();

    float aq[4] = {0,0,0,0}, av[4] = {0,0,0,0};
    for (int f = 0; f < 64; f++) {
        float4 wq4 = *(const float4*)&wqk[f*64 + c4];
        float4 wv4 = *(const float4*)&wv [f*64 + c4];
        float xv = xln[tok][f];
        aq[0] += xv*wq4.x; aq[1] += xv*wq4.y; aq[2] += xv*wq4.z; aq[3] += xv*wq4.w;
        av[0] += xv*wv4.x; av[1] += xv*wv4.y; av[2] += xv*wv4.z; av[3] += xv*wv4.w;
    }
    *(float4*)&qkt[tok][c4] = *(float4*)aq;
    *(float4*)&vvt[tok][c4] = *(float4*)av;
    __syncthreads();

    int p = tid >> 2;
    int ptok = p >> 2, head = p & 3;
    int sub = tid & 3;
    int e0 = sub * 4;
    int t = t0 + ptok;
    float4 qf4 = *(const float4*)&qkt[ptok][head*16 + e0];
    float nsq = qf4.x*qf4.x + qf4.y*qf4.y + qf4.z*qf4.z + qf4.w*qf4.w;
    nsq += __shfl_xor(nsq,1); nsq += __shfl_xor(nsq,2);
    float inv = 1.f / fmaxf(sqrtf(nsq), 1e-12f);
    float qe[4] = {qf4.x, qf4.y, qf4.z, qf4.w};
    unsigned wq[4], wk[4];
    #pragma unroll
    for (int i=0;i<4;i++){
        float xq = qe[i]*0.25f;
        unsigned qh = rnbf(xq);
        unsigned ql = rnbf(xq - bf2f(qh));
        wq[i] = qh | (ql<<16);
        float xk = qe[i]*inv;
        unsigned kh = rnbf(xk);
        unsigned kl = rnbf(xk - bf2f(kh));
        wk[i] = kh | (kl<<16);
    }
    float4 vf4 = *(const float4*)&vvt[ptok][head*16 + e0];
    float ve[4] = {vf4.x, vf4.y, vf4.z, vf4.w};
    unsigned wv1[4], wv3[4];
    #pragma unroll
    for (int i=0;i<4;i++){
        unsigned vh_, vm_, vl_;
        split3(ve[i], vh_, vm_, vl_);
        wv1[i] = vh_ | (vm_<<16);
        wv3[i] = vl_ | (vh_<<16);
    }
    size_t sb = (((size_t)(b*NHEADS+head))*LSEQ + t)*64;
    *(uint4*)&qkvs[sb + e0]      = *(uint4*)wq;
    *(uint4*)&qkvs[sb + 16 + e0] = *(uint4*)wk;
    *(uint4*)&qkvs[sb + 32 + e0] = *(uint4*)wv1;
    *(uint4*)&qkvs[sb + 48 + e0] = *(uint4*)wv3;

    float qf[16];
    {
        float4 a0 = *(const float4*)&qkt[ptok][head*16 + 0];
        float4 a1 = *(const float4*)&qkt[ptok][head*16 + 4];
        float4 a2 = *(const float4*)&qkt[ptok][head*16 + 8];
        float4 a3 = *(const float4*)&qkt[ptok][head*16 + 12];
        qf[0]=a0.x; qf[1]=a0.y; qf[2]=a0.z; qf[3]=a0.w;
        qf[4]=a1.x; qf[5]=a1.y; qf[6]=a1.z; qf[7]=a1.w;
        qf[8]=a2.x; qf[9]=a2.y; qf[10]=a2.z; qf[11]=a2.w;
        qf[12]=a3.x; qf[13]=a3.y; qf[14]=a3.z; qf[15]=a3.w;
    }
    int nh = sub;
    float rv[10];
    #pragma unroll
    for (int i=0;i<10;i++) {
        float acc = 0.f;
        #pragma unroll
        for (int f=0; f<16; f++) acc += qf[f]*rots[(f*NHASH+nh)*10 + i];
        rv[i] = acc;
    }
    float best = rv[0]; int bi = 0;
    #pragma unroll
    for (int i=1;i<10;i++) if (rv[i] > best) { best = rv[i]; bi = i; }
    #pragma unroll
    for (int i=0;i<10;i++) if (-rv[i] > best) { best = -rv[i]; bi = 10+i; }
    buckets[((size_t)(b*NHEADS+head)*NHASH + nh)*LSEQ + t] = bi;
}

// ---------------- counting sort per (bh, hash): stable, ballot-ranked ----------------
__global__ __launch_bounds__(64) void k_sort(
    const int* __restrict__ buckets, int* __restrict__ sorted)
{
    __shared__ int hist[20];
    __shared__ int startl[20];
    int lane = threadIdx.x;
    int gidx = blockIdx.x;
    const int* bk = buckets + (size_t)gidx * LSEQ;
    int* dst = sorted + (size_t)gidx * LSEQ;
    if (lane < 20) hist[lane] = 0;
    __syncthreads();
    int myb[20];
    for (int ch = 0; ch < 20; ch++) {
        myb[ch] = bk[ch*64 + lane];
        atomicAdd(&hist[myb[ch]], 1);
    }
    __syncthreads();
    if (lane == 0) {
        int acc = 0;
        for (int b2 = 0; b2 < 20; b2++) { startl[b2] = acc; acc += hist[b2]; }
    }
    __syncthreads();
    unsigned long long below = (lane == 63) ? 0x7fffffffffffffffull
                                            : ((1ull << lane) - 1ull);
    for (int ch = 0; ch < 20; ch++) {
        int bv = myb[ch];
        unsigned long long mymask = 0, ownmask = 0;
        #pragma unroll
        for (int b2 = 0; b2 < 20; b2++) {
            unsigned long long m2 = __ballot(bv == b2);
            if (b2 == bv)   mymask  = m2;
            if (b2 == lane) ownmask = m2;
        }
        int rank = __popcll(mymask & below);
        int base = startl[bv];
        dst[base + rank] = ch*64 + lane;
        __syncthreads();
        if (lane < 20) startl[lane] += __popcll(ownmask);
        __syncthreads();
    }
}

// ---------------- chunked attention v10: XCD-colocated + round-11 LDS layout ----------------
// bh = blockIdx&63 (same bh -> same XCD; qkvs rows L2-resident). 36.9 KB LDS, 4 blocks/CU.
__global__ __launch_bounds__(256) void k_attn(
    const unsigned* __restrict__ qkvs,
    const int* __restrict__ sorted, float* __restrict__ o_hash, float* __restrict__ slog)
{
    __shared__ __align__(16) unsigned SM[9216];
    unsigned* Va1 = SM;                    // [kt8][dh16][key16] kt-stride 328, dh-stride 20
    unsigned* Va3 = SM + 2624;
    unsigned* Ka1 = SM + 5248;             // [key128][16] stride 20 (phase 1)
    unsigned* Pa1 = SM + 5248;             // phase 2 alias: [t2][row64][key16] stride 20
    unsigned short* Pa2h = (unsigned short*)(SM + 7808);  // 2560 u16 (P lo)
    int* kposS = (int*)(SM + 9088);

    int tid = threadIdx.x;
    int bh = blockIdx.x & 63;          // XCD swizzle: same bh -> same XCD (64 % 8 == 0)
    int c  = blockIdx.x >> 6;
    int h  = c / NBUK, cc = c % NBUK;
    int cp = (c + NCHUNK - 1) % NCHUNK;
    int hp = cp / NBUK, ccp = cp % NBUK;

    int key = tid & 127;
    int pos = (key < 64)
        ? sorted[((size_t)bh*NHASH + h)*LSEQ + cc*64 + key]
        : sorted[((size_t)bh*NHASH + hp)*LSEQ + ccp*64 + (key-64)];
    size_t srow = ((size_t)bh*LSEQ + pos)*64;
    if (tid < 128) {
        kposS[key] = pos;
        const uint4* kr = (const uint4*)(qkvs + srow + 16);
        #pragma unroll
        for (int e4=0; e4<4; e4++)
            *(uint4*)&Ka1[key*20 + e4*4] = kr[e4];
    } else {
        const uint4* v1r = (const uint4*)(qkvs + srow + 32);
        const uint4* v3r = (const uint4*)(qkvs + srow + 48);
        int kt = key >> 4, jl = key & 15;
        int lb = kt*328 + jl;
        #pragma unroll
        for (int e4=0; e4<4; e4++){
            uint4 a = v1r[e4], c2 = v3r[e4];
            unsigned aa[4] = {a.x,a.y,a.z,a.w};
            unsigned cb[4] = {c2.x,c2.y,c2.z,c2.w};
            #pragma unroll
            for (int i=0;i<4;i++){
                int d = e4*4 + i;
                Va1[lb + d*20] = aa[i];
                Va3[lb + d*20] = cb[i];
            }
        }
    }
    __syncthreads();

    int w = tid >> 6, lane = tid & 63;
    int quad = lane >> 4, col = lane & 15;

    int qgpos = kposS[16*w + col];
    FU4 QA;
    QA.v = *(const uint4*)(qkvs + ((size_t)bh*LSEQ + qgpos)*64 + quad*4);
    frag_ab qA = QA.f;

    frag_c acc[8];
    #pragma unroll
    for (int nt=0; nt<8; nt++){
        FU4 B1, B2;
        B1.v = *(const uint4*)&Ka1[(nt*16+col)*20 + 4*quad];
        B2.v = rot16v(B1.v);
        frag_c a = {0.f,0.f,0.f,0.f};
        a = __builtin_amdgcn_mfma_f32_16x16x32_bf16(qA, B1.f, a, 0, 0, 0);
        a = __builtin_amdgcn_mfma_f32_16x16x32_bf16(qA, B2.f, a, 0, 0, 0);
        acc[nt] = a;
    }
    int qp[4];
    #pragma unroll
    for (int reg=0; reg<4; reg++) qp[reg] = kposS[16*w + quad*4 + reg];
    #pragma unroll
    for (int nt=0; nt<8; nt++){
        int kp2 = kposS[nt*16 + col];
        #pragma unroll
        for (int reg=0; reg<4; reg++)
            if (kp2 == qp[reg]) acc[nt][reg] = -5e4f;
    }
    float mx[4] = {-3.4e38f,-3.4e38f,-3.4e38f,-3.4e38f};
    #pragma unroll
    for (int nt=0; nt<8; nt++)
        #pragma unroll
        for (int reg=0; reg<4; reg++) mx[reg] = fmaxf(mx[reg], acc[nt][reg]);
    #pragma unroll
    for (int reg=0; reg<4; reg++){
        float m2 = mx[reg];
        m2 = fmaxf(m2, __shfl_xor(m2, 1)); m2 = fmaxf(m2, __shfl_xor(m2, 2));
        m2 = fmaxf(m2, __shfl_xor(m2, 4)); m2 = fmaxf(m2, __shfl_xor(m2, 8));
        mx[reg] = m2;
    }
    float sm2[4] = {0.f,0.f,0.f,0.f};
    #pragma unroll
    for (int nt=0; nt<8; nt++)
        #pragma unroll
        for (int reg=0; reg<4; reg++){
            float e = __expf(acc[nt][reg] - mx[reg]);
            acc[nt][reg] = e; sm2[reg] += e;
        }
    #pragma unroll
    for (int reg=0; reg<4; reg++){
        float s2 = sm2[reg];
        s2 += __shfl_xor(s2, 1); s2 += __shfl_xor(s2, 2);
        s2 += __shfl_xor(s2, 4); s2 += __shfl_xor(s2, 8);
        sm2[reg] = s2;
    }
    float invs[4];
    #pragma unroll
    for (int reg=0; reg<4; reg++) invs[reg] = 1.f / sm2[reg];
    if (col == 0) {
        #pragma unroll
        for (int reg=0; reg<4; reg++)
            slog[((size_t)bh*NHASH + h)*LSEQ + qp[reg]] = mx[reg] + __logf(sm2[reg]);
    }

    frag_c o = {0.f,0.f,0.f,0.f};
    __syncthreads();   // Ka1 dead -> Pa1 alias safe
    #pragma unroll
    for (int pass=0; pass<4; pass++){
        #pragma unroll
        for (int t2=0; t2<2; t2++){
            int nt = pass*2 + t2;
            #pragma unroll
            for (int reg=0; reg<4; reg++){
                float p = acc[nt][reg] * invs[reg];
                unsigned ph_, pm_, pl_;
                split3(p, ph_, pm_, pl_);
                int idx = t2*1280 + (16*w + 4*quad + reg)*20 + col;
                Pa1[idx] = ph_ | (pm_<<16);
                Pa2h[idx] = (unsigned short)pl_;
            }
        }
        __syncthreads();
        #pragma unroll
        for (int t2=0; t2<2; t2++){
            int ktg = pass*2 + t2;
            FU4 A1, A2, B1, B2, B3;
            int pidx = t2*1280 + (16*w + col)*20 + 4*quad;
            A1.v = *(const uint4*)&Pa1[pidx];
            uint2 z = *(const uint2*)&Pa2h[pidx];
            A2.v.x = (A1.v.x & 0xffffu) | (z.x << 16);
            A2.v.y = (A1.v.y & 0xffffu) | (z.x & 0xffff0000u);
            A2.v.z = (A1.v.z & 0xffffu) | (z.y << 16);
            A2.v.w = (A1.v.w & 0xffffu) | (z.y & 0xffff0000u);
            int vidx = ktg*328 + col*20 + 4*quad;
            B1.v = *(const uint4*)&Va1[vidx];
            B2.v = rot16v(B1.v);
            B3.v = *(const uint4*)&Va3[vidx];
            o = __builtin_amdgcn_mfma_f32_16x16x32_bf16(A1.f, B1.f, o, 0, 0, 0);
            o = __builtin_amdgcn_mfma_f32_16x16x32_bf16(A1.f, B2.f, o, 0, 0, 0);
            o = __builtin_amdgcn_mfma_f32_16x16x32_bf16(A2.f, B3.f, o, 0, 0, 0);
        }
        if (pass < 3) __syncthreads();
    }
    size_t obase = ((size_t)bh*NHASH + h)*LSEQ;
    #pragma unroll
    for (int reg=0; reg<4; reg++)
        o_hash[(obase + qp[reg])*DHD + col] = o[reg];
}

// ---------------- fused tail v4: B2=rot16(B1); optional fused output projection ----------------
__global__ __launch_bounds__(256) void k_tail(
    const float* __restrict__ o_hash, const float* __restrict__ slog,
    const unsigned* __restrict__ wo_s, const float* __restrict__ wo_b,
    const float* __restrict__ g2, const float* __restrict__ b2t,
    const unsigned* __restrict__ w1_s, const float* __restrict__ b1,
    const unsigned* __restrict__ w2_s, const float* __restrict__ b2f,
    float* __restrict__ x1, float* __restrict__ x2,
    const float* __restrict__ out_w, const float* __restrict__ out_b,
    float* __restrict__ y, int do_out)
{
    __shared__ unsigned cA1[1024], cA2[1024];
    __shared__ unsigned xA1[1024], xA2[1024];
    __shared__ unsigned gA1[4096], gA2[4096];
    __shared__ float lnS[64], lnQ[64];
    float* red = (float*)gA1;

    int tid = threadIdx.x;
    int b  = blockIdx.x / 80;
    int t0 = (blockIdx.x % 80) * 16;
    int w = tid >> 6, lane = tid & 63;
    int quad = lane >> 4, col = lane & 15;

    {
        int tok = tid >> 4;
        int dg  = tid & 15;
        int d0  = dg * 4;
        int kt  = dg >> 2;
        int t = t0 + tok;
        int bh = b*NHEADS + kt;
        float sl[4];
        #pragma unroll
        for (int nh=0; nh<4; nh++) sl[nh] = slog[((size_t)bh*NHASH + nh)*LSEQ + t];
        float mx = fmaxf(fmaxf(sl[0],sl[1]), fmaxf(sl[2],sl[3]));
        float wgt[4]; float wsum = 0.f;
        #pragma unroll
        for (int nh=0; nh<4; nh++){ wgt[nh] = __expf(sl[nh]-mx); wsum += wgt[nh]; }
        float iv = 1.f/wsum;
        float a4[4] = {0.f,0.f,0.f,0.f};
        #pragma unroll
        for (int nh=0; nh<4; nh++){
            float4 oh = *(const float4*)&o_hash[(((size_t)bh*NHASH + nh)*LSEQ + t)*DHD + (d0 & 15)];
            float wn = wgt[nh]*iv;
            a4[0] += wn*oh.x; a4[1] += wn*oh.y; a4[2] += wn*oh.z; a4[3] += wn*oh.w;
        }
        int sw = (tok & 7) << 2;
        unsigned cw1[4], cw2[4];
        #pragma unroll
        for (int i=0;i<4;i++){
            unsigned h_, m_, l_;
            split3(a4[i], h_, m_, l_);
            cw1[i] = h_ | (m_<<16);
            cw2[i] = h_ | (l_<<16);
        }
        *(uint4*)&cA1[tok*64 + (d0 ^ sw)] = *(uint4*)cw1;
        *(uint4*)&cA2[tok*64 + (d0 ^ sw)] = *(uint4*)cw2;
    }
    __syncthreads();
    FU4 aA1[4], aA2[4];
    {
        int sw = (col & 7) << 2;
        #pragma unroll
        for (int kt=0; kt<4; kt++){
            int word = (kt*16 + quad*4) ^ sw;
            aA1[kt].v = *(const uint4*)&cA1[col*64 + word];
            aA2[kt].v = *(const uint4*)&cA2[col*64 + word];
        }
    }

    frag_c awo = {0.f,0.f,0.f,0.f};
    #pragma unroll
    for (int kt=0; kt<4; kt++){
        FU4 B1, B2, B3;
        int bidx = ((kt*4 + w)*16 + col)*16 + quad*4;
        B1.v = *(const uint4*)&wo_s[bidx];
        B2.v = rot16v(B1.v);
        B3.v = *(const uint4*)&wo_s[bidx + 4096];
        awo = __builtin_amdgcn_mfma_f32_16x16x32_bf16(aA1[kt].f, B1.f, awo, 0, 0, 0);
        awo = __builtin_amdgcn_mfma_f32_16x16x32_bf16(aA1[kt].f, B2.f, awo, 0, 0, 0);
        awo = __builtin_amdgcn_mfma_f32_16x16x32_bf16(aA2[kt].f, B3.f, awo, 0, 0, 0);
    }
    int cg = w*16 + col;
    float x1n[4];
    float s1[4], s2[4];
    {
        float wb = wo_b[cg];
        #pragma unroll
        for (int reg=0; reg<4; reg++){
            int rg = t0 + quad*4 + reg;
            size_t xi = ((size_t)b*LSEQ + rg)*DM + cg;
            float xv = x1[xi] + awo[reg] + wb;
            x1[xi] = xv;
            x1n[reg] = xv;
            s1[reg] = xv; s2[reg] = xv*xv;
        }
    }
    #pragma unroll
    for (int reg=0; reg<4; reg++){
        float a = s1[reg], q = s2[reg];
        a += __shfl_xor(a,1); a += __shfl_xor(a,2); a += __shfl_xor(a,4); a += __shfl_xor(a,8);
        q += __shfl_xor(q,1); q += __shfl_xor(q,2); q += __shfl_xor(q,4); q += __shfl_xor(q,8);
        s1[reg] = a; s2[reg] = q;
    }
    if (col == 0) {
        #pragma unroll
        for (int reg=0; reg<4; reg++){
            lnS[w*16 + quad*4 + reg] = s1[reg];
            lnQ[w*16 + quad*4 + reg] = s2[reg];
        }
    }
    __syncthreads();
    float mean[4], rstd[4];
    #pragma unroll
    for (int reg=0; reg<4; reg++){
        int tok = quad*4 + reg;
        float a = lnS[tok] + lnS[16+tok] + lnS[32+tok] + lnS[48+tok];
        float q = lnQ[tok] + lnQ[16+tok] + lnQ[32+tok] + lnQ[48+tok];
        mean[reg] = a*(1.f/64.f);
        float var = q*(1.f/64.f) - mean[reg]*mean[reg];
        rstd[reg] = 1.f/sqrtf(var + 1e-5f);
    }
    {
        float gv = g2[cg], bv = b2t[cg];
        #pragma unroll
        for (int reg=0; reg<4; reg++){
            int row = quad*4 + reg;
            float xv = (x1n[reg]-mean[reg])*rstd[reg]*gv + bv;
            unsigned h_, m_, l_;
            split3(xv, h_, m_, l_);
            int word = cg ^ ((row & 7) << 2);
            xA1[row*64 + word] = h_ | (m_<<16);
            xA2[row*64 + word] = h_ | (l_<<16);
        }
    }
    __syncthreads();
    FU4 xa1[4], xa2[4];
    {
        int sw = (col & 7) << 2;
        #pragma unroll
        for (int kt=0; kt<4; kt++){
            int word = (kt*16 + quad*4) ^ sw;
            xa1[kt].v = *(const uint4*)&xA1[col*64 + word];
            xa2[kt].v = *(const uint4*)&xA2[col*64 + word];
        }
    }

    unsigned* myg1 = gA1 + w*1024;
    unsigned* myg2 = gA2 + w*1024;
    #pragma unroll
    for (int ntl=0; ntl<4; ntl++){
        int nt = w*4 + ntl;
        frag_c a = {0.f,0.f,0.f,0.f};
        #pragma unroll
        for (int kt=0; kt<4; kt++){
            FU4 B1, B2, B3;
            int bidx = ((kt*16 + nt)*16 + col)*16 + quad*4;
            B1.v = *(const uint4*)&w1_s[bidx];
            B2.v = rot16v(B1.v);
            B3.v = *(const uint4*)&w1_s[bidx + 16384];
            a = __builtin_amdgcn_mfma_f32_16x16x32_bf16(xa1[kt].f, B1.f, a, 0, 0, 0);
            a = __builtin_amdgcn_mfma_f32_16x16x32_bf16(xa1[kt].f, B2.f, a, 0, 0, 0);
            a = __builtin_amdgcn_mfma_f32_16x16x32_bf16(xa2[kt].f, B3.f, a, 0, 0, 0);
        }
        float bb = b1[nt*16 + col];
        #pragma unroll
        for (int reg=0; reg<4; reg++){
            float xx = a[reg] + bb;
            float ge = 0.5f*xx*(1.f + erff(xx*0.70710678118654752f));
            unsigned h_, m_, l_;
            split3(ge, h_, m_, l_);
            int row = quad*4 + reg;
            int word = (ntl*16 + col) ^ ((row & 7) << 2);
            myg1[row*64 + word] = h_ | (m_<<16);
            myg2[row*64 + word] = h_ | (l_<<16);
        }
    }
    frag_c aw2[4] = {{0,0,0,0},{0,0,0,0},{0,0,0,0},{0,0,0,0}};
    {
        int sw = (col & 7) << 2;
        #pragma unroll
        for (int kt2=0; kt2<4; kt2++){
            FU4 A1, A2;
            int word = (kt2*16 + quad*4) ^ sw;
            A1.v = *(const uint4*)&myg1[col*64 + word];
            A2.v = *(const uint4*)&myg2[col*64 + word];
            int kg = w*4 + kt2;
            #pragma unroll
            for (int nt2=0; nt2<4; nt2++){
                FU4 B1, B2, B3;
                int bidx = ((kg*4 + nt2)*16 + col)*16 + quad*4;
                B1.v = *(const uint4*)&w2_s[bidx];
                B2.v = rot16v(B1.v);
                B3.v = *(const uint4*)&w2_s[bidx + 16384];
                aw2[nt2] = __builtin_amdgcn_mfma_f32_16x16x32_bf16(A1.f, B1.f, aw2[nt2], 0, 0, 0);
                aw2[nt2] = __builtin_amdgcn_mfma_f32_16x16x32_bf16(A1.f, B2.f, aw2[nt2], 0, 0, 0);
                aw2[nt2] = __builtin_amdgcn_mfma_f32_16x16x32_bf16(A2.f, B3.f, aw2[nt2], 0, 0, 0);
            }
        }
    }
    __syncthreads();
    #pragma unroll
    for (int nt2=0; nt2<4; nt2++)
        #pragma unroll
        for (int reg=0; reg<4; reg++)
            red[((w*4 + nt2)*4 + reg)*64 + lane] = aw2[nt2][reg];
    __syncthreads();
    float x2f[4];
    {
        float bb = b2f[cg];
        #pragma unroll
        for (int reg=0; reg<4; reg++){
            float v = red[((0*4 + w)*4 + reg)*64 + lane]
                    + red[((1*4 + w)*4 + reg)*64 + lane]
                    + red[((2*4 + w)*4 + reg)*64 + lane]
                    + red[((3*4 + w)*4 + reg)*64 + lane];
            int rg = t0 + quad*4 + reg;
            size_t xi = ((size_t)b*LSEQ + rg)*DM + cg;
            float nv = x2[xi] + v + bb;
            x2[xi] = nv;
            x2f[reg] = nv;
        }
    }
    if (do_out) {
        float ow = out_w[cg];
        float part[4];
        #pragma unroll
        for (int reg=0; reg<4; reg++){
            float p = (x1n[reg] + x2f[reg]) * 0.5f * ow;
            p += __shfl_xor(p,1); p += __shfl_xor(p,2); p += __shfl_xor(p,4); p += __shfl_xor(p,8);
            part[reg] = p;
        }
        __syncthreads();
        if (col == 0) {
            #pragma unroll
            for (int reg=0; reg<4; reg++)
                lnS[w*16 + quad*4 + reg] = part[reg];
        }
        __syncthreads();
        if (tid < 16) {
            int t = t0 + tid;
            if (t < L0SEQ) {
                float v2 = lnS[tid] + lnS[16+tid] + lnS[32+tid] + lnS[48+tid];
                y[(size_t)b*L0SEQ + t] = v2 + out_b[0];
            }
        }
    }
}

extern "C" void kernel_launch(void* const* d_in, const int* in_sizes, int n_in,
                              void* d_out, int out_size, void* d_ws, size_t ws_size,
                              hipStream_t stream)
{
    const float* wave  = (const float*)d_in[0];
    const float* in_w  = (const float*)d_in[1];
    const float* in_b  = (const float*)d_in[2];
    const float* ln1_g = (const float*)d_in[3];
    const float* ln1_b = (const float*)d_in[4];
    const float* wqk   = (const float*)d_in[5];
    const float* wv    = (const float*)d_in[6];
    const float* wo_w  = (const float*)d_in[7];
    const float* wo_b  = (const float*)d_in[8];
    const float* rot   = (const float*)d_in[9];
    const float* ln2_g = (const float*)d_in[10];
    const float* ln2_b = (const float*)d_in[11];
    const float* w1    = (const float*)d_in[12];
    const float* b1    = (const float*)d_in[13];
    const float* w2    = (const float*)d_in[14];
    const float* b2    = (const float*)d_in[15];
    const float* out_w = (const float*)d_in[16];
    const float* out_b = (const float*)d_in[17];
    float* y = (float*)d_out;

    float* ws = (float*)d_ws;
    float* x1      = ws;                       // XSZ f32
    float* x2      = x1 + XSZ;                 // XSZ f32
    unsigned* qkvs = (unsigned*)(x2 + XSZ);    // 4*QKSZ u32 (interleaved)
    float* o_hash  = (float*)(qkvs + 4*QKSZ);  // OHSZ f32
    float* slogb   = o_hash + OHSZ;            // SLSZ f32
    int* buckets   = (int*)(slogb + SLSZ);     // SLSZ int
    int* sorted    = buckets + SLSZ;           // SLSZ int
    unsigned* wsplit = (unsigned*)(sorted + SLSZ); // 294912 u32

    k_init<<<5696, 256, 0, stream>>>(wave, in_w, in_b, x1, x2, wo_w, w1, w2, wsplit);
    for (int layer = 0; layer < 4; layer++) {
        k_qkv<<<NBATCH*80, 256, 0, stream>>>(x2, ln1_g + layer*64, ln1_b + layer*64,
                                       wqk + layer*4096, wv + layer*4096, rot + layer*640,
                                       qkvs, buckets);
        k_sort<<<256, 64, 0, stream>>>(buckets, sorted);
        k_attn<<<NBH*NCHUNK, 256, 0, stream>>>(qkvs, sorted, o_hash, slogb);
        k_tail<<<NBATCH*LSEQ/16, 256, 0, stream>>>(o_hash, slogb,
                                        wsplit + layer*8192, wo_b + layer*64,
                                        ln2_g + layer*64, ln2_b + layer*64,
                                        wsplit + 32768 + layer*32768, b1 + layer*256,
                                        wsplit + 163840 + layer*32768, b2 + layer*64,
                                        x1, x2,
                                        out_w, out_b, y, (layer == 3) ? 1 : 0);
    }
}

// Round 14
// 525.109 us; speedup vs baseline: 1.3147x; 1.0685x over previous
//
#include <hip/hip_runtime.h>
#include <math.h>

#define LSEQ 1280
#define L0SEQ 1250
#define DM 64
#define NHEADS 4
#define DHD 16
#define NHASH 4
#define NBUK 20
#define NCHUNK 80
#define FFD 256
#define NBATCH 16
#define NBH 64

#define XSZ (NBATCH*LSEQ*DM)        // 1310720
#define QKSZ (NBH*LSEQ*DHD)         // 1310720
#define OHSZ (NBH*NHASH*LSEQ*DHD)   // 5242880
#define SLSZ (NBH*NHASH*LSEQ)       // 327680

typedef __attribute__((ext_vector_type(8))) short frag_ab;   // 8 bf16
typedef __attribute__((ext_vector_type(4))) float frag_c;    // 4 fp32

union FU4 { uint4 v; frag_ab f; };

__device__ __forceinline__ unsigned rnbf(float x){
    unsigned b = __float_as_uint(x);
    return (b + 0x7fffu + ((b >> 16) & 1u)) >> 16;
}
__device__ __forceinline__ float bf2f(unsigned h){ return __uint_as_float(h << 16); }
__device__ __forceinline__ unsigned rot16(unsigned x){ return (x >> 16) | (x << 16); }
__device__ __forceinline__ uint4 rot16v(uint4 a){
    uint4 r; r.x=rot16(a.x); r.y=rot16(a.y); r.z=rot16(a.z); r.w=rot16(a.w); return r;
}

// exact triple split (truncation): x = h + m + l
__device__ __forceinline__ void split3(float x, unsigned& h, unsigned& m, unsigned& l){
    unsigned bx = __float_as_uint(x);
    h = bx >> 16;
    float r = x - __uint_as_float(bx & 0xffff0000u);
    unsigned br = __float_as_uint(r);
    m = br >> 16;
    float r2 = r - __uint_as_float(br & 0xffff0000u);
    l = __float_as_uint(r2) >> 16;
}

// ---------------- init: embed (blocks 0..5119) + weight pre-split (blocks 5120..5695) ----------------
__global__ __launch_bounds__(256) void k_init(
    const float* __restrict__ wave, const float* __restrict__ in_w, const float* __restrict__ in_b,
    float* __restrict__ x1, float* __restrict__ x2,
    const float* __restrict__ wo_w, const float* __restrict__ w1,
    const float* __restrict__ w2, unsigned* __restrict__ wsplit)
{
    if (blockIdx.x < 5120) {
        int idx = blockIdx.x * 256 + threadIdx.x;
        int d = idx & 63;
        int t = idx >> 6;
        int b = t / LSEQ;
        int tt = t % LSEQ;
        float v0 = 0.f, v1 = 0.f;
        if (tt < L0SEQ) {
            v0 = wave[(size_t)(b*2+0)*L0SEQ + tt];
            v1 = wave[(size_t)(b*2+1)*L0SEQ + tt];
        }
        float x = v0 * in_w[d] + v1 * in_w[64 + d] + in_b[d];
        x1[idx] = x;
        x2[idx] = x;
    } else {
        int gid = (blockIdx.x - 5120) * 256 + threadIdx.x;   // < 147456 exactly
        int l = gid / 36864;
        int r = gid % 36864;
        float src; unsigned* dst; int idx; int stride;
        if (r < 4096) {                 // wo: K=64, N=64
            int k = r >> 6, n = r & 63;
            src = wo_w[l*4096 + k*64 + n];
            dst = wsplit + l*8192;
            idx = (((k>>4)*4 + (n>>4))*16 + (n&15))*16 + (k&15);
            stride = 4096;
        } else if (r < 20480) {         // w1: K=64, N=256
            int rr = r - 4096;
            int k = rr >> 8, n = rr & 255;
            src = w1[l*16384 + k*256 + n];
            dst = wsplit + 32768 + l*32768;
            idx = (((k>>4)*16 + (n>>4))*16 + (n&15))*16 + (k&15);
            stride = 16384;
        } else {                        // w2: K=256, N=64
            int rr = r - 20480;
            int k = rr >> 6, n = rr & 63;
            src = w2[l*16384 + k*64 + n];
            dst = wsplit + 163840 + l*32768;
            idx = (((k>>4)*4 + (n>>4))*16 + (n&15))*16 + (k&15);
            stride = 16384;
        }
        unsigned h, m, lo;
        split3(src, h, m, lo);
        dst[idx]          = h | (m<<16);
        dst[idx + stride] = lo | (h<<16);
    }
}

// ---------------- LN + QK/V proj + bucketing + pre-split (interleaved 256B/token rows) ----------------
__global__ __launch_bounds__(256) void k_qkv(
    const float* __restrict__ x2, const float* __restrict__ g, const float* __restrict__ bta,
    const float* __restrict__ wqk, const float* __restrict__ wv, const float* __restrict__ rot,
    unsigned* __restrict__ qkvs, int* __restrict__ buckets)
{
    __shared__ float xln[16][68];
    __shared__ float qkt[16][68];
    __shared__ float vvt[16][68];
    __shared__ float rots[640];
    int tid = threadIdx.x;
    int b  = blockIdx.x / 80;
    int t0 = (blockIdx.x % 80) * 16;
    int tok = tid >> 4;
    int cg  = tid & 15;
    int c4  = cg * 4;

    for (int i = tid; i < 640; i += 256) rots[i] = rot[i];

    float4 xv4 = *(const float4*)&x2[((size_t)b*LSEQ + t0 + tok)*DM + c4];
    float s = xv4.x + xv4.y + xv4.z + xv4.w;
    float ss = xv4.x*xv4.x + xv4.y*xv4.y + xv4.z*xv4.z + xv4.w*xv4.w;
    s  += __shfl_xor(s,1);  s  += __shfl_xor(s,2);  s  += __shfl_xor(s,4);  s  += __shfl_xor(s,8);
    ss += __shfl_xor(ss,1); ss += __shfl_xor(ss,2); ss += __shfl_xor(ss,4); ss += __shfl_xor(ss,8);
    float m = s * (1.f/64.f);
    float vr = ss * (1.f/64.f) - m*m;
    float rstd = 1.f / sqrtf(vr + 1e-5f);
    {
        float4 g4 = *(const float4*)&g[c4];
        float4 b4 = *(const float4*)&bta[c4];
        float4 o;
        o.x = (xv4.x-m)*rstd*g4.x + b4.x;
        o.y = (xv4.y-m)*rstd*g4.y + b4.y;
        o.z = (xv4.z-m)*rstd*g4.z + b4.z;
        o.w = (xv4.w-m)*rstd*g4.w + b4.w;
        *(float4*)&xln[tok][c4] = o;
    }
    __syncthreads();

    float aq[4] = {0,0,0,0}, av[4] = {0,0,0,0};
    for (int f = 0; f < 64; f++) {
        float4 wq4 = *(const float4*)&wqk[f*64 + c4];
        float4 wv4 = *(const float4*)&wv [f*64 + c4];
        float xv = xln[tok][f];
        aq[0] += xv*wq4.x; aq[1] += xv*wq4.y; aq[2] += xv*wq4.z; aq[3] += xv*wq4.w;
        av[0] += xv*wv4.x; av[1] += xv*wv4.y; av[2] += xv*wv4.z; av[3] += xv*wv4.w;
    }
    *(float4*)&qkt[tok][c4] = *(float4*)aq;
    *(float4*)&vvt[tok][c4] = *(float4*)av;
    __syncthreads();

    int p = tid >> 2;
    int ptok = p >> 2, head = p & 3;
    int sub = tid & 3;
    int e0 = sub * 4;
    int t = t0 + ptok;
    float4 qf4 = *(const float4*)&qkt[ptok][head*16 + e0];
    float nsq = qf4.x*qf4.x + qf4.y*qf4.y + qf4.z*qf4.z + qf4.w*qf4.w;
    nsq += __shfl_xor(nsq,1); nsq += __shfl_xor(nsq,2);
    float inv = 1.f / fmaxf(sqrtf(nsq), 1e-12f);
    float qe[4] = {qf4.x, qf4.y, qf4.z, qf4.w};
    unsigned wq[4], wk[4];
    #pragma unroll
    for (int i=0;i<4;i++){
        float xq = qe[i]*0.25f;
        unsigned qh = rnbf(xq);
        unsigned ql = rnbf(xq - bf2f(qh));
        wq[i] = qh | (ql<<16);
        float xk = qe[i]*inv;
        unsigned kh = rnbf(xk);
        unsigned kl = rnbf(xk - bf2f(kh));
        wk[i] = kh | (kl<<16);
    }
    float4 vf4 = *(const float4*)&vvt[ptok][head*16 + e0];
    float ve[4] = {vf4.x, vf4.y, vf4.z, vf4.w};
    unsigned wv1[4], wv3[4];
    #pragma unroll
    for (int i=0;i<4;i++){
        unsigned vh_, vm_, vl_;
        split3(ve[i], vh_, vm_, vl_);
        wv1[i] = vh_ | (vm_<<16);
        wv3[i] = vl_ | (vh_<<16);
    }
    size_t sb = (((size_t)(b*NHEADS+head))*LSEQ + t)*64;
    *(uint4*)&qkvs[sb + e0]      = *(uint4*)wq;
    *(uint4*)&qkvs[sb + 16 + e0] = *(uint4*)wk;
    *(uint4*)&qkvs[sb + 32 + e0] = *(uint4*)wv1;
    *(uint4*)&qkvs[sb + 48 + e0] = *(uint4*)wv3;

    float qf[16];
    {
        float4 a0 = *(const float4*)&qkt[ptok][head*16 + 0];
        float4 a1 = *(const float4*)&qkt[ptok][head*16 + 4];
        float4 a2 = *(const float4*)&qkt[ptok][head*16 + 8];
        float4 a3 = *(const float4*)&qkt[ptok][head*16 + 12];
        qf[0]=a0.x; qf[1]=a0.y; qf[2]=a0.z; qf[3]=a0.w;
        qf[4]=a1.x; qf[5]=a1.y; qf[6]=a1.z; qf[7]=a1.w;
        qf[8]=a2.x; qf[9]=a2.y; qf[10]=a2.z; qf[11]=a2.w;
        qf[12]=a3.x; qf[13]=a3.y; qf[14]=a3.z; qf[15]=a3.w;
    }
    int nh = sub;
    float rv[10];
    #pragma unroll
    for (int i=0;i<10;i++) {
        float acc = 0.f;
        #pragma unroll
        for (int f=0; f<16; f++) acc += qf[f]*rots[(f*NHASH+nh)*10 + i];
        rv[i] = acc;
    }
    float best = rv[0]; int bi = 0;
    #pragma unroll
    for (int i=1;i<10;i++) if (rv[i] > best) { best = rv[i]; bi = i; }
    #pragma unroll
    for (int i=0;i<10;i++) if (-rv[i] > best) { best = -rv[i]; bi = 10+i; }
    buckets[((size_t)(b*NHEADS+head)*NHASH + nh)*LSEQ + t] = bi;
}

// ---------------- counting sort v2: 4 waves per (bh,hash) group; grid 256 x 256 ----------------
// wave w ballots chunks 5w..5w+4 into a mask table; 20-thread pass builds chunk-prefix and
// bucket-start tables; placement = start[b] + pre[ch][b] + in-chunk ballot rank.
// Ordering identical to v1 (bucket, chunk, lane) -> bit-exact permutation.
__global__ __launch_bounds__(256) void k_sort(
    const int* __restrict__ buckets, int* __restrict__ sorted)
{
    __shared__ unsigned long long masks[20][20];   // [chunk][bucket]
    __shared__ int pre[20][20];                    // prefix over chunks<ch per bucket
    __shared__ int startl[20];
    int tid = threadIdx.x;
    int w = tid >> 6, lane = tid & 63;
    int gidx = blockIdx.x;
    const int* bk = buckets + (size_t)gidx * LSEQ;
    int* dst = sorted + (size_t)gidx * LSEQ;

    int myb[5];
    #pragma unroll
    for (int i = 0; i < 5; i++) {
        int ch = w*5 + i;
        int bv = bk[ch*64 + lane];
        myb[i] = bv;
        #pragma unroll
        for (int b2 = 0; b2 < 20; b2++) {
            unsigned long long m2 = __ballot(bv == b2);
            if (lane == b2) masks[ch][b2] = m2;
        }
    }
    __syncthreads();
    if (tid < 20) {
        int run = 0;
        for (int ch = 0; ch < 20; ch++) {
            pre[ch][tid] = run;
            run += __popcll(masks[ch][tid]);
        }
        startl[tid] = run;          // total count for bucket tid (temp)
    }
    __syncthreads();
    if (tid == 0) {
        int acc = 0;
        for (int b2 = 0; b2 < 20; b2++) { int t = startl[b2]; startl[b2] = acc; acc += t; }
    }
    __syncthreads();
    unsigned long long below = (lane == 63) ? 0x7fffffffffffffffull
                                            : ((1ull << lane) - 1ull);
    #pragma unroll
    for (int i = 0; i < 5; i++) {
        int ch = w*5 + i;
        int bv = myb[i];
        int rank = startl[bv] + pre[ch][bv] + __popcll(masks[ch][bv] & below);
        dst[rank] = ch*64 + lane;
    }
}

// ---------------- chunked attention (round-12 version, measured best) ----------------
// XCD-colocated (bh = blockIdx&63); V-lo as bare u16 (B3 rebuilt); 30.9 KB LDS -> 5 blocks/CU.
__global__ __launch_bounds__(256) void k_attn(
    const unsigned* __restrict__ qkvs,
    const int* __restrict__ sorted, float* __restrict__ o_hash, float* __restrict__ slog)
{
    __shared__ __align__(16) unsigned SM[7904];            // 31616 B
    unsigned* Va1 = SM;                                    // 2624 u32 [kt8][dh16][key16] strides 328/20
    unsigned* Ka1 = SM + 2624;                             // 2560 u32 [key128][16] stride 20 (phase 1)
    unsigned* Pa1 = SM + 2624;                             // phase 2 alias
    unsigned short* Vlh  = (unsigned short*)(SM + 5184);   // 2624 u16 (V lo)
    unsigned short* Pa2h = (unsigned short*)(SM + 6496);   // 2560 u16 (P lo)
    int* kposS = (int*)(SM + 7776);                        // 128 ints

    int tid = threadIdx.x;
    int bh = blockIdx.x & 63;          // XCD swizzle: same bh -> same XCD (64 % 8 == 0)
    int c  = blockIdx.x >> 6;
    int h  = c / NBUK, cc = c % NBUK;
    int cp = (c + NCHUNK - 1) % NCHUNK;
    int hp = cp / NBUK, ccp = cp % NBUK;

    int key = tid & 127;
    int pos = (key < 64)
        ? sorted[((size_t)bh*NHASH + h)*LSEQ + cc*64 + key]
        : sorted[((size_t)bh*NHASH + hp)*LSEQ + ccp*64 + (key-64)];
    size_t srow = ((size_t)bh*LSEQ + pos)*64;
    if (tid < 128) {
        kposS[key] = pos;
        const uint4* kr = (const uint4*)(qkvs + srow + 16);
        #pragma unroll
        for (int e4=0; e4<4; e4++)
            *(uint4*)&Ka1[key*20 + e4*4] = kr[e4];
    } else {
        const uint4* v1r = (const uint4*)(qkvs + srow + 32);
        const uint4* v3r = (const uint4*)(qkvs + srow + 48);
        int kt = key >> 4, jl = key & 15;
        int lb = kt*328 + jl;
        #pragma unroll
        for (int e4=0; e4<4; e4++){
            uint4 a = v1r[e4], c2 = v3r[e4];
            unsigned aa[4] = {a.x,a.y,a.z,a.w};
            unsigned cb[4] = {c2.x,c2.y,c2.z,c2.w};
            #pragma unroll
            for (int i=0;i<4;i++){
                int d = e4*4 + i;
                Va1[lb + d*20] = aa[i];
                Vlh[lb + d*20] = (unsigned short)(cb[i] & 0xffffu);
            }
        }
    }
    __syncthreads();

    int w = tid >> 6, lane = tid & 63;
    int quad = lane >> 4, col = lane & 15;

    int qgpos = kposS[16*w + col];
    FU4 QA;
    QA.v = *(const uint4*)(qkvs + ((size_t)bh*LSEQ + qgpos)*64 + quad*4);
    frag_ab qA = QA.f;

    frag_c acc[8];
    #pragma unroll
    for (int nt=0; nt<8; nt++){
        FU4 B1, B2;
        B1.v = *(const uint4*)&Ka1[(nt*16+col)*20 + 4*quad];
        B2.v = rot16v(B1.v);
        frag_c a = {0.f,0.f,0.f,0.f};
        a = __builtin_amdgcn_mfma_f32_16x16x32_bf16(qA, B1.f, a, 0, 0, 0);
        a = __builtin_amdgcn_mfma_f32_16x16x32_bf16(qA, B2.f, a, 0, 0, 0);
        acc[nt] = a;
    }
    int qp[4];
    #pragma unroll
    for (int reg=0; reg<4; reg++) qp[reg] = kposS[16*w + quad*4 + reg];
    #pragma unroll
    for (int nt=0; nt<8; nt++){
        int kp2 = kposS[nt*16 + col];
        #pragma unroll
        for (int reg=0; reg<4; reg++)
            if (kp2 == qp[reg]) acc[nt][reg] = -5e4f;
    }
    float mx[4] = {-3.4e38f,-3.4e38f,-3.4e38f,-3.4e38f};
    #pragma unroll
    for (int nt=0; nt<8; nt++)
        #pragma unroll
        for (int reg=0; reg<4; reg++) mx[reg] = fmaxf(mx[reg], acc[nt][reg]);
    #pragma unroll
    for (int reg=0; reg<4; reg++){
        float m2 = mx[reg];
        m2 = fmaxf(m2, __shfl_xor(m2, 1)); m2 = fmaxf(m2, __shfl_xor(m2, 2));
        m2 = fmaxf(m2, __shfl_xor(m2, 4)); m2 = fmaxf(m2, __shfl_xor(m2, 8));
        mx[reg] = m2;
    }
    float sm2[4] = {0.f,0.f,0.f,0.f};
    #pragma unroll
    for (int nt=0; nt<8; nt++)
        #pragma unroll
        for (int reg=0; reg<4; reg++){
            float e = __expf(acc[nt][reg] - mx[reg]);
            acc[nt][reg] = e; sm2[reg] += e;
        }
    #pragma unroll
    for (int reg=0; reg<4; reg++){
        float s2 = sm2[reg];
        s2 += __shfl_xor(s2, 1); s2 += __shfl_xor(s2, 2);
        s2 += __shfl_xor(s2, 4); s2 += __shfl_xor(s2, 8);
        sm2[reg] = s2;
    }
    float invs[4];
    #pragma unroll
    for (int reg=0; reg<4; reg++) invs[reg] = 1.f / sm2[reg];
    if (col == 0) {
        #pragma unroll
        for (int reg=0; reg<4; reg++)
            slog[((size_t)bh*NHASH + h)*LSEQ + qp[reg]] = mx[reg] + __logf(sm2[reg]);
    }

    frag_c o = {0.f,0.f,0.f,0.f};
    __syncthreads();   // Ka1 dead -> Pa1 alias safe
    #pragma unroll
    for (int pass=0; pass<4; pass++){
        #pragma unroll
        for (int t2=0; t2<2; t2++){
            int nt = pass*2 + t2;
            #pragma unroll
            for (int reg=0; reg<4; reg++){
                float p = acc[nt][reg] * invs[reg];
                unsigned ph_, pm_, pl_;
                split3(p, ph_, pm_, pl_);
                int idx = t2*1280 + (16*w + 4*quad + reg)*20 + col;
                Pa1[idx] = ph_ | (pm_<<16);
                Pa2h[idx] = (unsigned short)pl_;
            }
        }
        __syncthreads();
        #pragma unroll
        for (int t2=0; t2<2; t2++){
            int ktg = pass*2 + t2;
            FU4 A1, A2, B1, B2, B3;
            int pidx = t2*1280 + (16*w + col)*20 + 4*quad;
            A1.v = *(const uint4*)&Pa1[pidx];
            uint2 z = *(const uint2*)&Pa2h[pidx];
            A2.v.x = (A1.v.x & 0xffffu) | (z.x << 16);
            A2.v.y = (A1.v.y & 0xffffu) | (z.x & 0xffff0000u);
            A2.v.z = (A1.v.z & 0xffffu) | (z.y << 16);
            A2.v.w = (A1.v.w & 0xffffu) | (z.y & 0xffff0000u);
            int vidx = ktg*328 + col*20 + 4*quad;
            B1.v = *(const uint4*)&Va1[vidx];
            B2.v = rot16v(B1.v);
            uint2 zl = *(const uint2*)&Vlh[vidx];
            B3.v.x = (zl.x & 0xffffu) | (B1.v.x << 16);
            B3.v.y = (zl.x >> 16)     | (B1.v.y << 16);
            B3.v.z = (zl.y & 0xffffu) | (B1.v.z << 16);
            B3.v.w = (zl.y >> 16)     | (B1.v.w << 16);
            o = __builtin_amdgcn_mfma_f32_16x16x32_bf16(A1.f, B1.f, o, 0, 0, 0);
            o = __builtin_amdgcn_mfma_f32_16x16x32_bf16(A1.f, B2.f, o, 0, 0, 0);
            o = __builtin_amdgcn_mfma_f32_16x16x32_bf16(A2.f, B3.f, o, 0, 0, 0);
        }
        if (pass < 3) __syncthreads();
    }
    size_t obase = ((size_t)bh*NHASH + h)*LSEQ;
    #pragma unroll
    for (int reg=0; reg<4; reg++)
        o_hash[(obase + qp[reg])*DHD + col] = o[reg];
}

// ---------------- fused tail v4: B2=rot16(B1); optional fused output projection ----------------
__global__ __launch_bounds__(256) void k_tail(
    const float* __restrict__ o_hash, const float* __restrict__ slog,
    const unsigned* __restrict__ wo_s, const float* __restrict__ wo_b,
    const float* __restrict__ g2, const float* __restrict__ b2t,
    const unsigned* __restrict__ w1_s, const float* __restrict__ b1,
    const unsigned* __restrict__ w2_s, const float* __restrict__ b2f,
    float* __restrict__ x1, float* __restrict__ x2,
    const float* __restrict__ out_w, const float* __restrict__ out_b,
    float* __restrict__ y, int do_out)
{
    __shared__ unsigned cA1[1024], cA2[1024];
    __shared__ unsigned xA1[1024], xA2[1024];
    __shared__ unsigned gA1[4096], gA2[4096];
    __shared__ float lnS[64], lnQ[64];
    float* red = (float*)gA1;

    int tid = threadIdx.x;
    int b  = blockIdx.x / 80;
    int t0 = (blockIdx.x % 80) * 16;
    int w = tid >> 6, lane = tid & 63;
    int quad = lane >> 4, col = lane & 15;

    {
        int tok = tid >> 4;
        int dg  = tid & 15;
        int d0  = dg * 4;
        int kt  = dg >> 2;
        int t = t0 + tok;
        int bh = b*NHEADS + kt;
        float sl[4];
        #pragma unroll
        for (int nh=0; nh<4; nh++) sl[nh] = slog[((size_t)bh*NHASH + nh)*LSEQ + t];
        float mx = fmaxf(fmaxf(sl[0],sl[1]), fmaxf(sl[2],sl[3]));
        float wgt[4]; float wsum = 0.f;
        #pragma unroll
        for (int nh=0; nh<4; nh++){ wgt[nh] = __expf(sl[nh]-mx); wsum += wgt[nh]; }
        float iv = 1.f/wsum;
        float a4[4] = {0.f,0.f,0.f,0.f};
        #pragma unroll
        for (int nh=0; nh<4; nh++){
            float4 oh = *(const float4*)&o_hash[(((size_t)bh*NHASH + nh)*LSEQ + t)*DHD + (d0 & 15)];
            float wn = wgt[nh]*iv;
            a4[0] += wn*oh.x; a4[1] += wn*oh.y; a4[2] += wn*oh.z; a4[3] += wn*oh.w;
        }
        int sw = (tok & 7) << 2;
        unsigned cw1[4], cw2[4];
        #pragma unroll
        for (int i=0;i<4;i++){
            unsigned h_, m_, l_;
            split3(a4[i], h_, m_, l_);
            cw1[i] = h_ | (m_<<16);
            cw2[i] = h_ | (l_<<16);
        }
        *(uint4*)&cA1[tok*64 + (d0 ^ sw)] = *(uint4*)cw1;
        *(uint4*)&cA2[tok*64 + (d0 ^ sw)] = *(uint4*)cw2;
    }
    __syncthreads();
    FU4 aA1[4], aA2[4];
    {
        int sw = (col & 7) << 2;
        #pragma unroll
        for (int kt=0; kt<4; kt++){
            int word = (kt*16 + quad*4) ^ sw;
            aA1[kt].v = *(const uint4*)&cA1[col*64 + word];
            aA2[kt].v = *(const uint4*)&cA2[col*64 + word];
        }
    }

    frag_c awo = {0.f,0.f,0.f,0.f};
    #pragma unroll
    for (int kt=0; kt<4; kt++){
        FU4 B1, B2, B3;
        int bidx = ((kt*4 + w)*16 + col)*16 + quad*4;
        B1.v = *(const uint4*)&wo_s[bidx];
        B2.v = rot16v(B1.v);
        B3.v = *(const uint4*)&wo_s[bidx + 4096];
        awo = __builtin_amdgcn_mfma_f32_16x16x32_bf16(aA1[kt].f, B1.f, awo, 0, 0, 0);
        awo = __builtin_amdgcn_mfma_f32_16x16x32_bf16(aA1[kt].f, B2.f, awo, 0, 0, 0);
        awo = __builtin_amdgcn_mfma_f32_16x16x32_bf16(aA2[kt].f, B3.f, awo, 0, 0, 0);
    }
    int cg = w*16 + col;
    float x1n[4];
    float s1[4], s2[4];
    {
        float wb = wo_b[cg];
        #pragma unroll
        for (int reg=0; reg<4; reg++){
            int rg = t0 + quad*4 + reg;
            size_t xi = ((size_t)b*LSEQ + rg)*DM + cg;
            float xv = x1[xi] + awo[reg] + wb;
            x1[xi] = xv;
            x1n[reg] = xv;
            s1[reg] = xv; s2[reg] = xv*xv;
        }
    }
    #pragma unroll
    for (int reg=0; reg<4; reg++){
        float a = s1[reg], q = s2[reg];
        a += __shfl_xor(a,1); a += __shfl_xor(a,2); a += __shfl_xor(a,4); a += __shfl_xor(a,8);
        q += __shfl_xor(q,1); q += __shfl_xor(q,2); q += __shfl_xor(q,4); q += __shfl_xor(q,8);
        s1[reg] = a; s2[reg] = q;
    }
    if (col == 0) {
        #pragma unroll
        for (int reg=0; reg<4; reg++){
            lnS[w*16 + quad*4 + reg] = s1[reg];
            lnQ[w*16 + quad*4 + reg] = s2[reg];
        }
    }
    __syncthreads();
    float mean[4], rstd[4];
    #pragma unroll
    for (int reg=0; reg<4; reg++){
        int tok = quad*4 + reg;
        float a = lnS[tok] + lnS[16+tok] + lnS[32+tok] + lnS[48+tok];
        float q = lnQ[tok] + lnQ[16+tok] + lnQ[32+tok] + lnQ[48+tok];
        mean[reg] = a*(1.f/64.f);
        float var = q*(1.f/64.f) - mean[reg]*mean[reg];
        rstd[reg] = 1.f/sqrtf(var + 1e-5f);
    }
    {
        float gv = g2[cg], bv = b2t[cg];
        #pragma unroll
        for (int reg=0; reg<4; reg++){
            int row = quad*4 + reg;
            float xv = (x1n[reg]-mean[reg])*rstd[reg]*gv + bv;
            unsigned h_, m_, l_;
            split3(xv, h_, m_, l_);
            int word = cg ^ ((row & 7) << 2);
            xA1[row*64 + word] = h_ | (m_<<16);
            xA2[row*64 + word] = h_ | (l_<<16);
        }
    }
    __syncthreads();
    FU4 xa1[4], xa2[4];
    {
        int sw = (col & 7) << 2;
        #pragma unroll
        for (int kt=0; kt<4; kt++){
            int word = (kt*16 + quad*4) ^ sw;
            xa1[kt].v = *(const uint4*)&xA1[col*64 + word];
            xa2[kt].v = *(const uint4*)&xA2[col*64 + word];
        }
    }

    unsigned* myg1 = gA1 + w*1024;
    unsigned* myg2 = gA2 + w*1024;
    #pragma unroll
    for (int ntl=0; ntl<4; ntl++){
        int nt = w*4 + ntl;
        frag_c a = {0.f,0.f,0.f,0.f};
        #pragma unroll
        for (int kt=0; kt<4; kt++){
            FU4 B1, B2, B3;
            int bidx = ((kt*16 + nt)*16 + col)*16 + quad*4;
            B1.v = *(const uint4*)&w1_s[bidx];
            B2.v = rot16v(B1.v);
            B3.v = *(const uint4*)&w1_s[bidx + 16384];
            a = __builtin_amdgcn_mfma_f32_16x16x32_bf16(xa1[kt].f, B1.f, a, 0, 0, 0);
            a = __builtin_amdgcn_mfma_f32_16x16x32_bf16(xa1[kt].f, B2.f, a, 0, 0, 0);
            a = __builtin_amdgcn_mfma_f32_16x16x32_bf16(xa2[kt].f, B3.f, a, 0, 0, 0);
        }
        float bb = b1[nt*16 + col];
        #pragma unroll
        for (int reg=0; reg<4; reg++){
            float xx = a[reg] + bb;
            float ge = 0.5f*xx*(1.f + erff(xx*0.70710678118654752f));
            unsigned h_, m_, l_;
            split3(ge, h_, m_, l_);
            int row = quad*4 + reg;
            int word = (ntl*16 + col) ^ ((row & 7) << 2);
            myg1[row*64 + word] = h_ | (m_<<16);
            myg2[row*64 + word] = h_ | (l_<<16);
        }
    }
    frag_c aw2[4] = {{0,0,0,0},{0,0,0,0},{0,0,0,0},{0,0,0,0}};
    {
        int sw = (col & 7) << 2;
        #pragma unroll
        for (int kt2=0; kt2<4; kt2++){
            FU4 A1, A2;
            int word = (kt2*16 + quad*4) ^ sw;
            A1.v = *(const uint4*)&myg1[col*64 + word];
            A2.v = *(const uint4*)&myg2[col*64 + word];
            int kg = w*4 + kt2;
            #pragma unroll
            for (int nt2=0; nt2<4; nt2++){
                FU4 B1, B2, B3;
                int bidx = ((kg*4 + nt2)*16 + col)*16 + quad*4;
                B1.v = *(const uint4*)&w2_s[bidx];
                B2.v = rot16v(B1.v);
                B3.v = *(const uint4*)&w2_s[bidx + 16384];
                aw2[nt2] = __builtin_amdgcn_mfma_f32_16x16x32_bf16(A1.f, B1.f, aw2[nt2], 0, 0, 0);
                aw2[nt2] = __builtin_amdgcn_mfma_f32_16x16x32_bf16(A1.f, B2.f, aw2[nt2], 0, 0, 0);
                aw2[nt2] = __builtin_amdgcn_mfma_f32_16x16x32_bf16(A2.f, B3.f, aw2[nt2], 0, 0, 0);
            }
        }
    }
    __syncthreads();
    #pragma unroll
    for (int nt2=0; nt2<4; nt2++)
        #pragma unroll
        for (int reg=0; reg<4; reg++)
            red[((w*4 + nt2)*4 + reg)*64 + lane] = aw2[nt2][reg];
    __syncthreads();
    float x2f[4];
    {
        float bb = b2f[cg];
        #pragma unroll
        for (int reg=0; reg<4; reg++){
            float v = red[((0*4 + w)*4 + reg)*64 + lane]
                    + red[((1*4 + w)*4 + reg)*64 + lane]
                    + red[((2*4 + w)*4 + reg)*64 + lane]
                    + red[((3*4 + w)*4 + reg)*64 + lane];
            int rg = t0 + quad*4 + reg;
            size_t xi = ((size_t)b*LSEQ + rg)*DM + cg;
            float nv = x2[xi] + v + bb;
            x2[xi] = nv;
            x2f[reg] = nv;
        }
    }
    if (do_out) {
        float ow = out_w[cg];
        float part[4];
        #pragma unroll
        for (int reg=0; reg<4; reg++){
            float p = (x1n[reg] + x2f[reg]) * 0.5f * ow;
            p += __shfl_xor(p,1); p += __shfl_xor(p,2); p += __shfl_xor(p,4); p += __shfl_xor(p,8);
            part[reg] = p;
        }
        __syncthreads();
        if (col == 0) {
            #pragma unroll
            for (int reg=0; reg<4; reg++)
                lnS[w*16 + quad*4 + reg] = part[reg];
        }
        __syncthreads();
        if (tid < 16) {
            int t = t0 + tid;
            if (t < L0SEQ) {
                float v2 = lnS[tid] + lnS[16+tid] + lnS[32+tid] + lnS[48+tid];
                y[(size_t)b*L0SEQ + t] = v2 + out_b[0];
            }
        }
    }
}

extern "C" void kernel_launch(void* const* d_in, const int* in_sizes, int n_in,
                              void* d_out, int out_size, void* d_ws, size_t ws_size,
                              hipStream_t stream)
{
    const float* wave  = (const float*)d_in[0];
    const float* in_w  = (const float*)d_in[1];
    const float* in_b  = (const float*)d_in[2];
    const float* ln1_g = (const float*)d_in[3];
    const float* ln1_b = (const float*)d_in[4];
    const float* wqk   = (const float*)d_in[5];
    const float* wv    = (const float*)d_in[6];
    const float* wo_w  = (const float*)d_in[7];
    const float* wo_b  = (const float*)d_in[8];
    const float* rot   = (const float*)d_in[9];
    const float* ln2_g = (const float*)d_in[10];
    const float* ln2_b = (const float*)d_in[11];
    const float* w1    = (const float*)d_in[12];
    const float* b1    = (const float*)d_in[13];
    const float* w2    = (const float*)d_in[14];
    const float* b2    = (const float*)d_in[15];
    const float* out_w = (const float*)d_in[16];
    const float* out_b = (const float*)d_in[17];
    float* y = (float*)d_out;

    float* ws = (float*)d_ws;
    float* x1      = ws;                       // XSZ f32
    float* x2      = x1 + XSZ;                 // XSZ f32
    unsigned* qkvs = (unsigned*)(x2 + XSZ);    // 4*QKSZ u32 (interleaved)
    float* o_hash  = (float*)(qkvs + 4*QKSZ);  // OHSZ f32
    float* slogb   = o_hash + OHSZ;            // SLSZ f32
    int* buckets   = (int*)(slogb + SLSZ);     // SLSZ int
    int* sorted    = buckets + SLSZ;           // SLSZ int
    unsigned* wsplit = (unsigned*)(sorted + SLSZ); // 294912 u32

    k_init<<<5696, 256, 0, stream>>>(wave, in_w, in_b, x1, x2, wo_w, w1, w2, wsplit);
    for (int layer = 0; layer < 4; layer++) {
        k_qkv<<<NBATCH*80, 256, 0, stream>>>(x2, ln1_g + layer*64, ln1_b + layer*64,
                                       wqk + layer*4096, wv + layer*4096, rot + layer*640,
                                       qkvs, buckets);
        k_sort<<<256, 256, 0, stream>>>(buckets, sorted);
        k_attn<<<NBH*NCHUNK, 256, 0, stream>>>(qkvs, sorted, o_hash, slogb);
        k_tail<<<NBATCH*LSEQ/16, 256, 0, stream>>>(o_hash, slogb,
                                        wsplit + layer*8192, wo_b + layer*64,
                                        ln2_g + layer*64, ln2_b + layer*64,
                                        wsplit + 32768 + layer*32768, b1 + layer*256,
                                        wsplit + 163840 + layer*32768, b2 + layer*64,
                                        x1, x2,
                                        out_w, out_b, y, (layer == 3) ? 1 : 0);
    }
}